// Round 6
// baseline (209.880 us; speedup 1.0000x reference)
//
#include <hip/hip_runtime.h>

typedef unsigned int uint;
typedef unsigned short ushort;
typedef __bf16 bf16x8 __attribute__((ext_vector_type(8)));
typedef float f32x4 __attribute__((ext_vector_type(4)));

__device__ __forceinline__ ushort f2bf(float v) {
    uint u = __builtin_bit_cast(uint, v);
    u += 0x7fffu + ((u >> 16) & 1u);   // RNE
    return (ushort)(u >> 16);
}

// 4 consecutive elements at p (vectorized epilogue stores)
__device__ __forceinline__ void store4(float* p, const f32x4 v) { *(f32x4*)p = v; }
__device__ __forceinline__ void store4(ushort* p, const f32x4 v) {
    uint2 r;
    r.x = (uint)f2bf(v[0]) | ((uint)f2bf(v[1]) << 16);
    r.y = (uint)f2bf(v[2]) | ((uint)f2bf(v[3]) << 16);
    *(uint2*)p = r;
}

#define GLDS(g, l) __builtin_amdgcn_global_load_lds( \
    (const __attribute__((address_space(1))) uint*)(g), \
    (__attribute__((address_space(3))) uint*)(l), 16, 0, 0)

#define VMW(N)  asm volatile("s_waitcnt vmcnt(" #N ")" ::: "memory")
#define SBAR()  asm volatile("s_barrier" ::: "memory")

// Stage 128 rows x 64 cols bf16 (16KB) = one half-tile = 2 gload_lds/thread.
// LDS swizzle: 16B-slot s of row r stored at slot s^(r&7); pre-swizzled
// GLOBAL source (linear LDS dest, rule #21); reads apply the same XOR.
__device__ __forceinline__ void stage_half(const ushort* __restrict__ src, int ld,
                                           int halfrow, char* ldsbase, int tid)
{
#pragma unroll
    for (int i = 0; i < 2; i++) {
        const int byte = i * 8192 + tid * 16;
        const int row  = byte >> 7;
        const int slot = (byte >> 4) & 7;
        const int srcs = slot ^ (row & 7);
        GLDS(src + (long long)(halfrow + row) * ld + srcs * 8,
             ldsbase + halfrow * 128 + byte);
    }
}

__device__ __forceinline__ bf16x8 ldf(const char* base, int rbase, int ks,
                                      int lrow, int lquad)
{
    const int r    = rbase + lrow;
    const int slot = ((ks << 2) + lquad) ^ (r & 7);
    return *(const bf16x8*)(base + r * 128 + slot * 16);
}

#define RD_A(BASE, ROFF) \
    _Pragma("unroll") for (int m_ = 0; m_ < 4; m_++) \
    _Pragma("unroll") for (int k_ = 0; k_ < 2; k_++) \
        af[m_][k_] = ldf(BASE, (ROFF) + m_ * 16, k_, lrow, lquad);

#define RD_B(DST, BASE, ROFF) \
    _Pragma("unroll") for (int n_ = 0; n_ < 2; n_++) \
    _Pragma("unroll") for (int k_ = 0; k_ < 2; k_++) \
        DST[n_][k_] = ldf(BASE, (ROFF) + n_ * 16, k_, lrow, lquad);

// OPERAND-SWAPPED MFMA: mfma(B, A) computes C^T in regs; per verified D-layout
// (col=lane&15, row=lquad*4+reg) each lane then holds C-row = frag_row + lrow,
// C-cols = frag_col + lquad*4 + {0..3}  -> 4 CONSECUTIVE cols = one 8/16B store.
#define QUAD(MOFF, NOFF, B) \
    __builtin_amdgcn_s_setprio(1); \
    _Pragma("unroll") for (int m_ = 0; m_ < 4; m_++) \
    _Pragma("unroll") for (int n_ = 0; n_ < 2; n_++) \
    _Pragma("unroll") for (int k_ = 0; k_ < 2; k_++) \
        acc[(MOFF) + m_][(NOFF) + n_] = __builtin_amdgcn_mfma_f32_16x16x32_bf16( \
            B[n_][k_], af[m_][k_], acc[(MOFF) + m_][(NOFF) + n_], 0, 0, 0); \
    __builtin_amdgcn_s_setprio(0);

// ---------------------------------------------------------------------------
// gemm256_8ph: 256x256 tile, BK=64, m201-faithful 8-phase (verified round 5).
// EXP epilogue: e=exp(acc*scale) -> bf16, per-wave 64-col row sums -> Zp.
// ---------------------------------------------------------------------------
template<bool EXP>
__global__ __launch_bounds__(512, 2)
void gemm256_8ph(const ushort* __restrict__ A, int lda, long long bsA,
                 const ushort* __restrict__ Bt, int ldb, long long bsB,
                 ushort* __restrict__ C, int ldc, long long bsC,
                 int K, float scale, float* __restrict__ Zp)
{
    __shared__ char smem[131072];
    char* A0 = smem;
    char* A1 = smem + 32768;
    char* B0 = smem + 65536;
    char* B1 = smem + 98304;

    const int tid   = threadIdx.x;
    const int lane  = tid & 63;
    const int wave  = tid >> 6;
    const int wr    = wave >> 2;
    const int wc    = wave & 3;
    const int lrow  = lane & 15;
    const int lquad = lane >> 4;
    const long long b = blockIdx.z;

    const ushort* Ag = A  + b * bsA + (long long)blockIdx.y * 256 * lda;
    const ushort* Bg = Bt + b * bsB + (long long)blockIdx.x * 256 * ldb;
    ushort*       Cg = C  + b * bsC + (long long)blockIdx.y * 256 * ldc
                           + (long long)blockIdx.x * 256;

    f32x4 acc[8][4] = {};
    bf16x8 af[4][2], bl[2][2], bh[2][2];

    const int nk    = K >> 6;
    const int nIter = nk >> 1;

    stage_half(Ag,      lda, 0,   A0, tid);
    stage_half(Bg,      ldb, 0,   B0, tid);
    stage_half(Bg,      ldb, 128, B0, tid);
    stage_half(Ag,      lda, 128, A0, tid);
    stage_half(Ag + 64, lda, 0,   A1, tid);
    stage_half(Bg + 64, ldb, 0,   B1, tid);
    stage_half(Bg + 64, ldb, 128, B1, tid);
    VMW(6); SBAR();

    for (int i = 0; i < nIter - 1; ++i) {
        const ushort* An1 = Ag + (2 * i + 1) * 64;
        const ushort* An2 = Ag + (2 * i + 2) * 64;
        const ushort* Bn2 = Bg + (2 * i + 2) * 64;
        const ushort* An3 = Ag + (2 * i + 3) * 64;
        const ushort* Bn3 = Bg + (2 * i + 3) * 64;

        RD_A(A0, wr * 64); RD_B(bl, B0, wc * 32);
        stage_half(An1, lda, 128, A1, tid);
        SBAR(); QUAD(0, 0, bl); SBAR();

        RD_B(bh, B0, 128 + wc * 32);
        stage_half(An2, lda, 0, A0, tid);
        SBAR(); QUAD(0, 2, bh); SBAR();

        RD_A(A0, 128 + wr * 64);
        stage_half(Bn2, ldb, 0, B0, tid);
        SBAR(); QUAD(4, 0, bl); SBAR();

        stage_half(Bn2, ldb, 128, B0, tid);
        SBAR(); QUAD(4, 2, bh); VMW(6); SBAR();

        RD_A(A1, wr * 64); RD_B(bl, B1, wc * 32);
        stage_half(An2, lda, 128, A0, tid);
        SBAR(); QUAD(0, 0, bl); SBAR();

        RD_B(bh, B1, 128 + wc * 32);
        stage_half(An3, lda, 0, A1, tid);
        SBAR(); QUAD(0, 2, bh); SBAR();

        RD_A(A1, 128 + wr * 64);
        stage_half(Bn3, ldb, 0, B1, tid);
        SBAR(); QUAD(4, 0, bl); SBAR();

        stage_half(Bn3, ldb, 128, B1, tid);
        SBAR(); QUAD(4, 2, bh); VMW(6); SBAR();
    }

    {
        const ushort* An1 = Ag + (nk - 1) * 64;

        RD_A(A0, wr * 64); RD_B(bl, B0, wc * 32);
        stage_half(An1, lda, 128, A1, tid);
        SBAR(); QUAD(0, 0, bl); SBAR();

        RD_B(bh, B0, 128 + wc * 32);
        SBAR(); QUAD(0, 2, bh); SBAR();

        RD_A(A0, 128 + wr * 64);
        SBAR(); QUAD(4, 0, bl); SBAR();

        SBAR(); QUAD(4, 2, bh); VMW(0); SBAR();

        RD_A(A1, wr * 64); RD_B(bl, B1, wc * 32);
        SBAR(); QUAD(0, 0, bl); SBAR();

        RD_B(bh, B1, 128 + wc * 32);
        SBAR(); QUAD(0, 2, bh); SBAR();

        RD_A(A1, 128 + wr * 64);
        SBAR(); QUAD(4, 0, bl); SBAR();

        SBAR(); QUAD(4, 2, bh);
    }

    // vectorized epilogue (swapped layout): row = frag_row + lrow,
    // col = frag_col + lquad*4 + j  (4 consecutive -> one uint2 store)
#pragma unroll
    for (int m = 0; m < 8; m++) {
        const int row = (m >> 2) * 128 + wr * 64 + (m & 3) * 16 + lrow;
        float rs = 0.f;
#pragma unroll
        for (int n = 0; n < 4; n++) {
            const int col = (n >> 1) * 128 + wc * 32 + (n & 1) * 16 + lquad * 4;
            f32x4 v = acc[m][n];
            if (EXP) {
#pragma unroll
                for (int j = 0; j < 4; j++) { v[j] = __expf(v[j] * scale); rs += v[j]; }
            }
            store4(&Cg[(long long)row * ldc + col], v);
        }
        if (EXP) {
            rs += __shfl_xor(rs, 16);
            rs += __shfl_xor(rs, 32);   // all lquads of this lrow now hold wave row-sum
            if (lquad == 0) {
                const long long zi = ((long long)b * 32 + blockIdx.x * 4 + wc) * 2048
                                   + (long long)blockIdx.y * 256 + row;
                Zp[zi] = rs;
            }
        }
    }
}

// ---------------------------------------------------------------------------
// gemm128: 256x128 tile, BK=64, 2-phase counted-vmcnt (verified round 4).
//   prologue: stage Alo0,B0,Ahi0 (6) -> VMW(2); SBAR
//   ph1: RD Alo,B; stage Alo',B'; SBAR; 16 MFMA; VMW(4) lands Ahi(T); SBAR
//   ph2: RD Ahi; stage Ahi'; SBAR; 16 MFMA; VMW(2) lands Alo',B'; SBAR
// ---------------------------------------------------------------------------
template<typename OUT_T>
__global__ __launch_bounds__(512, 2)
void gemm128(const ushort* __restrict__ A, int lda, long long bsA,
             const ushort* __restrict__ Bt, int ldb, long long bsB,
             OUT_T* __restrict__ C, int ldc, long long bsC, int K)
{
    __shared__ char smem[98304];

    const int tid   = threadIdx.x;
    const int lane  = tid & 63;
    const int wave  = tid >> 6;
    const int wr    = wave >> 2;
    const int wc    = wave & 3;
    const int lrow  = lane & 15;
    const int lquad = lane >> 4;
    const long long b = blockIdx.z;

    const ushort* Ag = A  + b * bsA + (long long)blockIdx.y * 256 * lda;
    const ushort* Bg = Bt + b * bsB + (long long)blockIdx.x * 128 * ldb;
    OUT_T*        Cg = C  + b * bsC + (long long)blockIdx.y * 256 * ldc
                           + (long long)blockIdx.x * 128;

    f32x4 acc[8][2] = {};
    bf16x8 af[4][2], bfr[2][2];

    const int nk = K >> 6;

    stage_half(Ag, lda, 0,   smem,         tid);
    stage_half(Bg, ldb, 0,   smem + 65536, tid);
    stage_half(Ag, lda, 128, smem,         tid);
    VMW(2); SBAR();

    for (int t = 0; t < nk - 1; ++t) {
        const int cur = t & 1;
        const char* lAc = smem + cur * 32768;
        const char* lBc = smem + 65536 + cur * 16384;
        char* lAn = smem + (cur ^ 1) * 32768;
        char* lBn = smem + 65536 + (cur ^ 1) * 16384;
        const ushort* An = Ag + (t + 1) * 64;
        const ushort* Bn = Bg + (t + 1) * 64;

        RD_A(lAc, wr * 64);
        RD_B(bfr, lBc, wc * 32);
        stage_half(An, lda, 0, lAn, tid);
        stage_half(Bn, ldb, 0, lBn, tid);
        SBAR();
        QUAD(0, 0, bfr);
        VMW(4); SBAR();

        RD_A(lAc, 128 + wr * 64);
        stage_half(An, lda, 128, lAn, tid);
        SBAR();
        QUAD(4, 0, bfr);
        VMW(2); SBAR();
    }

    {
        const int cur = (nk - 1) & 1;
        const char* lAc = smem + cur * 32768;
        const char* lBc = smem + 65536 + cur * 16384;

        RD_A(lAc, wr * 64);
        RD_B(bfr, lBc, wc * 32);
        SBAR();
        QUAD(0, 0, bfr);
        VMW(0); SBAR();

        RD_A(lAc, 128 + wr * 64);
        SBAR();
        QUAD(4, 0, bfr);
    }

#pragma unroll
    for (int m = 0; m < 8; m++) {
        const int row = (m >> 2) * 128 + wr * 64 + (m & 3) * 16 + lrow;
#pragma unroll
        for (int n = 0; n < 2; n++) {
            const int col = wc * 32 + n * 16 + lquad * 4;
            store4(&Cg[(long long)row * ldc + col], acc[m][n]);
        }
    }
}

// ---------------------------------------------------------------------------
// gemm_bm128: 128x256 tile, BK=64 (verified round 5 structure).
// ---------------------------------------------------------------------------
template<typename OUT_T, bool ZSCALE>
__global__ __launch_bounds__(512, 2)
void gemm_bm128(const ushort* __restrict__ A, int lda, long long bsA,
                const ushort* __restrict__ Bt, int ldb, long long bsB,
                OUT_T* __restrict__ C, int ldc, long long bsC,
                int K, const float* __restrict__ zinv)
{
    __shared__ char smem[98304];

    const int tid   = threadIdx.x;
    const int lane  = tid & 63;
    const int wave  = tid >> 6;
    const int wr    = wave >> 2;
    const int wc    = wave & 3;
    const int lrow  = lane & 15;
    const int lquad = lane >> 4;
    const long long b = blockIdx.z;

    const ushort* Ag = A  + b * bsA + (long long)blockIdx.y * 128 * lda;
    const ushort* Bg = Bt + b * bsB + (long long)blockIdx.x * 256 * ldb;
    OUT_T*        Cg = C  + b * bsC + (long long)blockIdx.y * 128 * ldc
                           + (long long)blockIdx.x * 256;

    f32x4 acc[4][4] = {};
    bf16x8 af[4][2], bl[2][2], bh[2][2];

    const int nk = K >> 6;

    stage_half(Ag, lda, 0,   smem,         tid);
    stage_half(Bg, ldb, 0,   smem + 32768, tid);
    stage_half(Bg, ldb, 128, smem + 32768, tid);
    VMW(2); SBAR();

    for (int t = 0; t < nk - 1; ++t) {
        const int cur = t & 1;
        const char* lAc = smem + cur * 16384;
        const char* lBc = smem + 32768 + cur * 32768;
        char* lAn = smem + (cur ^ 1) * 16384;
        char* lBn = smem + 32768 + (cur ^ 1) * 32768;
        const ushort* An = Ag + (t + 1) * 64;
        const ushort* Bn = Bg + (t + 1) * 64;

        RD_A(lAc, wr * 64);
        RD_B(bl, lBc, wc * 32);
        stage_half(An, lda, 0, lAn, tid);
        stage_half(Bn, ldb, 0, lBn, tid);
        SBAR();
        QUAD(0, 0, bl);
        VMW(4); SBAR();

        RD_B(bh, lBc, 128 + wc * 32);
        stage_half(Bn, ldb, 128, lBn, tid);
        SBAR();
        QUAD(0, 2, bh);
        VMW(2); SBAR();
    }

    {
        const int cur = (nk - 1) & 1;
        const char* lAc = smem + cur * 16384;
        const char* lBc = smem + 32768 + cur * 32768;

        RD_A(lAc, wr * 64);
        RD_B(bl, lBc, wc * 32);
        SBAR();
        QUAD(0, 0, bl);
        VMW(0); SBAR();

        RD_B(bh, lBc, 128 + wc * 32);
        SBAR();
        QUAD(0, 2, bh);
    }

#pragma unroll
    for (int m = 0; m < 4; m++) {
        const int row = wr * 64 + m * 16 + lrow;
        float z = 1.f;
        if (ZSCALE) z = zinv[b * 2048 + (long long)blockIdx.y * 128 + row];
#pragma unroll
        for (int n = 0; n < 4; n++) {
            const int col = (n >> 1) * 128 + wc * 32 + (n & 1) * 16 + lquad * 4;
            f32x4 v = acc[m][n];
            if (ZSCALE) {
#pragma unroll
                for (int j = 0; j < 4; j++) v[j] *= z;
            }
            store4(&Cg[(long long)row * ldc + col], v);
        }
    }
}

// ---------------------------------------------------------------------------
__global__ __launch_bounds__(256)
void f32_to_bf16_vec(const float* __restrict__ in, ushort* __restrict__ out, int n4)
{
    int i = blockIdx.x * 256 + threadIdx.x;
    if (i >= n4) return;
    float4 v = ((const float4*)in)[i];
    ushort o[4] = { f2bf(v.x), f2bf(v.y), f2bf(v.z), f2bf(v.w) };
    *(uint2*)&out[(size_t)i * 4] = *(const uint2*)&o[0];
}

// ---------------------------------------------------------------------------
__global__ __launch_bounds__(256)
void zinv_k(const float* __restrict__ zp, float* __restrict__ zi)
{
    const int t = blockIdx.x * 256 + threadIdx.x;   // 0..8191
    const int b = t >> 11, r = t & 2047;
    const float* p = zp + (long long)b * 32 * 2048 + r;
    float s = 0.f;
#pragma unroll
    for (int i = 0; i < 32; i++) s += p[i * 2048];
    zi[t] = 1.0f / s;
}

// ---------------------------------------------------------------------------
__global__ __launch_bounds__(256)
void transpose_v(const ushort* __restrict__ V, int ldv, long long bsV,
                 ushort* __restrict__ Vt)
{
    __shared__ ushort t[64][65];
    const int b = blockIdx.z;
    const ushort* src = V  + (size_t)b * bsV;
    ushort*       dst = Vt + (size_t)b * 1024 * 2048;
    const int e0 = blockIdx.x * 64;
    const int k0 = blockIdx.y * 64;
    const int r = threadIdx.x >> 2;
    const int c = (threadIdx.x & 3) * 16;

    const ushort* p = &src[(size_t)(k0 + r) * ldv + e0 + c];
    ushort vals[16];
    *(uint4*)&vals[0] = *(const uint4*)p;
    *(uint4*)&vals[8] = *(const uint4*)(p + 8);
#pragma unroll
    for (int j = 0; j < 16; j++) t[r][c + j] = vals[j];
    __syncthreads();

    ushort o[16];
#pragma unroll
    for (int j = 0; j < 16; j++) o[j] = t[c + j][r];
    ushort* q = &dst[(size_t)(e0 + r) * 2048 + k0 + c];
    *(uint4*)q       = *(const uint4*)&o[0];
    *(uint4*)(q + 8) = *(const uint4*)&o[8];
}

// ---------------------------------------------------------------------------
extern "C" void kernel_launch(void* const* d_in, const int* in_sizes, int n_in,
                              void* d_out, int out_size, void* d_ws, size_t ws_size,
                              hipStream_t stream)
{
    const float* x  = (const float*)d_in[0];
    const float* wq = (const float*)d_in[1];
    const float* wk = (const float*)d_in[2];
    const float* wv = (const float*)d_in[3];
    const float* wo = (const float*)d_in[4];
    float* out = (float*)d_out;

    // B=4, S=2048, D=1024; M = 8192
    char* ws = (char*)d_ws;
    ushort* xb    = (ushort*)(ws);                 // 16 MB  [8192][1024]
    ushort* wqkv  = (ushort*)(ws + 16777216);      //  6 MB  [3072][1024]
    ushort* wob   = (ushort*)(ws + 23068672);      //  2 MB  [1024][1024]
    ushort* QKVb  = (ushort*)(ws + 25165824);      // 48 MB  [8192][3072]
    ushort* Vtb   = (ushort*)(ws + 75497472);      // 16 MB  [4][1024][2048]
    ushort* Ob    = (ushort*)(ws + 92274688);      // 16 MB  [8192][1024]
    ushort* E     = (ushort*)(ws + 109051904);     // 32 MB  [4][2048][2048] bf16
    float*  Zp    = (float*)(ws + 142606336);      //  1 MB  [4][32][2048]
    float*  Zi    = (float*)(ws + 143654912);      // 32 KB  [4][2048]

    // 1. converts (wq/wk/wv packed into one [3072][1024])
    f32_to_bf16_vec<<<8192, 256, 0, stream>>>(x,  xb,   2097152);
    f32_to_bf16_vec<<<1024, 256, 0, stream>>>(wq, wqkv,           262144);
    f32_to_bf16_vec<<<1024, 256, 0, stream>>>(wk, wqkv + 1048576, 262144);
    f32_to_bf16_vec<<<1024, 256, 0, stream>>>(wv, wqkv + 2097152, 262144);
    f32_to_bf16_vec<<<1024, 256, 0, stream>>>(wo, wob,            262144);

    // 2. fused QKV projection: [8192][3072] = xb @ wqkv^T  (768 blocks = 3 exact waves)
    gemm128<ushort><<<dim3(24, 32, 1), 512, 0, stream>>>(
        xb, 1024, 0, wqkv, 1024, 0, QKVb, 3072, 0, 1024);

    // 3. V^T per batch -> [b][1024][2048]
    transpose_v<<<dim3(16, 32, 4), 256, 0, stream>>>(QKVb + 2048, 3072, 2048LL * 3072, Vtb);

    // 4. E = exp(Q K^T / 32) bf16 + row-sum partials   (256 blocks = 1 wave)
    gemm256_8ph<true><<<dim3(8, 8, 4), 512, 0, stream>>>(
        QKVb, 3072, 2048LL * 3072, QKVb + 1024, 3072, 2048LL * 3072,
        E, 2048, 2048LL * 2048, 1024, 0.03125f, Zp);

    // 5. Zi = 1 / rowsum
    zinv_k<<<32, 256, 0, stream>>>(Zp, Zi);

    // 6. O = (E @ V) * Zi   (256 blocks = 1 wave)
    gemm_bm128<ushort, true><<<dim3(4, 16, 4), 512, 0, stream>>>(
        E, 2048, 2048LL * 2048, Vtb, 2048, 1024LL * 2048,
        Ob, 1024, 2048LL * 1024, 2048, Zi);

    // 7. out = O @ Wout^T -> fp32   (256 blocks = 1 wave)
    gemm_bm128<float, false><<<dim3(4, 64, 1), 512, 0, stream>>>(
        Ob, 1024, 0, wob, 1024, 0, out, 1024, 0, 1024, nullptr);
}

// Round 7
// 204.580 us; speedup vs baseline: 1.0259x; 1.0259x over previous
//
#include <hip/hip_runtime.h>

typedef unsigned int uint;
typedef unsigned short ushort;
typedef __bf16 bf16x8 __attribute__((ext_vector_type(8)));
typedef float f32x4 __attribute__((ext_vector_type(4)));

__device__ __forceinline__ ushort f2bf(float v) {
    uint u = __builtin_bit_cast(uint, v);
    u += 0x7fffu + ((u >> 16) & 1u);   // RNE
    return (ushort)(u >> 16);
}

// 4 consecutive elements at p (vectorized epilogue stores)
__device__ __forceinline__ void store4(float* p, const f32x4 v) { *(f32x4*)p = v; }
__device__ __forceinline__ void store4(ushort* p, const f32x4 v) {
    uint2 r;
    r.x = (uint)f2bf(v[0]) | ((uint)f2bf(v[1]) << 16);
    r.y = (uint)f2bf(v[2]) | ((uint)f2bf(v[3]) << 16);
    *(uint2*)p = r;
}

#define GLDS(g, l) __builtin_amdgcn_global_load_lds( \
    (const __attribute__((address_space(1))) uint*)(g), \
    (__attribute__((address_space(3))) uint*)(l), 16, 0, 0)

#define VMW(N)  asm volatile("s_waitcnt vmcnt(" #N ")" ::: "memory")
#define SBAR()  asm volatile("s_barrier" ::: "memory")

// T1: bijective XCD swizzle (m204). Requires nwg % 8 == 0 (all our grids).
// Hardware runs linear block id round-robin over 8 XCDs; remap so each XCD
// owns a CONTIGUOUS chunk of tile-space -> panel-sharing neighbors co-locate
// in one XCD's L2.
struct Tile3 { int bx, by, bz; };
__device__ __forceinline__ Tile3 xcd_swizzle()
{
    const int gx = gridDim.x, gy = gridDim.y;
    const int nwg = gx * gy * gridDim.z;
    const int id  = blockIdx.x + gx * (blockIdx.y + gy * blockIdx.z);
    const int wg  = (id & 7) * (nwg >> 3) + (id >> 3);
    Tile3 t;
    t.bx = wg % gx;
    const int tmp = wg / gx;
    t.by = tmp % gy;
    t.bz = tmp / gy;
    return t;
}

// Stage 128 rows x 64 cols bf16 (16KB) = one half-tile = 2 gload_lds/thread.
// LDS swizzle: 16B-slot s of row r stored at slot s^(r&7); pre-swizzled
// GLOBAL source (linear LDS dest, rule #21); reads apply the same XOR.
__device__ __forceinline__ void stage_half(const ushort* __restrict__ src, int ld,
                                           int halfrow, char* ldsbase, int tid)
{
#pragma unroll
    for (int i = 0; i < 2; i++) {
        const int byte = i * 8192 + tid * 16;
        const int row  = byte >> 7;
        const int slot = (byte >> 4) & 7;
        const int srcs = slot ^ (row & 7);
        GLDS(src + (long long)(halfrow + row) * ld + srcs * 8,
             ldsbase + halfrow * 128 + byte);
    }
}

__device__ __forceinline__ bf16x8 ldf(const char* base, int rbase, int ks,
                                      int lrow, int lquad)
{
    const int r    = rbase + lrow;
    const int slot = ((ks << 2) + lquad) ^ (r & 7);
    return *(const bf16x8*)(base + r * 128 + slot * 16);
}

#define RD_A(BASE, ROFF) \
    _Pragma("unroll") for (int m_ = 0; m_ < 4; m_++) \
    _Pragma("unroll") for (int k_ = 0; k_ < 2; k_++) \
        af[m_][k_] = ldf(BASE, (ROFF) + m_ * 16, k_, lrow, lquad);

#define RD_B(DST, BASE, ROFF) \
    _Pragma("unroll") for (int n_ = 0; n_ < 2; n_++) \
    _Pragma("unroll") for (int k_ = 0; k_ < 2; k_++) \
        DST[n_][k_] = ldf(BASE, (ROFF) + n_ * 16, k_, lrow, lquad);

// OPERAND-SWAPPED MFMA: mfma(B, A) computes C^T in regs; per verified D-layout
// (col=lane&15, row=lquad*4+reg) each lane then holds C-row = frag_row + lrow,
// C-cols = frag_col + lquad*4 + {0..3}  -> 4 CONSECUTIVE cols = one 8/16B store.
#define QUAD(MOFF, NOFF, B) \
    __builtin_amdgcn_s_setprio(1); \
    _Pragma("unroll") for (int m_ = 0; m_ < 4; m_++) \
    _Pragma("unroll") for (int n_ = 0; n_ < 2; n_++) \
    _Pragma("unroll") for (int k_ = 0; k_ < 2; k_++) \
        acc[(MOFF) + m_][(NOFF) + n_] = __builtin_amdgcn_mfma_f32_16x16x32_bf16( \
            B[n_][k_], af[m_][k_], acc[(MOFF) + m_][(NOFF) + n_], 0, 0, 0); \
    __builtin_amdgcn_s_setprio(0);

// ---------------------------------------------------------------------------
// gemm256_8ph: 256x256 tile, BK=64, m201-faithful 8-phase (verified round 5).
// EXP epilogue: e=exp(acc*scale) -> bf16, per-wave 64-col row sums -> Zp.
// ---------------------------------------------------------------------------
template<bool EXP>
__global__ __launch_bounds__(512, 2)
void gemm256_8ph(const ushort* __restrict__ A, int lda, long long bsA,
                 const ushort* __restrict__ Bt, int ldb, long long bsB,
                 ushort* __restrict__ C, int ldc, long long bsC,
                 int K, float scale, float* __restrict__ Zp)
{
    __shared__ char smem[131072];
    char* A0 = smem;
    char* A1 = smem + 32768;
    char* B0 = smem + 65536;
    char* B1 = smem + 98304;

    const Tile3 t3 = xcd_swizzle();

    const int tid   = threadIdx.x;
    const int lane  = tid & 63;
    const int wave  = tid >> 6;
    const int wr    = wave >> 2;
    const int wc    = wave & 3;
    const int lrow  = lane & 15;
    const int lquad = lane >> 4;
    const long long b = t3.bz;

    const ushort* Ag = A  + b * bsA + (long long)t3.by * 256 * lda;
    const ushort* Bg = Bt + b * bsB + (long long)t3.bx * 256 * ldb;
    ushort*       Cg = C  + b * bsC + (long long)t3.by * 256 * ldc
                           + (long long)t3.bx * 256;

    f32x4 acc[8][4] = {};
    bf16x8 af[4][2], bl[2][2], bh[2][2];

    const int nk    = K >> 6;
    const int nIter = nk >> 1;

    stage_half(Ag,      lda, 0,   A0, tid);
    stage_half(Bg,      ldb, 0,   B0, tid);
    stage_half(Bg,      ldb, 128, B0, tid);
    stage_half(Ag,      lda, 128, A0, tid);
    stage_half(Ag + 64, lda, 0,   A1, tid);
    stage_half(Bg + 64, ldb, 0,   B1, tid);
    stage_half(Bg + 64, ldb, 128, B1, tid);
    VMW(6); SBAR();

    for (int i = 0; i < nIter - 1; ++i) {
        const ushort* An1 = Ag + (2 * i + 1) * 64;
        const ushort* An2 = Ag + (2 * i + 2) * 64;
        const ushort* Bn2 = Bg + (2 * i + 2) * 64;
        const ushort* An3 = Ag + (2 * i + 3) * 64;
        const ushort* Bn3 = Bg + (2 * i + 3) * 64;

        RD_A(A0, wr * 64); RD_B(bl, B0, wc * 32);
        stage_half(An1, lda, 128, A1, tid);
        SBAR(); QUAD(0, 0, bl); SBAR();

        RD_B(bh, B0, 128 + wc * 32);
        stage_half(An2, lda, 0, A0, tid);
        SBAR(); QUAD(0, 2, bh); SBAR();

        RD_A(A0, 128 + wr * 64);
        stage_half(Bn2, ldb, 0, B0, tid);
        SBAR(); QUAD(4, 0, bl); SBAR();

        stage_half(Bn2, ldb, 128, B0, tid);
        SBAR(); QUAD(4, 2, bh); VMW(6); SBAR();

        RD_A(A1, wr * 64); RD_B(bl, B1, wc * 32);
        stage_half(An2, lda, 128, A0, tid);
        SBAR(); QUAD(0, 0, bl); SBAR();

        RD_B(bh, B1, 128 + wc * 32);
        stage_half(An3, lda, 0, A1, tid);
        SBAR(); QUAD(0, 2, bh); SBAR();

        RD_A(A1, 128 + wr * 64);
        stage_half(Bn3, ldb, 0, B1, tid);
        SBAR(); QUAD(4, 0, bl); SBAR();

        stage_half(Bn3, ldb, 128, B1, tid);
        SBAR(); QUAD(4, 2, bh); VMW(6); SBAR();
    }

    {
        const ushort* An1 = Ag + (nk - 1) * 64;

        RD_A(A0, wr * 64); RD_B(bl, B0, wc * 32);
        stage_half(An1, lda, 128, A1, tid);
        SBAR(); QUAD(0, 0, bl); SBAR();

        RD_B(bh, B0, 128 + wc * 32);
        SBAR(); QUAD(0, 2, bh); SBAR();

        RD_A(A0, 128 + wr * 64);
        SBAR(); QUAD(4, 0, bl); SBAR();

        SBAR(); QUAD(4, 2, bh); VMW(0); SBAR();

        RD_A(A1, wr * 64); RD_B(bl, B1, wc * 32);
        SBAR(); QUAD(0, 0, bl); SBAR();

        RD_B(bh, B1, 128 + wc * 32);
        SBAR(); QUAD(0, 2, bh); SBAR();

        RD_A(A1, 128 + wr * 64);
        SBAR(); QUAD(4, 0, bl); SBAR();

        SBAR(); QUAD(4, 2, bh);
    }

    // vectorized epilogue (swapped layout): row = frag_row + lrow,
    // col = frag_col + lquad*4 + j  (4 consecutive -> one uint2 store)
#pragma unroll
    for (int m = 0; m < 8; m++) {
        const int row = (m >> 2) * 128 + wr * 64 + (m & 3) * 16 + lrow;
        float rs = 0.f;
#pragma unroll
        for (int n = 0; n < 4; n++) {
            const int col = (n >> 1) * 128 + wc * 32 + (n & 1) * 16 + lquad * 4;
            f32x4 v = acc[m][n];
            if (EXP) {
#pragma unroll
                for (int j = 0; j < 4; j++) { v[j] = __expf(v[j] * scale); rs += v[j]; }
            }
            store4(&Cg[(long long)row * ldc + col], v);
        }
        if (EXP) {
            rs += __shfl_xor(rs, 16);
            rs += __shfl_xor(rs, 32);   // all lquads of this lrow now hold wave row-sum
            if (lquad == 0) {
                const long long zi = ((long long)b * 32 + t3.bx * 4 + wc) * 2048
                                   + (long long)t3.by * 256 + row;
                Zp[zi] = rs;
            }
        }
    }
}

// ---------------------------------------------------------------------------
// gemm128: 256x128 tile, BK=64, 2-phase counted-vmcnt (verified round 4).
// ---------------------------------------------------------------------------
template<typename OUT_T>
__global__ __launch_bounds__(512, 2)
void gemm128(const ushort* __restrict__ A, int lda, long long bsA,
             const ushort* __restrict__ Bt, int ldb, long long bsB,
             OUT_T* __restrict__ C, int ldc, long long bsC, int K)
{
    __shared__ char smem[98304];

    const Tile3 t3 = xcd_swizzle();

    const int tid   = threadIdx.x;
    const int lane  = tid & 63;
    const int wave  = tid >> 6;
    const int wr    = wave >> 2;
    const int wc    = wave & 3;
    const int lrow  = lane & 15;
    const int lquad = lane >> 4;
    const long long b = t3.bz;

    const ushort* Ag = A  + b * bsA + (long long)t3.by * 256 * lda;
    const ushort* Bg = Bt + b * bsB + (long long)t3.bx * 128 * ldb;
    OUT_T*        Cg = C  + b * bsC + (long long)t3.by * 256 * ldc
                           + (long long)t3.bx * 128;

    f32x4 acc[8][2] = {};
    bf16x8 af[4][2], bfr[2][2];

    const int nk = K >> 6;

    stage_half(Ag, lda, 0,   smem,         tid);
    stage_half(Bg, ldb, 0,   smem + 65536, tid);
    stage_half(Ag, lda, 128, smem,         tid);
    VMW(2); SBAR();

    for (int t = 0; t < nk - 1; ++t) {
        const int cur = t & 1;
        const char* lAc = smem + cur * 32768;
        const char* lBc = smem + 65536 + cur * 16384;
        char* lAn = smem + (cur ^ 1) * 32768;
        char* lBn = smem + 65536 + (cur ^ 1) * 16384;
        const ushort* An = Ag + (t + 1) * 64;
        const ushort* Bn = Bg + (t + 1) * 64;

        RD_A(lAc, wr * 64);
        RD_B(bfr, lBc, wc * 32);
        stage_half(An, lda, 0, lAn, tid);
        stage_half(Bn, ldb, 0, lBn, tid);
        SBAR();
        QUAD(0, 0, bfr);
        VMW(4); SBAR();

        RD_A(lAc, 128 + wr * 64);
        stage_half(An, lda, 128, lAn, tid);
        SBAR();
        QUAD(4, 0, bfr);
        VMW(2); SBAR();
    }

    {
        const int cur = (nk - 1) & 1;
        const char* lAc = smem + cur * 32768;
        const char* lBc = smem + 65536 + cur * 16384;

        RD_A(lAc, wr * 64);
        RD_B(bfr, lBc, wc * 32);
        SBAR();
        QUAD(0, 0, bfr);
        VMW(0); SBAR();

        RD_A(lAc, 128 + wr * 64);
        SBAR();
        QUAD(4, 0, bfr);
    }

#pragma unroll
    for (int m = 0; m < 8; m++) {
        const int row = (m >> 2) * 128 + wr * 64 + (m & 3) * 16 + lrow;
#pragma unroll
        for (int n = 0; n < 2; n++) {
            const int col = wc * 32 + n * 16 + lquad * 4;
            store4(&Cg[(long long)row * ldc + col], acc[m][n]);
        }
    }
}

// ---------------------------------------------------------------------------
// gemm_bm128: 128x256 tile, BK=64 (verified round 5 structure).
// ---------------------------------------------------------------------------
template<typename OUT_T, bool ZSCALE>
__global__ __launch_bounds__(512, 2)
void gemm_bm128(const ushort* __restrict__ A, int lda, long long bsA,
                const ushort* __restrict__ Bt, int ldb, long long bsB,
                OUT_T* __restrict__ C, int ldc, long long bsC,
                int K, const float* __restrict__ zinv)
{
    __shared__ char smem[98304];

    const Tile3 t3 = xcd_swizzle();

    const int tid   = threadIdx.x;
    const int lane  = tid & 63;
    const int wave  = tid >> 6;
    const int wr    = wave >> 2;
    const int wc    = wave & 3;
    const int lrow  = lane & 15;
    const int lquad = lane >> 4;
    const long long b = t3.bz;

    const ushort* Ag = A  + b * bsA + (long long)t3.by * 128 * lda;
    const ushort* Bg = Bt + b * bsB + (long long)t3.bx * 256 * ldb;
    OUT_T*        Cg = C  + b * bsC + (long long)t3.by * 128 * ldc
                           + (long long)t3.bx * 256;

    f32x4 acc[4][4] = {};
    bf16x8 af[4][2], bl[2][2], bh[2][2];

    const int nk = K >> 6;

    stage_half(Ag, lda, 0,   smem,         tid);
    stage_half(Bg, ldb, 0,   smem + 32768, tid);
    stage_half(Bg, ldb, 128, smem + 32768, tid);
    VMW(2); SBAR();

    for (int t = 0; t < nk - 1; ++t) {
        const int cur = t & 1;
        const char* lAc = smem + cur * 16384;
        const char* lBc = smem + 32768 + cur * 32768;
        char* lAn = smem + (cur ^ 1) * 16384;
        char* lBn = smem + 32768 + (cur ^ 1) * 32768;
        const ushort* An = Ag + (t + 1) * 64;
        const ushort* Bn = Bg + (t + 1) * 64;

        RD_A(lAc, wr * 64);
        RD_B(bl, lBc, wc * 32);
        stage_half(An, lda, 0, lAn, tid);
        stage_half(Bn, ldb, 0, lBn, tid);
        SBAR();
        QUAD(0, 0, bl);
        VMW(4); SBAR();

        RD_B(bh, lBc, 128 + wc * 32);
        stage_half(Bn, ldb, 128, lBn, tid);
        SBAR();
        QUAD(0, 2, bh);
        VMW(2); SBAR();
    }

    {
        const int cur = (nk - 1) & 1;
        const char* lAc = smem + cur * 16384;
        const char* lBc = smem + 32768 + cur * 32768;

        RD_A(lAc, wr * 64);
        RD_B(bl, lBc, wc * 32);
        SBAR();
        QUAD(0, 0, bl);
        VMW(0); SBAR();

        RD_B(bh, lBc, 128 + wc * 32);
        SBAR();
        QUAD(0, 2, bh);
    }

#pragma unroll
    for (int m = 0; m < 4; m++) {
        const int row = wr * 64 + m * 16 + lrow;
        float z = 1.f;
        if (ZSCALE) z = zinv[b * 2048 + (long long)t3.by * 128 + row];
#pragma unroll
        for (int n = 0; n < 4; n++) {
            const int col = (n >> 1) * 128 + wc * 32 + (n & 1) * 16 + lquad * 4;
            f32x4 v = acc[m][n];
            if (ZSCALE) {
#pragma unroll
                for (int j = 0; j < 4; j++) v[j] *= z;
            }
            store4(&Cg[(long long)row * ldc + col], v);
        }
    }
}

// ---------------------------------------------------------------------------
__global__ __launch_bounds__(256)
void f32_to_bf16_vec(const float* __restrict__ in, ushort* __restrict__ out, int n4)
{
    int i = blockIdx.x * 256 + threadIdx.x;
    if (i >= n4) return;
    float4 v = ((const float4*)in)[i];
    ushort o[4] = { f2bf(v.x), f2bf(v.y), f2bf(v.z), f2bf(v.w) };
    *(uint2*)&out[(size_t)i * 4] = *(const uint2*)&o[0];
}

// ---------------------------------------------------------------------------
__global__ __launch_bounds__(256)
void zinv_k(const float* __restrict__ zp, float* __restrict__ zi)
{
    const int t = blockIdx.x * 256 + threadIdx.x;   // 0..8191
    const int b = t >> 11, r = t & 2047;
    const float* p = zp + (long long)b * 32 * 2048 + r;
    float s = 0.f;
#pragma unroll
    for (int i = 0; i < 32; i++) s += p[i * 2048];
    zi[t] = 1.0f / s;
}

// ---------------------------------------------------------------------------
__global__ __launch_bounds__(256)
void transpose_v(const ushort* __restrict__ V, int ldv, long long bsV,
                 ushort* __restrict__ Vt)
{
    __shared__ ushort t[64][65];
    const int b = blockIdx.z;
    const ushort* src = V  + (size_t)b * bsV;
    ushort*       dst = Vt + (size_t)b * 1024 * 2048;
    const int e0 = blockIdx.x * 64;
    const int k0 = blockIdx.y * 64;
    const int r = threadIdx.x >> 2;
    const int c = (threadIdx.x & 3) * 16;

    const ushort* p = &src[(size_t)(k0 + r) * ldv + e0 + c];
    ushort vals[16];
    *(uint4*)&vals[0] = *(const uint4*)p;
    *(uint4*)&vals[8] = *(const uint4*)(p + 8);
#pragma unroll
    for (int j = 0; j < 16; j++) t[r][c + j] = vals[j];
    __syncthreads();

    ushort o[16];
#pragma unroll
    for (int j = 0; j < 16; j++) o[j] = t[c + j][r];
    ushort* q = &dst[(size_t)(e0 + r) * 2048 + k0 + c];
    *(uint4*)q       = *(const uint4*)&o[0];
    *(uint4*)(q + 8) = *(const uint4*)&o[8];
}

// ---------------------------------------------------------------------------
extern "C" void kernel_launch(void* const* d_in, const int* in_sizes, int n_in,
                              void* d_out, int out_size, void* d_ws, size_t ws_size,
                              hipStream_t stream)
{
    const float* x  = (const float*)d_in[0];
    const float* wq = (const float*)d_in[1];
    const float* wk = (const float*)d_in[2];
    const float* wv = (const float*)d_in[3];
    const float* wo = (const float*)d_in[4];
    float* out = (float*)d_out;

    // B=4, S=2048, D=1024; M = 8192
    char* ws = (char*)d_ws;
    ushort* xb    = (ushort*)(ws);                 // 16 MB  [8192][1024]
    ushort* wqkv  = (ushort*)(ws + 16777216);      //  6 MB  [3072][1024]
    ushort* wob   = (ushort*)(ws + 23068672);      //  2 MB  [1024][1024]
    ushort* QKVb  = (ushort*)(ws + 25165824);      // 48 MB  [8192][3072]
    ushort* Vtb   = (ushort*)(ws + 75497472);      // 16 MB  [4][1024][2048]
    ushort* Ob    = (ushort*)(ws + 92274688);      // 16 MB  [8192][1024]
    ushort* E     = (ushort*)(ws + 109051904);     // 32 MB  [4][2048][2048] bf16
    float*  Zp    = (float*)(ws + 142606336);      //  1 MB  [4][32][2048]
    float*  Zi    = (float*)(ws + 143654912);      // 32 KB  [4][2048]

    // 1. converts (wq/wk/wv packed into one [3072][1024])
    f32_to_bf16_vec<<<8192, 256, 0, stream>>>(x,  xb,   2097152);
    f32_to_bf16_vec<<<1024, 256, 0, stream>>>(wq, wqkv,           262144);
    f32_to_bf16_vec<<<1024, 256, 0, stream>>>(wk, wqkv + 1048576, 262144);
    f32_to_bf16_vec<<<1024, 256, 0, stream>>>(wv, wqkv + 2097152, 262144);
    f32_to_bf16_vec<<<1024, 256, 0, stream>>>(wo, wob,            262144);

    // 2. fused QKV projection: [8192][3072] = xb @ wqkv^T  (768 blocks = 3 exact waves)
    gemm128<ushort><<<dim3(24, 32, 1), 512, 0, stream>>>(
        xb, 1024, 0, wqkv, 1024, 0, QKVb, 3072, 0, 1024);

    // 3. V^T per batch -> [b][1024][2048]
    transpose_v<<<dim3(16, 32, 4), 256, 0, stream>>>(QKVb + 2048, 3072, 2048LL * 3072, Vtb);

    // 4. E = exp(Q K^T / 32) bf16 + row-sum partials   (256 blocks = 1 wave)
    gemm256_8ph<true><<<dim3(8, 8, 4), 512, 0, stream>>>(
        QKVb, 3072, 2048LL * 3072, QKVb + 1024, 3072, 2048LL * 3072,
        E, 2048, 2048LL * 2048, 1024, 0.03125f, Zp);

    // 5. Zi = 1 / rowsum
    zinv_k<<<32, 256, 0, stream>>>(Zp, Zi);

    // 6. O = (E @ V) * Zi   (256 blocks = 1 wave)
    gemm_bm128<ushort, true><<<dim3(4, 16, 4), 512, 0, stream>>>(
        E, 2048, 2048LL * 2048, Vtb, 2048, 1024LL * 2048,
        Ob, 1024, 2048LL * 1024, 2048, Zi);

    // 7. out = O @ Wout^T -> fp32   (256 blocks = 1 wave)
    gemm_bm128<float, false><<<dim3(4, 64, 1), 512, 0, stream>>>(
        Ob, 1024, 0, wob, 1024, 0, out, 1024, 0, 1024, nullptr);
}

// Round 8
// 203.815 us; speedup vs baseline: 1.0298x; 1.0038x over previous
//
#include <hip/hip_runtime.h>

typedef unsigned int uint;
typedef unsigned short ushort;
typedef __bf16 bf16x8 __attribute__((ext_vector_type(8)));
typedef float f32x4 __attribute__((ext_vector_type(4)));

__device__ __forceinline__ ushort f2bf(float v) {
    uint u = __builtin_bit_cast(uint, v);
    u += 0x7fffu + ((u >> 16) & 1u);   // RNE
    return (ushort)(u >> 16);
}

__device__ __forceinline__ void store4(float* p, const f32x4 v) { *(f32x4*)p = v; }
__device__ __forceinline__ void store4(ushort* p, const f32x4 v) {
    uint2 r;
    r.x = (uint)f2bf(v[0]) | ((uint)f2bf(v[1]) << 16);
    r.y = (uint)f2bf(v[2]) | ((uint)f2bf(v[3]) << 16);
    *(uint2*)p = r;
}

#define GLDS(g, l) __builtin_amdgcn_global_load_lds( \
    (const __attribute__((address_space(1))) uint*)(g), \
    (__attribute__((address_space(3))) uint*)(l), 16, 0, 0)

#define VMW(N)  asm volatile("s_waitcnt vmcnt(" #N ")" ::: "memory")
#define SBAR()  asm volatile("s_barrier" ::: "memory")

// Stage 128 rows x 64 cols bf16 (16KB) = one half-tile = 2 gload_lds/thread.
// LDS swizzle: 16B-slot s of row r stored at slot s^(r&7); pre-swizzled
// GLOBAL source (linear LDS dest, rule #21); reads apply the same XOR.
__device__ __forceinline__ void stage_half(const ushort* __restrict__ src, int ld,
                                           int halfrow, char* ldsbase, int tid)
{
#pragma unroll
    for (int i = 0; i < 2; i++) {
        const int byte = i * 8192 + tid * 16;
        const int row  = byte >> 7;
        const int slot = (byte >> 4) & 7;
        const int srcs = slot ^ (row & 7);
        GLDS(src + (long long)(halfrow + row) * ld + srcs * 8,
             ldsbase + halfrow * 128 + byte);
    }
}

__device__ __forceinline__ bf16x8 ldf(const char* base, int rbase, int ks,
                                      int lrow, int lquad)
{
    const int r    = rbase + lrow;
    const int slot = ((ks << 2) + lquad) ^ (r & 7);
    return *(const bf16x8*)(base + r * 128 + slot * 16);
}

#define RD_A(BASE, ROFF) \
    _Pragma("unroll") for (int m_ = 0; m_ < 4; m_++) \
    _Pragma("unroll") for (int k_ = 0; k_ < 2; k_++) \
        af[m_][k_] = ldf(BASE, (ROFF) + m_ * 16, k_, lrow, lquad);

#define RD_B(DST, BASE, ROFF) \
    _Pragma("unroll") for (int n_ = 0; n_ < 2; n_++) \
    _Pragma("unroll") for (int k_ = 0; k_ < 2; k_++) \
        DST[n_][k_] = ldf(BASE, (ROFF) + n_ * 16, k_, lrow, lquad);

// OPERAND-SWAPPED MFMA: mfma(B, A) computes C^T in regs; per verified D-layout
// each lane holds C-row = frag_row + lrow, C-cols = frag_col + lquad*4 + {0..3}
// -> 4 CONSECUTIVE cols = one 8/16B store.
#define QUAD(MOFF, NOFF, B) \
    __builtin_amdgcn_s_setprio(1); \
    _Pragma("unroll") for (int m_ = 0; m_ < 4; m_++) \
    _Pragma("unroll") for (int n_ = 0; n_ < 2; n_++) \
    _Pragma("unroll") for (int k_ = 0; k_ < 2; k_++) \
        acc[(MOFF) + m_][(NOFF) + n_] = __builtin_amdgcn_mfma_f32_16x16x32_bf16( \
            B[n_][k_], af[m_][k_], acc[(MOFF) + m_][(NOFF) + n_], 0, 0, 0); \
    __builtin_amdgcn_s_setprio(0);

// ---------------------------------------------------------------------------
// gemm256_8ph: 256x256 tile, BK=64, 8-phase (verified R5/R6/R7).
// EXP epilogue: e=exp(acc*scale) -> bf16, per-wave 64-col row sums -> Zp.
// ---------------------------------------------------------------------------
template<bool EXP>
__global__ __launch_bounds__(512, 2)
void gemm256_8ph(const ushort* __restrict__ A, int lda, long long bsA,
                 const ushort* __restrict__ Bt, int ldb, long long bsB,
                 ushort* __restrict__ C, int ldc, long long bsC,
                 int K, float scale, float* __restrict__ Zp)
{
    __shared__ char smem[131072];
    char* A0 = smem;
    char* A1 = smem + 32768;
    char* B0 = smem + 65536;
    char* B1 = smem + 98304;

    const int tid   = threadIdx.x;
    const int lane  = tid & 63;
    const int wave  = tid >> 6;
    const int wr    = wave >> 2;
    const int wc    = wave & 3;
    const int lrow  = lane & 15;
    const int lquad = lane >> 4;
    const long long b = blockIdx.z;

    const ushort* Ag = A  + b * bsA + (long long)blockIdx.y * 256 * lda;
    const ushort* Bg = Bt + b * bsB + (long long)blockIdx.x * 256 * ldb;
    ushort*       Cg = C  + b * bsC + (long long)blockIdx.y * 256 * ldc
                           + (long long)blockIdx.x * 256;

    f32x4 acc[8][4] = {};
    bf16x8 af[4][2], bl[2][2], bh[2][2];

    const int nk    = K >> 6;
    const int nIter = nk >> 1;

    stage_half(Ag,      lda, 0,   A0, tid);
    stage_half(Bg,      ldb, 0,   B0, tid);
    stage_half(Bg,      ldb, 128, B0, tid);
    stage_half(Ag,      lda, 128, A0, tid);
    stage_half(Ag + 64, lda, 0,   A1, tid);
    stage_half(Bg + 64, ldb, 0,   B1, tid);
    stage_half(Bg + 64, ldb, 128, B1, tid);
    VMW(6); SBAR();

    for (int i = 0; i < nIter - 1; ++i) {
        const ushort* An1 = Ag + (2 * i + 1) * 64;
        const ushort* An2 = Ag + (2 * i + 2) * 64;
        const ushort* Bn2 = Bg + (2 * i + 2) * 64;
        const ushort* An3 = Ag + (2 * i + 3) * 64;
        const ushort* Bn3 = Bg + (2 * i + 3) * 64;

        RD_A(A0, wr * 64); RD_B(bl, B0, wc * 32);
        stage_half(An1, lda, 128, A1, tid);
        SBAR(); QUAD(0, 0, bl); SBAR();

        RD_B(bh, B0, 128 + wc * 32);
        stage_half(An2, lda, 0, A0, tid);
        SBAR(); QUAD(0, 2, bh); SBAR();

        RD_A(A0, 128 + wr * 64);
        stage_half(Bn2, ldb, 0, B0, tid);
        SBAR(); QUAD(4, 0, bl); SBAR();

        stage_half(Bn2, ldb, 128, B0, tid);
        SBAR(); QUAD(4, 2, bh); VMW(6); SBAR();

        RD_A(A1, wr * 64); RD_B(bl, B1, wc * 32);
        stage_half(An2, lda, 128, A0, tid);
        SBAR(); QUAD(0, 0, bl); SBAR();

        RD_B(bh, B1, 128 + wc * 32);
        stage_half(An3, lda, 0, A1, tid);
        SBAR(); QUAD(0, 2, bh); SBAR();

        RD_A(A1, 128 + wr * 64);
        stage_half(Bn3, ldb, 0, B1, tid);
        SBAR(); QUAD(4, 0, bl); SBAR();

        stage_half(Bn3, ldb, 128, B1, tid);
        SBAR(); QUAD(4, 2, bh); VMW(6); SBAR();
    }

    {
        const ushort* An1 = Ag + (nk - 1) * 64;

        RD_A(A0, wr * 64); RD_B(bl, B0, wc * 32);
        stage_half(An1, lda, 128, A1, tid);
        SBAR(); QUAD(0, 0, bl); SBAR();

        RD_B(bh, B0, 128 + wc * 32);
        SBAR(); QUAD(0, 2, bh); SBAR();

        RD_A(A0, 128 + wr * 64);
        SBAR(); QUAD(4, 0, bl); SBAR();

        SBAR(); QUAD(4, 2, bh); VMW(0); SBAR();

        RD_A(A1, wr * 64); RD_B(bl, B1, wc * 32);
        SBAR(); QUAD(0, 0, bl); SBAR();

        RD_B(bh, B1, 128 + wc * 32);
        SBAR(); QUAD(0, 2, bh); SBAR();

        RD_A(A1, 128 + wr * 64);
        SBAR(); QUAD(4, 0, bl); SBAR();

        SBAR(); QUAD(4, 2, bh);
    }

#pragma unroll
    for (int m = 0; m < 8; m++) {
        const int row = (m >> 2) * 128 + wr * 64 + (m & 3) * 16 + lrow;
        float rs = 0.f;
#pragma unroll
        for (int n = 0; n < 4; n++) {
            const int col = (n >> 1) * 128 + wc * 32 + (n & 1) * 16 + lquad * 4;
            f32x4 v = acc[m][n];
            if (EXP) {
#pragma unroll
                for (int j = 0; j < 4; j++) { v[j] = __expf(v[j] * scale); rs += v[j]; }
            }
            store4(&Cg[(long long)row * ldc + col], v);
        }
        if (EXP) {
            rs += __shfl_xor(rs, 16);
            rs += __shfl_xor(rs, 32);
            if (lquad == 0) {
                const long long zi = ((long long)b * 32 + blockIdx.x * 4 + wc) * 2048
                                   + (long long)blockIdx.y * 256 + row;
                Zp[zi] = rs;
            }
        }
    }
}

// ---------------------------------------------------------------------------
// gemm_bm128: 128x256 tile, BK=64 (verified R6/R7). ZSCALE: v *= zinv[row].
// ---------------------------------------------------------------------------
template<typename OUT_T, bool ZSCALE>
__global__ __launch_bounds__(512, 2)
void gemm_bm128(const ushort* __restrict__ A, int lda, long long bsA,
                const ushort* __restrict__ Bt, int ldb, long long bsB,
                OUT_T* __restrict__ C, int ldc, long long bsC,
                int K, const float* __restrict__ zinv)
{
    __shared__ char smem[98304];

    const int tid   = threadIdx.x;
    const int lane  = tid & 63;
    const int wave  = tid >> 6;
    const int wr    = wave >> 2;
    const int wc    = wave & 3;
    const int lrow  = lane & 15;
    const int lquad = lane >> 4;
    const long long b = blockIdx.z;

    const ushort* Ag = A  + b * bsA + (long long)blockIdx.y * 128 * lda;
    const ushort* Bg = Bt + b * bsB + (long long)blockIdx.x * 256 * ldb;
    OUT_T*        Cg = C  + b * bsC + (long long)blockIdx.y * 128 * ldc
                           + (long long)blockIdx.x * 256;

    f32x4 acc[4][4] = {};
    bf16x8 af[4][2], bl[2][2], bh[2][2];

    const int nk = K >> 6;

    stage_half(Ag, lda, 0,   smem,         tid);
    stage_half(Bg, ldb, 0,   smem + 32768, tid);
    stage_half(Bg, ldb, 128, smem + 32768, tid);
    VMW(2); SBAR();

    for (int t = 0; t < nk - 1; ++t) {
        const int cur = t & 1;
        const char* lAc = smem + cur * 16384;
        const char* lBc = smem + 32768 + cur * 32768;
        char* lAn = smem + (cur ^ 1) * 16384;
        char* lBn = smem + 32768 + (cur ^ 1) * 32768;
        const ushort* An = Ag + (t + 1) * 64;
        const ushort* Bn = Bg + (t + 1) * 64;

        RD_A(lAc, wr * 64);
        RD_B(bl, lBc, wc * 32);
        stage_half(An, lda, 0, lAn, tid);
        stage_half(Bn, ldb, 0, lBn, tid);
        SBAR();
        QUAD(0, 0, bl);
        VMW(4); SBAR();

        RD_B(bh, lBc, 128 + wc * 32);
        stage_half(Bn, ldb, 128, lBn, tid);
        SBAR();
        QUAD(0, 2, bh);
        VMW(2); SBAR();
    }

    {
        const int cur = (nk - 1) & 1;
        const char* lAc = smem + cur * 16384;
        const char* lBc = smem + 32768 + cur * 32768;

        RD_A(lAc, wr * 64);
        RD_B(bl, lBc, wc * 32);
        SBAR();
        QUAD(0, 0, bl);
        VMW(0); SBAR();

        RD_B(bh, lBc, 128 + wc * 32);
        SBAR();
        QUAD(0, 2, bh);
    }

#pragma unroll
    for (int m = 0; m < 4; m++) {
        const int row = wr * 64 + m * 16 + lrow;
        float z = 1.f;
        if (ZSCALE) z = zinv[b * 2048 + (long long)blockIdx.y * 128 + row];
#pragma unroll
        for (int n = 0; n < 4; n++) {
            const int col = (n >> 1) * 128 + wc * 32 + (n & 1) * 16 + lquad * 4;
            f32x4 v = acc[m][n];
            if (ZSCALE) {
#pragma unroll
                for (int j = 0; j < 4; j++) v[j] *= z;
            }
            store4(&Cg[(long long)row * ldc + col], v);
        }
    }
}

// ---------------------------------------------------------------------------
// gemm_bt_small: R1-verified 128x128-tile, 256-thr, high-occupancy GEMM.
// C[m][n] = sum_k A[m][k] * Bt[n][k], bf16 out. Used only for Wvo (1024^3).
// ---------------------------------------------------------------------------
__global__ __launch_bounds__(256)
void gemm_bt_small(const ushort* __restrict__ A, int lda,
                   const ushort* __restrict__ Bt, int ldb,
                   ushort* __restrict__ C, int ldc, int K)
{
    __shared__ ushort lA[128 * 64];
    __shared__ ushort lB[128 * 64];

    const int tid  = threadIdx.x;
    const int lane = tid & 63;
    const int wave = tid >> 6;
    const int wr   = wave >> 1;
    const int wc   = wave & 1;

    A  += (long long)blockIdx.y * 128 * lda;
    Bt += (long long)blockIdx.x * 128 * ldb;
    C  += (long long)blockIdx.y * 128 * ldc + (long long)blockIdx.x * 128;

    f32x4 acc[4][4] = {};
    const int byte_base = wave * 1024 + lane * 16;

    for (int kt = 0; kt < K; kt += 64) {
#pragma unroll
        for (int i = 0; i < 4; i++) {
            const int byte = i * 4096 + byte_base;
            const int row  = byte >> 7;
            const int k0   = (byte & 127) >> 1;
            GLDS(A  + (long long)row * lda + kt + k0, (char*)lA + byte);
            GLDS(Bt + (long long)row * ldb + kt + k0, (char*)lB + byte);
        }
        __syncthreads();

#pragma unroll
        for (int ks = 0; ks < 2; ks++) {
            bf16x8 af2[4], bf2[4];
#pragma unroll
            for (int m = 0; m < 4; m++)
                af2[m] = *(const bf16x8*)&lA[(wr * 64 + m * 16 + (lane & 15)) * 64 + ks * 32 + (lane >> 4) * 8];
#pragma unroll
            for (int n = 0; n < 4; n++)
                bf2[n] = *(const bf16x8*)&lB[(wc * 64 + n * 16 + (lane & 15)) * 64 + ks * 32 + (lane >> 4) * 8];
#pragma unroll
            for (int m = 0; m < 4; m++)
#pragma unroll
                for (int n = 0; n < 4; n++)
                    acc[m][n] = __builtin_amdgcn_mfma_f32_16x16x32_bf16(af2[m], bf2[n], acc[m][n], 0, 0, 0);
        }
        __syncthreads();
    }

    const int r0 = wr * 64 + (lane >> 4) * 4;
    const int c0 = wc * 64 + (lane & 15);
#pragma unroll
    for (int m = 0; m < 4; m++)
#pragma unroll
        for (int n = 0; n < 4; n++)
#pragma unroll
            for (int j = 0; j < 4; j++)
                C[(long long)(r0 + m * 16 + j) * ldc + c0 + n * 16] = f2bf(acc[m][n][j]);
}

// ---------------------------------------------------------------------------
__global__ __launch_bounds__(256)
void f32_to_bf16_vec(const float* __restrict__ in, ushort* __restrict__ out, int n4)
{
    int i = blockIdx.x * 256 + threadIdx.x;
    if (i >= n4) return;
    float4 v = ((const float4*)in)[i];
    ushort o[4] = { f2bf(v.x), f2bf(v.y), f2bf(v.z), f2bf(v.w) };
    *(uint2*)&out[(size_t)i * 4] = *(const uint2*)&o[0];
}

// ---------------------------------------------------------------------------
// wv [1024][1024] fp32 -> wvT [1024][1024] bf16, wvT[j][k] = wv[k][j]
// ---------------------------------------------------------------------------
__global__ __launch_bounds__(256)
void tr_cvt(const float* __restrict__ src, ushort* __restrict__ dst)
{
    __shared__ float t[64][65];
    const int k0 = blockIdx.y * 64, j0 = blockIdx.x * 64;
    const int r = threadIdx.x >> 2;
    const int c = (threadIdx.x & 3) * 16;

    const float* p = src + (size_t)(k0 + r) * 1024 + j0 + c;
#pragma unroll
    for (int j = 0; j < 16; j++) t[r][c + j] = p[j];
    __syncthreads();

    ushort o[16];
#pragma unroll
    for (int j = 0; j < 16; j++) o[j] = f2bf(t[c + j][r]);
    ushort* q = dst + (size_t)(j0 + r) * 1024 + k0 + c;
    *(uint4*)q       = *(const uint4*)&o[0];
    *(uint4*)(q + 8) = *(const uint4*)&o[8];
}

// ---------------------------------------------------------------------------
__global__ __launch_bounds__(256)
void zinv_k(const float* __restrict__ zp, float* __restrict__ zi)
{
    const int t = blockIdx.x * 256 + threadIdx.x;
    const int b = t >> 11, r = t & 2047;
    const float* p = zp + (long long)b * 32 * 2048 + r;
    float s = 0.f;
#pragma unroll
    for (int i = 0; i < 32; i++) s += p[i * 2048];
    zi[t] = 1.0f / s;
}

// ---------------------------------------------------------------------------
__global__ __launch_bounds__(256)
void transpose_v(const ushort* __restrict__ V, int ldv, long long bsV,
                 ushort* __restrict__ Vt)
{
    __shared__ ushort t[64][65];
    const int b = blockIdx.z;
    const ushort* src = V  + (size_t)b * bsV;
    ushort*       dst = Vt + (size_t)b * 1024 * 2048;
    const int e0 = blockIdx.x * 64;
    const int k0 = blockIdx.y * 64;
    const int r = threadIdx.x >> 2;
    const int c = (threadIdx.x & 3) * 16;

    const ushort* p = &src[(size_t)(k0 + r) * ldv + e0 + c];
    ushort vals[16];
    *(uint4*)&vals[0] = *(const uint4*)p;
    *(uint4*)&vals[8] = *(const uint4*)(p + 8);
#pragma unroll
    for (int j = 0; j < 16; j++) t[r][c + j] = vals[j];
    __syncthreads();

    ushort o[16];
#pragma unroll
    for (int j = 0; j < 16; j++) o[j] = t[c + j][r];
    ushort* q = &dst[(size_t)(e0 + r) * 2048 + k0 + c];
    *(uint4*)q       = *(const uint4*)&o[0];
    *(uint4*)(q + 8) = *(const uint4*)&o[8];
}

// ---------------------------------------------------------------------------
extern "C" void kernel_launch(void* const* d_in, const int* in_sizes, int n_in,
                              void* d_out, int out_size, void* d_ws, size_t ws_size,
                              hipStream_t stream)
{
    const float* x  = (const float*)d_in[0];
    const float* wq = (const float*)d_in[1];
    const float* wk = (const float*)d_in[2];
    const float* wv = (const float*)d_in[3];
    const float* wo = (const float*)d_in[4];
    float* out = (float*)d_out;

    // B=4, S=2048, D=1024; M = 8192
    char* ws = (char*)d_ws;
    ushort* xb    = (ushort*)(ws);                 // 16 MB  [8192][1024]
    ushort* wqkv  = (ushort*)(ws + 16777216);      //  6 MB  [3072][1024]: wq, wk, Wvo
    ushort* wo_bf = (ushort*)(ws + 23068672);      //  2 MB  [1024][1024]
    ushort* wvT   = (ushort*)(ws + 25165824);      //  2 MB  [1024][1024] (= wv^T)
    ushort* QKVb  = (ushort*)(ws + 27262976);      // 48 MB  [8192][3072]  (Q,K,Vw)
    ushort* Vtb   = (ushort*)(ws + 77594624);      // 16 MB  [4][1024][2048] (Vw^T)
    ushort* E     = (ushort*)(ws + 94371840);      // 32 MB  [4][2048][2048] bf16
    float*  Zp    = (float*)(ws + 127926272);      //  1 MB  [4][32][2048]
    float*  Zi    = (float*)(ws + 128974848);      // 32 KB  [4][2048]

    // 1. converts
    f32_to_bf16_vec<<<8192, 256, 0, stream>>>(x,  xb,   2097152);
    f32_to_bf16_vec<<<1024, 256, 0, stream>>>(wq, wqkv,           262144);
    f32_to_bf16_vec<<<1024, 256, 0, stream>>>(wk, wqkv + 1048576, 262144);
    f32_to_bf16_vec<<<1024, 256, 0, stream>>>(wo, wo_bf,          262144);
    tr_cvt<<<dim3(16, 16), 256, 0, stream>>>(wv, wvT);

    // 2. Wvo = Wo @ Wv  (fold out-projection into V's weight):
    //    Wvo[i][j] = sum_k wo[i][k] * wv[k][j] = sum_k wo_bf[i][k] * wvT[j][k]
    gemm_bt_small<<<dim3(8, 8), 256, 0, stream>>>(
        wo_bf, 1024, wvT, 1024, wqkv + 2097152, 1024, 1024);

    // 3. fused QKVw projection: [8192][3072] = xb @ wqkv^T  (384 blocks)
    gemm256_8ph<false><<<dim3(12, 32, 1), 512, 0, stream>>>(
        xb, 1024, 0, wqkv, 1024, 0, QKVb, 3072, 0, 1024, 1.f, nullptr);

    // 4. Vw^T per batch -> [b][1024][2048]
    transpose_v<<<dim3(16, 32, 4), 256, 0, stream>>>(QKVb + 2048, 3072, 2048LL * 3072, Vtb);

    // 5. E = exp(Q K^T / 32) bf16 + row-sum partials   (256 blocks)
    gemm256_8ph<true><<<dim3(8, 8, 4), 512, 0, stream>>>(
        QKVb, 3072, 2048LL * 3072, QKVb + 1024, 3072, 2048LL * 3072,
        E, 2048, 2048LL * 2048, 1024, 0.03125f, Zp);

    // 6. Zi = 1 / rowsum
    zinv_k<<<32, 256, 0, stream>>>(Zp, Zi);

    // 7. out = (E @ Vw) * Zi  -> fp32 d_out directly  (256 blocks)
    gemm_bm128<float, true><<<dim3(4, 16, 4), 512, 0, stream>>>(
        E, 2048, 2048LL * 2048, Vtb, 2048, 1024LL * 2048,
        out, 1024, 2048LL * 1024, 2048, Zi);
}

// Round 9
// 191.544 us; speedup vs baseline: 1.0957x; 1.0641x over previous
//
#include <hip/hip_runtime.h>

typedef unsigned int uint;
typedef unsigned short ushort;
typedef __bf16 bf16x8 __attribute__((ext_vector_type(8)));
typedef float f32x4 __attribute__((ext_vector_type(4)));

__device__ __forceinline__ ushort f2bf(float v) {
    uint u = __builtin_bit_cast(uint, v);
    u += 0x7fffu + ((u >> 16) & 1u);   // RNE
    return (ushort)(u >> 16);
}

__device__ __forceinline__ void storeval(float* p, float v)  { *p = v; }
__device__ __forceinline__ void storeval(ushort* p, float v) { *p = f2bf(v); }

#define GLDS(g, l) __builtin_amdgcn_global_load_lds( \
    (const __attribute__((address_space(1))) uint*)(g), \
    (__attribute__((address_space(3))) uint*)(l), 16, 0, 0)

#define VMW(N)  asm volatile("s_waitcnt vmcnt(" #N ")" ::: "memory")
#define SBAR()  asm volatile("s_barrier" ::: "memory")

// Stage 128 rows x 64 cols bf16 (16KB) = one half-tile = 2 gload_lds/thread.
// LDS swizzle: 16B-slot s of row r stored at slot s^(r&7); pre-swizzled
// GLOBAL source (linear LDS dest, rule #21); reads apply the same XOR.
__device__ __forceinline__ void stage_half(const ushort* __restrict__ src, int ld,
                                           int halfrow, char* ldsbase, int tid)
{
#pragma unroll
    for (int i = 0; i < 2; i++) {
        const int byte = i * 8192 + tid * 16;
        const int row  = byte >> 7;
        const int slot = (byte >> 4) & 7;
        const int srcs = slot ^ (row & 7);
        GLDS(src + (long long)(halfrow + row) * ld + srcs * 8,
             ldsbase + halfrow * 128 + byte);
    }
}

__device__ __forceinline__ bf16x8 ldf(const char* base, int rbase, int ks,
                                      int lrow, int lquad)
{
    const int r    = rbase + lrow;
    const int slot = ((ks << 2) + lquad) ^ (r & 7);
    return *(const bf16x8*)(base + r * 128 + slot * 16);
}

#define RD_A(BASE, ROFF) \
    _Pragma("unroll") for (int m_ = 0; m_ < 4; m_++) \
    _Pragma("unroll") for (int k_ = 0; k_ < 2; k_++) \
        af[m_][k_] = ldf(BASE, (ROFF) + m_ * 16, k_, lrow, lquad);

#define RD_B(DST, BASE, ROFF) \
    _Pragma("unroll") for (int n_ = 0; n_ < 2; n_++) \
    _Pragma("unroll") for (int k_ = 0; k_ < 2; k_++) \
        DST[n_][k_] = ldf(BASE, (ROFF) + n_ * 16, k_, lrow, lquad);

// R5-verified (non-swapped) MFMA quad: mfma(A, B).
#define QUAD(MOFF, NOFF, B) \
    __builtin_amdgcn_s_setprio(1); \
    _Pragma("unroll") for (int m_ = 0; m_ < 4; m_++) \
    _Pragma("unroll") for (int n_ = 0; n_ < 2; n_++) \
    _Pragma("unroll") for (int k_ = 0; k_ < 2; k_++) \
        acc[(MOFF) + m_][(NOFF) + n_] = __builtin_amdgcn_mfma_f32_16x16x32_bf16( \
            af[m_][k_], B[n_][k_], acc[(MOFF) + m_][(NOFF) + n_], 0, 0, 0); \
    __builtin_amdgcn_s_setprio(0);

// ---------------------------------------------------------------------------
// gemm256_8ph: 256x256 tile, BK=64, 8-phase counted-vmcnt (R5-verified form).
// EXP epilogue: e=exp(acc*scale) -> bf16, per-wave 64-col row sums -> Zp.
// ---------------------------------------------------------------------------
template<bool EXP>
__global__ __launch_bounds__(512, 2)
void gemm256_8ph(const ushort* __restrict__ A, int lda, long long bsA,
                 const ushort* __restrict__ Bt, int ldb, long long bsB,
                 ushort* __restrict__ C, int ldc, long long bsC,
                 int K, float scale, float* __restrict__ Zp)
{
    __shared__ char smem[131072];
    char* A0 = smem;
    char* A1 = smem + 32768;
    char* B0 = smem + 65536;
    char* B1 = smem + 98304;

    const int tid   = threadIdx.x;
    const int lane  = tid & 63;
    const int wave  = tid >> 6;
    const int wr    = wave >> 2;
    const int wc    = wave & 3;
    const int lrow  = lane & 15;
    const int lquad = lane >> 4;
    const long long b = blockIdx.z;

    const ushort* Ag = A  + b * bsA + (long long)blockIdx.y * 256 * lda;
    const ushort* Bg = Bt + b * bsB + (long long)blockIdx.x * 256 * ldb;
    ushort*       Cg = C  + b * bsC + (long long)blockIdx.y * 256 * ldc
                           + (long long)blockIdx.x * 256;

    f32x4 acc[8][4] = {};
    bf16x8 af[4][2], bl[2][2], bh[2][2];

    const int nk    = K >> 6;
    const int nIter = nk >> 1;

    stage_half(Ag,      lda, 0,   A0, tid);
    stage_half(Bg,      ldb, 0,   B0, tid);
    stage_half(Bg,      ldb, 128, B0, tid);
    stage_half(Ag,      lda, 128, A0, tid);
    stage_half(Ag + 64, lda, 0,   A1, tid);
    stage_half(Bg + 64, ldb, 0,   B1, tid);
    stage_half(Bg + 64, ldb, 128, B1, tid);
    VMW(6); SBAR();

    for (int i = 0; i < nIter - 1; ++i) {
        const ushort* An1 = Ag + (2 * i + 1) * 64;
        const ushort* An2 = Ag + (2 * i + 2) * 64;
        const ushort* Bn2 = Bg + (2 * i + 2) * 64;
        const ushort* An3 = Ag + (2 * i + 3) * 64;
        const ushort* Bn3 = Bg + (2 * i + 3) * 64;

        RD_A(A0, wr * 64); RD_B(bl, B0, wc * 32);
        stage_half(An1, lda, 128, A1, tid);
        SBAR(); QUAD(0, 0, bl); SBAR();

        RD_B(bh, B0, 128 + wc * 32);
        stage_half(An2, lda, 0, A0, tid);
        SBAR(); QUAD(0, 2, bh); SBAR();

        RD_A(A0, 128 + wr * 64);
        stage_half(Bn2, ldb, 0, B0, tid);
        SBAR(); QUAD(4, 0, bl); SBAR();

        stage_half(Bn2, ldb, 128, B0, tid);
        SBAR(); QUAD(4, 2, bh); VMW(6); SBAR();

        RD_A(A1, wr * 64); RD_B(bl, B1, wc * 32);
        stage_half(An2, lda, 128, A0, tid);
        SBAR(); QUAD(0, 0, bl); SBAR();

        RD_B(bh, B1, 128 + wc * 32);
        stage_half(An3, lda, 0, A1, tid);
        SBAR(); QUAD(0, 2, bh); SBAR();

        RD_A(A1, 128 + wr * 64);
        stage_half(Bn3, ldb, 0, B1, tid);
        SBAR(); QUAD(4, 0, bl); SBAR();

        stage_half(Bn3, ldb, 128, B1, tid);
        SBAR(); QUAD(4, 2, bh); VMW(6); SBAR();
    }

    {
        const ushort* An1 = Ag + (nk - 1) * 64;

        RD_A(A0, wr * 64); RD_B(bl, B0, wc * 32);
        stage_half(An1, lda, 128, A1, tid);
        SBAR(); QUAD(0, 0, bl); SBAR();

        RD_B(bh, B0, 128 + wc * 32);
        SBAR(); QUAD(0, 2, bh); SBAR();

        RD_A(A0, 128 + wr * 64);
        SBAR(); QUAD(4, 0, bl); SBAR();

        SBAR(); QUAD(4, 2, bh); VMW(0); SBAR();

        RD_A(A1, wr * 64); RD_B(bl, B1, wc * 32);
        SBAR(); QUAD(0, 0, bl); SBAR();

        RD_B(bh, B1, 128 + wc * 32);
        SBAR(); QUAD(0, 2, bh); SBAR();

        RD_A(A1, 128 + wr * 64);
        SBAR(); QUAD(4, 0, bl); SBAR();

        SBAR(); QUAD(4, 2, bh);
    }

    // R5-verified epilogue: row = frag + lquad*4 + j, col = frag + lrow
#pragma unroll
    for (int m = 0; m < 8; m++) {
        const int row = (m >> 2) * 128 + wr * 64 + (m & 3) * 16 + lquad * 4;
        float rs[4] = {0.f, 0.f, 0.f, 0.f};
#pragma unroll
        for (int n = 0; n < 4; n++) {
            const int col = (n >> 1) * 128 + wc * 32 + (n & 1) * 16 + lrow;
#pragma unroll
            for (int j = 0; j < 4; j++) {
                float v = acc[m][n][j];
                if (EXP) {
                    float e = __expf(v * scale);
                    rs[j] += e;
                    Cg[(long long)(row + j) * ldc + col] = f2bf(e);
                } else {
                    Cg[(long long)(row + j) * ldc + col] = f2bf(v);
                }
            }
        }
        if (EXP) {
#pragma unroll
            for (int j = 0; j < 4; j++) {
                float s = rs[j];
                s += __shfl_xor(s, 1);
                s += __shfl_xor(s, 2);
                s += __shfl_xor(s, 4);
                s += __shfl_xor(s, 8);
                rs[j] = s;
            }
            if (lrow == 0) {
                const long long zi = ((long long)b * 32 + blockIdx.x * 4 + wc) * 2048
                                   + (long long)blockIdx.y * 256 + row;
#pragma unroll
                for (int j = 0; j < 4; j++) Zp[zi + j] = rs[j];
            }
        }
    }
}

// ---------------------------------------------------------------------------
// gemm_bm128: 128x256 tile, BK=64, 2-phase counted-vmcnt (R5-verified form).
// ZSCALE: v *= zinv[row] (PV normalization).
// ---------------------------------------------------------------------------
template<typename OUT_T, bool ZSCALE>
__global__ __launch_bounds__(512, 2)
void gemm_bm128(const ushort* __restrict__ A, int lda, long long bsA,
                const ushort* __restrict__ Bt, int ldb, long long bsB,
                OUT_T* __restrict__ C, int ldc, long long bsC,
                int K, const float* __restrict__ zinv)
{
    __shared__ char smem[98304];

    const int tid   = threadIdx.x;
    const int lane  = tid & 63;
    const int wave  = tid >> 6;
    const int wr    = wave >> 2;
    const int wc    = wave & 3;
    const int lrow  = lane & 15;
    const int lquad = lane >> 4;
    const long long b = blockIdx.z;

    const ushort* Ag = A  + b * bsA + (long long)blockIdx.y * 128 * lda;
    const ushort* Bg = Bt + b * bsB + (long long)blockIdx.x * 256 * ldb;
    OUT_T*        Cg = C  + b * bsC + (long long)blockIdx.y * 128 * ldc
                           + (long long)blockIdx.x * 256;

    f32x4 acc[4][4] = {};
    bf16x8 af[4][2], bl[2][2], bh[2][2];

    const int nk = K >> 6;

    stage_half(Ag, lda, 0,   smem,         tid);
    stage_half(Bg, ldb, 0,   smem + 32768, tid);
    stage_half(Bg, ldb, 128, smem + 32768, tid);
    VMW(2); SBAR();

    for (int t = 0; t < nk - 1; ++t) {
        const int cur = t & 1;
        const char* lAc = smem + cur * 16384;
        const char* lBc = smem + 32768 + cur * 32768;
        char* lAn = smem + (cur ^ 1) * 16384;
        char* lBn = smem + 32768 + (cur ^ 1) * 32768;
        const ushort* An = Ag + (t + 1) * 64;
        const ushort* Bn = Bg + (t + 1) * 64;

        RD_A(lAc, wr * 64);
        RD_B(bl, lBc, wc * 32);
        stage_half(An, lda, 0, lAn, tid);
        stage_half(Bn, ldb, 0, lBn, tid);
        SBAR();
        QUAD(0, 0, bl);
        VMW(4); SBAR();

        RD_B(bh, lBc, 128 + wc * 32);
        stage_half(Bn, ldb, 128, lBn, tid);
        SBAR();
        QUAD(0, 2, bh);
        VMW(2); SBAR();
    }

    {
        const int cur = (nk - 1) & 1;
        const char* lAc = smem + cur * 16384;
        const char* lBc = smem + 32768 + cur * 32768;

        RD_A(lAc, wr * 64);
        RD_B(bl, lBc, wc * 32);
        SBAR();
        QUAD(0, 0, bl);
        VMW(0); SBAR();

        RD_B(bh, lBc, 128 + wc * 32);
        SBAR();
        QUAD(0, 2, bh);
    }

#pragma unroll
    for (int m = 0; m < 4; m++) {
        const int row = wr * 64 + m * 16 + lquad * 4;
        f32x4 z4;
        if (ZSCALE)
            z4 = *(const f32x4*)&zinv[b * 2048 + (long long)blockIdx.y * 128 + row];
#pragma unroll
        for (int n = 0; n < 4; n++) {
            const int col = (n >> 1) * 128 + wc * 32 + (n & 1) * 16 + lrow;
#pragma unroll
            for (int j = 0; j < 4; j++) {
                float v = acc[m][n][j];
                if (ZSCALE) v *= z4[j];
                storeval(&Cg[(long long)(row + j) * ldc + col], v);
            }
        }
    }
}

// ---------------------------------------------------------------------------
// gemm_bt_small: 128x128-tile, 256-thr, high-occupancy GEMM for 1024^2 weights.
// C[m][n] = sum_k A[m][k] * Bt[n][k], bf16 out.
// ---------------------------------------------------------------------------
__global__ __launch_bounds__(256)
void gemm_bt_small(const ushort* __restrict__ A, int lda,
                   const ushort* __restrict__ Bt, int ldb,
                   ushort* __restrict__ C, int ldc, int K)
{
    __shared__ ushort lA[128 * 64];
    __shared__ ushort lB[128 * 64];

    const int tid  = threadIdx.x;
    const int lane = tid & 63;
    const int wave = tid >> 6;
    const int wr   = wave >> 1;
    const int wc   = wave & 1;

    A  += (long long)blockIdx.y * 128 * lda;
    Bt += (long long)blockIdx.x * 128 * ldb;
    C  += (long long)blockIdx.y * 128 * ldc + (long long)blockIdx.x * 128;

    f32x4 acc[4][4] = {};
    const int byte_base = wave * 1024 + lane * 16;

    for (int kt = 0; kt < K; kt += 64) {
#pragma unroll
        for (int i = 0; i < 4; i++) {
            const int byte = i * 4096 + byte_base;
            const int row  = byte >> 7;
            const int k0   = (byte & 127) >> 1;
            GLDS(A  + (long long)row * lda + kt + k0, (char*)lA + byte);
            GLDS(Bt + (long long)row * ldb + kt + k0, (char*)lB + byte);
        }
        __syncthreads();

#pragma unroll
        for (int ks = 0; ks < 2; ks++) {
            bf16x8 af2[4], bf2[4];
#pragma unroll
            for (int m = 0; m < 4; m++)
                af2[m] = *(const bf16x8*)&lA[(wr * 64 + m * 16 + (lane & 15)) * 64 + ks * 32 + (lane >> 4) * 8];
#pragma unroll
            for (int n = 0; n < 4; n++)
                bf2[n] = *(const bf16x8*)&lB[(wc * 64 + n * 16 + (lane & 15)) * 64 + ks * 32 + (lane >> 4) * 8];
#pragma unroll
            for (int m = 0; m < 4; m++)
#pragma unroll
                for (int n = 0; n < 4; n++)
                    acc[m][n] = __builtin_amdgcn_mfma_f32_16x16x32_bf16(af2[m], bf2[n], acc[m][n], 0, 0, 0);
        }
        __syncthreads();
    }

    const int r0 = wr * 64 + (lane >> 4) * 4;
    const int c0 = wc * 64 + (lane & 15);
#pragma unroll
    for (int m = 0; m < 4; m++)
#pragma unroll
        for (int n = 0; n < 4; n++)
#pragma unroll
            for (int j = 0; j < 4; j++)
                C[(long long)(r0 + m * 16 + j) * ldc + c0 + n * 16] = f2bf(acc[m][n][j]);
}

// ---------------------------------------------------------------------------
__global__ __launch_bounds__(256)
void f32_to_bf16_vec(const float* __restrict__ in, ushort* __restrict__ out, int n4)
{
    int i = blockIdx.x * 256 + threadIdx.x;
    if (i >= n4) return;
    float4 v = ((const float4*)in)[i];
    ushort o[4] = { f2bf(v.x), f2bf(v.y), f2bf(v.z), f2bf(v.w) };
    *(uint2*)&out[(size_t)i * 4] = *(const uint2*)&o[0];
}

// ---------------------------------------------------------------------------
// src [1024][1024] fp32 -> dst [1024][1024] bf16 TRANSPOSED: dst[j][k]=src[k][j]
// ---------------------------------------------------------------------------
__global__ __launch_bounds__(256)
void tr_cvt(const float* __restrict__ src, ushort* __restrict__ dst)
{
    __shared__ float t[64][65];
    const int k0 = blockIdx.y * 64, j0 = blockIdx.x * 64;
    const int r = threadIdx.x >> 2;
    const int c = (threadIdx.x & 3) * 16;

    const float* p = src + (size_t)(k0 + r) * 1024 + j0 + c;
#pragma unroll
    for (int j = 0; j < 16; j++) t[r][c + j] = p[j];
    __syncthreads();

    ushort o[16];
#pragma unroll
    for (int j = 0; j < 16; j++) o[j] = f2bf(t[c + j][r]);
    ushort* q = dst + (size_t)(j0 + r) * 1024 + k0 + c;
    *(uint4*)q       = *(const uint4*)&o[0];
    *(uint4*)(q + 8) = *(const uint4*)&o[8];
}

// ---------------------------------------------------------------------------
__global__ __launch_bounds__(256)
void zinv_k(const float* __restrict__ zp, float* __restrict__ zi)
{
    const int t = blockIdx.x * 256 + threadIdx.x;
    const int b = t >> 11, r = t & 2047;
    const float* p = zp + (long long)b * 32 * 2048 + r;
    float s = 0.f;
#pragma unroll
    for (int i = 0; i < 32; i++) s += p[i * 2048];
    zi[t] = 1.0f / s;
}

// ---------------------------------------------------------------------------
__global__ __launch_bounds__(256)
void transpose_v(const ushort* __restrict__ V, int ldv, long long bsV,
                 ushort* __restrict__ Vt)
{
    __shared__ ushort t[64][65];
    const int b = blockIdx.z;
    const ushort* src = V  + (size_t)b * bsV;
    ushort*       dst = Vt + (size_t)b * 1024 * 2048;
    const int e0 = blockIdx.x * 64;
    const int k0 = blockIdx.y * 64;
    const int r = threadIdx.x >> 2;
    const int c = (threadIdx.x & 3) * 16;

    const ushort* p = &src[(size_t)(k0 + r) * ldv + e0 + c];
    ushort vals[16];
    *(uint4*)&vals[0] = *(const uint4*)p;
    *(uint4*)&vals[8] = *(const uint4*)(p + 8);
#pragma unroll
    for (int j = 0; j < 16; j++) t[r][c + j] = vals[j];
    __syncthreads();

    ushort o[16];
#pragma unroll
    for (int j = 0; j < 16; j++) o[j] = t[c + j][r];
    ushort* q = &dst[(size_t)(e0 + r) * 2048 + k0 + c];
    *(uint4*)q       = *(const uint4*)&o[0];
    *(uint4*)(q + 8) = *(const uint4*)&o[8];
}

// ---------------------------------------------------------------------------
extern "C" void kernel_launch(void* const* d_in, const int* in_sizes, int n_in,
                              void* d_out, int out_size, void* d_ws, size_t ws_size,
                              hipStream_t stream)
{
    const float* x  = (const float*)d_in[0];
    const float* wq = (const float*)d_in[1];
    const float* wk = (const float*)d_in[2];
    const float* wv = (const float*)d_in[3];
    const float* wo = (const float*)d_in[4];
    float* out = (float*)d_out;

    // B=4, S=2048, D=1024; M = 8192
    // Algebra: scores = x·M·x^T with M = Wq^T·Wk  (K-projection eliminated);
    //          out    = P·x·Wvo^T · (1/Z) with Wvo = Wo·Wv (out-proj eliminated).
    // W2 = [ M^T ; Wvo ]  [2048][1024] bf16 -> TVw = xb @ W2^T  [8192][2048].
    char* ws = (char*)d_ws;
    ushort* xb    = (ushort*)(ws);                 // 16 MB  [8192][1024]
    ushort* W2    = (ushort*)(ws + 16777216);      //  4 MB  [2048][1024]
    ushort* wqT   = (ushort*)(ws + 20971520);      //  2 MB
    ushort* wkT   = (ushort*)(ws + 23068672);      //  2 MB
    ushort* wvT   = (ushort*)(ws + 25165824);      //  2 MB
    ushort* wo_bf = (ushort*)(ws + 27262976);      //  2 MB
    ushort* TVw   = (ushort*)(ws + 29360128);      // 32 MB  [8192][2048] (T | Vw)
    ushort* Vtb   = (ushort*)(ws + 62914560);      // 16 MB  [4][1024][2048]
    ushort* E     = (ushort*)(ws + 79691776);      // 32 MB  [4][2048][2048]
    float*  Zp    = (float*)(ws + 113246208);      //  1 MB  [4][32][2048]
    float*  Zi    = (float*)(ws + 114294784);      // 32 KB  [4][2048]

    // 1. converts / transposes of weights
    f32_to_bf16_vec<<<8192, 256, 0, stream>>>(x,  xb, 2097152);
    tr_cvt<<<dim3(16, 16), 256, 0, stream>>>(wq, wqT);
    tr_cvt<<<dim3(16, 16), 256, 0, stream>>>(wk, wkT);
    tr_cvt<<<dim3(16, 16), 256, 0, stream>>>(wv, wvT);
    f32_to_bf16_vec<<<1024, 256, 0, stream>>>(wo, wo_bf, 262144);

    // 2a. M^T = Wk^T · Wq :  C[e][d] = sum_c wkT[e][c] * wqT[d][c]
    gemm_bt_small<<<dim3(8, 8), 256, 0, stream>>>(wkT, 1024, wqT, 1024, W2, 1024, 1024);
    // 2b. Wvo = Wo · Wv   :  C[i][j] = sum_k wo_bf[i][k] * wvT[j][k]
    gemm_bt_small<<<dim3(8, 8), 256, 0, stream>>>(wo_bf, 1024, wvT, 1024,
                                                  W2 + 1048576, 1024, 1024);

    // 3. TVw = xb @ W2^T  [8192][2048]   (256 blocks = 1 exact round)
    gemm256_8ph<false><<<dim3(8, 32, 1), 512, 0, stream>>>(
        xb, 1024, 0, W2, 1024, 0, TVw, 2048, 0, 1024, 1.f, nullptr);

    // 4. Vw^T per batch -> [b][1024][2048]
    transpose_v<<<dim3(16, 32, 4), 256, 0, stream>>>(TVw + 1024, 2048, 2048LL * 2048, Vtb);

    // 5. E = exp(T x^T / 32) bf16 + row-sum partials   (256 blocks)
    gemm256_8ph<true><<<dim3(8, 8, 4), 512, 0, stream>>>(
        TVw, 2048, 2048LL * 2048, xb, 1024, 2048LL * 1024,
        E, 2048, 2048LL * 2048, 1024, 0.03125f, Zp);

    // 6. Zi = 1 / rowsum
    zinv_k<<<32, 256, 0, stream>>>(Zp, Zi);

    // 7. out = (E @ Vw) * Zi  -> fp32 d_out   (256 blocks)
    gemm_bm128<float, true><<<dim3(4, 16, 4), 512, 0, stream>>>(
        E, 2048, 2048LL * 2048, Vtb, 2048, 1024LL * 2048,
        out, 1024, 2048LL * 1024, 2048, Zi);
}

// Round 10
// 165.701 us; speedup vs baseline: 1.2666x; 1.1560x over previous
//
#include <hip/hip_runtime.h>

typedef unsigned int uint;
typedef unsigned short ushort;
typedef __bf16 bf16x8 __attribute__((ext_vector_type(8)));
typedef float f32x4 __attribute__((ext_vector_type(4)));

__device__ __forceinline__ ushort f2bf(float v) {
    uint u = __builtin_bit_cast(uint, v);
    u += 0x7fffu + ((u >> 16) & 1u);   // RNE
    return (ushort)(u >> 16);
}

__device__ __forceinline__ void storeval(float* p, float v)  { *p = v; }
__device__ __forceinline__ void storeval(ushort* p, float v) { *p = f2bf(v); }

#define GLDS(g, l) __builtin_amdgcn_global_load_lds( \
    (const __attribute__((address_space(1))) uint*)(g), \
    (__attribute__((address_space(3))) uint*)(l), 16, 0, 0)

#define VMW(N)  asm volatile("s_waitcnt vmcnt(" #N ")" ::: "memory")
#define SBAR()  asm volatile("s_barrier" ::: "memory")

// Stage 128 rows x 64 cols bf16 (16KB) = one half-tile = 2 gload_lds/thread.
// LDS swizzle: 16B-slot s of row r stored at slot s^(r&7); pre-swizzled
// GLOBAL source (linear LDS dest, rule #21); reads apply the same XOR.
__device__ __forceinline__ void stage_half(const ushort* __restrict__ src, int ld,
                                           int halfrow, char* ldsbase, int tid)
{
#pragma unroll
    for (int i = 0; i < 2; i++) {
        const int byte = i * 8192 + tid * 16;
        const int row  = byte >> 7;
        const int slot = (byte >> 4) & 7;
        const int srcs = slot ^ (row & 7);
        GLDS(src + (long long)(halfrow + row) * ld + srcs * 8,
             ldsbase + halfrow * 128 + byte);
    }
}

__device__ __forceinline__ bf16x8 ldf(const char* base, int rbase, int ks,
                                      int lrow, int lquad)
{
    const int r    = rbase + lrow;
    const int slot = ((ks << 2) + lquad) ^ (r & 7);
    return *(const bf16x8*)(base + r * 128 + slot * 16);
}

#define RD_A(BASE, ROFF) \
    _Pragma("unroll") for (int m_ = 0; m_ < 4; m_++) \
    _Pragma("unroll") for (int k_ = 0; k_ < 2; k_++) \
        af[m_][k_] = ldf(BASE, (ROFF) + m_ * 16, k_, lrow, lquad);

#define RD_B(DST, BASE, ROFF) \
    _Pragma("unroll") for (int n_ = 0; n_ < 2; n_++) \
    _Pragma("unroll") for (int k_ = 0; k_ < 2; k_++) \
        DST[n_][k_] = ldf(BASE, (ROFF) + n_ * 16, k_, lrow, lquad);

// R5-verified (non-swapped) MFMA quad: mfma(A, B).
#define QUAD(MOFF, NOFF, B) \
    __builtin_amdgcn_s_setprio(1); \
    _Pragma("unroll") for (int m_ = 0; m_ < 4; m_++) \
    _Pragma("unroll") for (int n_ = 0; n_ < 2; n_++) \
    _Pragma("unroll") for (int k_ = 0; k_ < 2; k_++) \
        acc[(MOFF) + m_][(NOFF) + n_] = __builtin_amdgcn_mfma_f32_16x16x32_bf16( \
            af[m_][k_], B[n_][k_], acc[(MOFF) + m_][(NOFF) + n_], 0, 0, 0); \
    __builtin_amdgcn_s_setprio(0);

// ---------------------------------------------------------------------------
// gemm256_8ph: 256x256 tile, BK=64, 8-phase counted-vmcnt (R5/R9-verified).
// EXP epilogue: e=exp(acc*scale) -> bf16, per-wave 64-col row sums -> Zp.
// ---------------------------------------------------------------------------
template<bool EXP>
__global__ __launch_bounds__(512, 2)
void gemm256_8ph(const ushort* __restrict__ A, int lda, long long bsA,
                 const ushort* __restrict__ Bt, int ldb, long long bsB,
                 ushort* __restrict__ C, int ldc, long long bsC,
                 int K, float scale, float* __restrict__ Zp)
{
    __shared__ char smem[131072];
    char* A0 = smem;
    char* A1 = smem + 32768;
    char* B0 = smem + 65536;
    char* B1 = smem + 98304;

    const int tid   = threadIdx.x;
    const int lane  = tid & 63;
    const int wave  = tid >> 6;
    const int wr    = wave >> 2;
    const int wc    = wave & 3;
    const int lrow  = lane & 15;
    const int lquad = lane >> 4;
    const long long b = blockIdx.z;

    const ushort* Ag = A  + b * bsA + (long long)blockIdx.y * 256 * lda;
    const ushort* Bg = Bt + b * bsB + (long long)blockIdx.x * 256 * ldb;
    ushort*       Cg = C  + b * bsC + (long long)blockIdx.y * 256 * ldc
                           + (long long)blockIdx.x * 256;

    f32x4 acc[8][4] = {};
    bf16x8 af[4][2], bl[2][2], bh[2][2];

    const int nk    = K >> 6;
    const int nIter = nk >> 1;

    stage_half(Ag,      lda, 0,   A0, tid);
    stage_half(Bg,      ldb, 0,   B0, tid);
    stage_half(Bg,      ldb, 128, B0, tid);
    stage_half(Ag,      lda, 128, A0, tid);
    stage_half(Ag + 64, lda, 0,   A1, tid);
    stage_half(Bg + 64, ldb, 0,   B1, tid);
    stage_half(Bg + 64, ldb, 128, B1, tid);
    VMW(6); SBAR();

    for (int i = 0; i < nIter - 1; ++i) {
        const ushort* An1 = Ag + (2 * i + 1) * 64;
        const ushort* An2 = Ag + (2 * i + 2) * 64;
        const ushort* Bn2 = Bg + (2 * i + 2) * 64;
        const ushort* An3 = Ag + (2 * i + 3) * 64;
        const ushort* Bn3 = Bg + (2 * i + 3) * 64;

        RD_A(A0, wr * 64); RD_B(bl, B0, wc * 32);
        stage_half(An1, lda, 128, A1, tid);
        SBAR(); QUAD(0, 0, bl); SBAR();

        RD_B(bh, B0, 128 + wc * 32);
        stage_half(An2, lda, 0, A0, tid);
        SBAR(); QUAD(0, 2, bh); SBAR();

        RD_A(A0, 128 + wr * 64);
        stage_half(Bn2, ldb, 0, B0, tid);
        SBAR(); QUAD(4, 0, bl); SBAR();

        stage_half(Bn2, ldb, 128, B0, tid);
        SBAR(); QUAD(4, 2, bh); VMW(6); SBAR();

        RD_A(A1, wr * 64); RD_B(bl, B1, wc * 32);
        stage_half(An2, lda, 128, A0, tid);
        SBAR(); QUAD(0, 0, bl); SBAR();

        RD_B(bh, B1, 128 + wc * 32);
        stage_half(An3, lda, 0, A1, tid);
        SBAR(); QUAD(0, 2, bh); SBAR();

        RD_A(A1, 128 + wr * 64);
        stage_half(Bn3, ldb, 0, B1, tid);
        SBAR(); QUAD(4, 0, bl); SBAR();

        stage_half(Bn3, ldb, 128, B1, tid);
        SBAR(); QUAD(4, 2, bh); VMW(6); SBAR();
    }

    {
        const ushort* An1 = Ag + (nk - 1) * 64;

        RD_A(A0, wr * 64); RD_B(bl, B0, wc * 32);
        stage_half(An1, lda, 128, A1, tid);
        SBAR(); QUAD(0, 0, bl); SBAR();

        RD_B(bh, B0, 128 + wc * 32);
        SBAR(); QUAD(0, 2, bh); SBAR();

        RD_A(A0, 128 + wr * 64);
        SBAR(); QUAD(4, 0, bl); SBAR();

        SBAR(); QUAD(4, 2, bh); VMW(0); SBAR();

        RD_A(A1, wr * 64); RD_B(bl, B1, wc * 32);
        SBAR(); QUAD(0, 0, bl); SBAR();

        RD_B(bh, B1, 128 + wc * 32);
        SBAR(); QUAD(0, 2, bh); SBAR();

        RD_A(A1, 128 + wr * 64);
        SBAR(); QUAD(4, 0, bl); SBAR();

        SBAR(); QUAD(4, 2, bh);
    }

#pragma unroll
    for (int m = 0; m < 8; m++) {
        const int row = (m >> 2) * 128 + wr * 64 + (m & 3) * 16 + lquad * 4;
        float rs[4] = {0.f, 0.f, 0.f, 0.f};
#pragma unroll
        for (int n = 0; n < 4; n++) {
            const int col = (n >> 1) * 128 + wc * 32 + (n & 1) * 16 + lrow;
#pragma unroll
            for (int j = 0; j < 4; j++) {
                float v = acc[m][n][j];
                if (EXP) {
                    float e = __expf(v * scale);
                    rs[j] += e;
                    Cg[(long long)(row + j) * ldc + col] = f2bf(e);
                } else {
                    Cg[(long long)(row + j) * ldc + col] = f2bf(v);
                }
            }
        }
        if (EXP) {
#pragma unroll
            for (int j = 0; j < 4; j++) {
                float s = rs[j];
                s += __shfl_xor(s, 1);
                s += __shfl_xor(s, 2);
                s += __shfl_xor(s, 4);
                s += __shfl_xor(s, 8);
                rs[j] = s;
            }
            if (lrow == 0) {
                const long long zi = ((long long)b * 32 + blockIdx.x * 4 + wc) * 2048
                                   + (long long)blockIdx.y * 256 + row;
#pragma unroll
                for (int j = 0; j < 4; j++) Zp[zi + j] = rs[j];
            }
        }
    }
}

// ---------------------------------------------------------------------------
// gemm_bm128: 128x256 tile, BK=64, 2-phase counted-vmcnt (R5/R9-verified).
// ZSCALE: v *= zinv[row] (PV normalization).
// ---------------------------------------------------------------------------
template<typename OUT_T, bool ZSCALE>
__global__ __launch_bounds__(512, 2)
void gemm_bm128(const ushort* __restrict__ A, int lda, long long bsA,
                const ushort* __restrict__ Bt, int ldb, long long bsB,
                OUT_T* __restrict__ C, int ldc, long long bsC,
                int K, const float* __restrict__ zinv)
{
    __shared__ char smem[98304];

    const int tid   = threadIdx.x;
    const int lane  = tid & 63;
    const int wave  = tid >> 6;
    const int wr    = wave >> 2;
    const int wc    = wave & 3;
    const int lrow  = lane & 15;
    const int lquad = lane >> 4;
    const long long b = blockIdx.z;

    const ushort* Ag = A  + b * bsA + (long long)blockIdx.y * 128 * lda;
    const ushort* Bg = Bt + b * bsB + (long long)blockIdx.x * 256 * ldb;
    OUT_T*        Cg = C  + b * bsC + (long long)blockIdx.y * 128 * ldc
                           + (long long)blockIdx.x * 256;

    f32x4 acc[4][4] = {};
    bf16x8 af[4][2], bl[2][2], bh[2][2];

    const int nk = K >> 6;

    stage_half(Ag, lda, 0,   smem,         tid);
    stage_half(Bg, ldb, 0,   smem + 32768, tid);
    stage_half(Bg, ldb, 128, smem + 32768, tid);
    VMW(2); SBAR();

    for (int t = 0; t < nk - 1; ++t) {
        const int cur = t & 1;
        const char* lAc = smem + cur * 16384;
        const char* lBc = smem + 32768 + cur * 32768;
        char* lAn = smem + (cur ^ 1) * 16384;
        char* lBn = smem + 32768 + (cur ^ 1) * 32768;
        const ushort* An = Ag + (t + 1) * 64;
        const ushort* Bn = Bg + (t + 1) * 64;

        RD_A(lAc, wr * 64);
        RD_B(bl, lBc, wc * 32);
        stage_half(An, lda, 0, lAn, tid);
        stage_half(Bn, ldb, 0, lBn, tid);
        SBAR();
        QUAD(0, 0, bl);
        VMW(4); SBAR();

        RD_B(bh, lBc, 128 + wc * 32);
        stage_half(Bn, ldb, 128, lBn, tid);
        SBAR();
        QUAD(0, 2, bh);
        VMW(2); SBAR();
    }

    {
        const int cur = (nk - 1) & 1;
        const char* lAc = smem + cur * 16384;
        const char* lBc = smem + 32768 + cur * 32768;

        RD_A(lAc, wr * 64);
        RD_B(bl, lBc, wc * 32);
        SBAR();
        QUAD(0, 0, bl);
        VMW(0); SBAR();

        RD_B(bh, lBc, 128 + wc * 32);
        SBAR();
        QUAD(0, 2, bh);
    }

#pragma unroll
    for (int m = 0; m < 4; m++) {
        const int row = wr * 64 + m * 16 + lquad * 4;
        f32x4 z4;
        if (ZSCALE)
            z4 = *(const f32x4*)&zinv[b * 2048 + (long long)blockIdx.y * 128 + row];
#pragma unroll
        for (int n = 0; n < 4; n++) {
            const int col = (n >> 1) * 128 + wc * 32 + (n & 1) * 16 + lrow;
#pragma unroll
            for (int j = 0; j < 4; j++) {
                float v = acc[m][n][j];
                if (ZSCALE) v *= z4[j];
                storeval(&Cg[(long long)(row + j) * ldc + col], v);
            }
        }
    }
}

// ---------------------------------------------------------------------------
// wgemm_splitk: BATCHED split-K weight GEMM. grid (8,8,8): z = pair*4 + ks.
// pair 0: C[e][d] = sum_c wkT[e][c]*wqT[d][c]  (= M^T rows of W2)
// pair 1: C[i][j] = sum_k wo[i][k]*wvT[j][k]   (= Wvo rows of W2)
// Each block: 128x128 tile over K in [ks*256, ks*256+256) -> fp32 partial
// P[z][1024][1024]. Fixed-order reduce in wreduce (deterministic).
// ---------------------------------------------------------------------------
__global__ __launch_bounds__(256)
void wgemm_splitk(const ushort* __restrict__ A0, const ushort* __restrict__ B0,
                  const ushort* __restrict__ A1, const ushort* __restrict__ B1,
                  float* __restrict__ P)
{
    __shared__ ushort lA[128 * 64];
    __shared__ ushort lB[128 * 64];

    const int z    = blockIdx.z;
    const int pair = z >> 2;
    const int ksl  = z & 3;

    const ushort* A  = (pair ? A1 : B0 == B1 ? A0 : A0);  // keep simple below
    A = pair ? A1 : A0;
    const ushort* Bt = pair ? B1 : B0;

    const int tid  = threadIdx.x;
    const int lane = tid & 63;
    const int wave = tid >> 6;
    const int wr   = wave >> 1;
    const int wc   = wave & 1;

    A  += (long long)blockIdx.y * 128 * 1024 + ksl * 256;
    Bt += (long long)blockIdx.x * 128 * 1024 + ksl * 256;
    float* Pg = P + (long long)z * 1048576
                  + (long long)blockIdx.y * 128 * 1024 + (long long)blockIdx.x * 128;

    f32x4 acc[4][4] = {};
    const int byte_base = wave * 1024 + lane * 16;

    for (int kt = 0; kt < 256; kt += 64) {
#pragma unroll
        for (int i = 0; i < 4; i++) {
            const int byte = i * 4096 + byte_base;
            const int row  = byte >> 7;
            const int k0   = (byte & 127) >> 1;
            GLDS(A  + (long long)row * 1024 + kt + k0, (char*)lA + byte);
            GLDS(Bt + (long long)row * 1024 + kt + k0, (char*)lB + byte);
        }
        __syncthreads();

#pragma unroll
        for (int ks = 0; ks < 2; ks++) {
            bf16x8 af2[4], bf2[4];
#pragma unroll
            for (int m = 0; m < 4; m++)
                af2[m] = *(const bf16x8*)&lA[(wr * 64 + m * 16 + (lane & 15)) * 64 + ks * 32 + (lane >> 4) * 8];
#pragma unroll
            for (int n = 0; n < 4; n++)
                bf2[n] = *(const bf16x8*)&lB[(wc * 64 + n * 16 + (lane & 15)) * 64 + ks * 32 + (lane >> 4) * 8];
#pragma unroll
            for (int m = 0; m < 4; m++)
#pragma unroll
                for (int n = 0; n < 4; n++)
                    acc[m][n] = __builtin_amdgcn_mfma_f32_16x16x32_bf16(af2[m], bf2[n], acc[m][n], 0, 0, 0);
        }
        __syncthreads();
    }

    const int r0 = wr * 64 + (lane >> 4) * 4;
    const int c0 = wc * 64 + (lane & 15);
#pragma unroll
    for (int m = 0; m < 4; m++)
#pragma unroll
        for (int n = 0; n < 4; n++)
#pragma unroll
            for (int j = 0; j < 4; j++)
                Pg[(long long)(r0 + m * 16 + j) * 1024 + c0 + n * 16] = acc[m][n][j];
}

// ---------------------------------------------------------------------------
// wreduce: W2[pair][1024][1024] = bf16( sum_{ks=0..3} P[pair*4+ks][...] ).
// One float4-group per thread; fixed summation order -> deterministic.
// ---------------------------------------------------------------------------
__global__ __launch_bounds__(256)
void wreduce(const float* __restrict__ P, ushort* __restrict__ W2)
{
    const int i = blockIdx.x * 256 + threadIdx.x;      // 0..524287
    const int pair = i >> 18;
    const int off  = (i & 262143) * 4;
    const float* base = P + (long long)pair * 4194304 + off;
    float4 s = *(const float4*)(base);
#pragma unroll
    for (int ks = 1; ks < 4; ks++) {
        float4 v = *(const float4*)(base + (long long)ks * 1048576);
        s.x += v.x; s.y += v.y; s.z += v.z; s.w += v.w;
    }
    ushort o[4] = { f2bf(s.x), f2bf(s.y), f2bf(s.z), f2bf(s.w) };
    *(uint2*)&W2[(long long)pair * 1048576 + off] = *(const uint2*)&o[0];
}

// ---------------------------------------------------------------------------
__global__ __launch_bounds__(256)
void f32_to_bf16_vec(const float* __restrict__ in, ushort* __restrict__ out, int n4)
{
    int i = blockIdx.x * 256 + threadIdx.x;
    if (i >= n4) return;
    float4 v = ((const float4*)in)[i];
    ushort o[4] = { f2bf(v.x), f2bf(v.y), f2bf(v.z), f2bf(v.w) };
    *(uint2*)&out[(size_t)i * 4] = *(const uint2*)&o[0];
}

// ---------------------------------------------------------------------------
// BATCHED transpose+convert: z in {0,1,2} selects src in {wq,wk,wv};
// dst[z] = wT + z*1048576; dst[j][k] = src[k][j] (bf16).
// ---------------------------------------------------------------------------
__global__ __launch_bounds__(256)
void tr_cvt3(const float* __restrict__ s0, const float* __restrict__ s1,
             const float* __restrict__ s2, ushort* __restrict__ wT)
{
    __shared__ float t[64][65];
    const int z = blockIdx.z;
    const float* src = (z == 0) ? s0 : (z == 1) ? s1 : s2;
    ushort* dst = wT + (size_t)z * 1048576;

    const int k0 = blockIdx.y * 64, j0 = blockIdx.x * 64;
    const int r = threadIdx.x >> 2;
    const int c = (threadIdx.x & 3) * 16;

    const float* p = src + (size_t)(k0 + r) * 1024 + j0 + c;
#pragma unroll
    for (int j = 0; j < 16; j++) t[r][c + j] = p[j];
    __syncthreads();

    ushort o[16];
#pragma unroll
    for (int j = 0; j < 16; j++) o[j] = f2bf(t[c + j][r]);
    ushort* q = dst + (size_t)(j0 + r) * 1024 + k0 + c;
    *(uint4*)q       = *(const uint4*)&o[0];
    *(uint4*)(q + 8) = *(const uint4*)&o[8];
}

// ---------------------------------------------------------------------------
__global__ __launch_bounds__(256)
void zinv_k(const float* __restrict__ zp, float* __restrict__ zi)
{
    const int t = blockIdx.x * 256 + threadIdx.x;
    const int b = t >> 11, r = t & 2047;
    const float* p = zp + (long long)b * 32 * 2048 + r;
    float s = 0.f;
#pragma unroll
    for (int i = 0; i < 32; i++) s += p[i * 2048];
    zi[t] = 1.0f / s;
}

// ---------------------------------------------------------------------------
__global__ __launch_bounds__(256)
void transpose_v(const ushort* __restrict__ V, int ldv, long long bsV,
                 ushort* __restrict__ Vt)
{
    __shared__ ushort t[64][65];
    const int b = blockIdx.z;
    const ushort* src = V  + (size_t)b * bsV;
    ushort*       dst = Vt + (size_t)b * 1024 * 2048;
    const int e0 = blockIdx.x * 64;
    const int k0 = blockIdx.y * 64;
    const int r = threadIdx.x >> 2;
    const int c = (threadIdx.x & 3) * 16;

    const ushort* p = &src[(size_t)(k0 + r) * ldv + e0 + c];
    ushort vals[16];
    *(uint4*)&vals[0] = *(const uint4*)p;
    *(uint4*)&vals[8] = *(const uint4*)(p + 8);
#pragma unroll
    for (int j = 0; j < 16; j++) t[r][c + j] = vals[j];
    __syncthreads();

    ushort o[16];
#pragma unroll
    for (int j = 0; j < 16; j++) o[j] = t[c + j][r];
    ushort* q = &dst[(size_t)(e0 + r) * 2048 + k0 + c];
    *(uint4*)q       = *(const uint4*)&o[0];
    *(uint4*)(q + 8) = *(const uint4*)&o[8];
}

// ---------------------------------------------------------------------------
extern "C" void kernel_launch(void* const* d_in, const int* in_sizes, int n_in,
                              void* d_out, int out_size, void* d_ws, size_t ws_size,
                              hipStream_t stream)
{
    const float* x  = (const float*)d_in[0];
    const float* wq = (const float*)d_in[1];
    const float* wk = (const float*)d_in[2];
    const float* wv = (const float*)d_in[3];
    const float* wo = (const float*)d_in[4];
    float* out = (float*)d_out;

    // B=4, S=2048, D=1024; M = 8192
    // Algebra: scores = x·M·x^T with M = Wq^T·Wk  (K-projection eliminated);
    //          out    = P·x·Wvo^T · (1/Z) with Wvo = Wo·Wv (out-proj eliminated).
    // W2 = [ M^T ; Wvo ]  [2048][1024] bf16 -> TVw = xb @ W2^T  [8192][2048].
    char* ws = (char*)d_ws;
    ushort* xb    = (ushort*)(ws);                 // 16 MB  [8192][1024]
    ushort* W2    = (ushort*)(ws + 16777216);      //  4 MB  [2048][1024]
    ushort* wT    = (ushort*)(ws + 20971520);      //  6 MB  wqT|wkT|wvT
    ushort* wo_bf = (ushort*)(ws + 27262976);      //  2 MB
    ushort* TVw   = (ushort*)(ws + 29360128);      // 32 MB  [8192][2048] (T | Vw)
    ushort* Vtb   = (ushort*)(ws + 62914560);      // 16 MB  [4][1024][2048]
    ushort* E     = (ushort*)(ws + 79691776);      // 32 MB  [4][2048][2048]
    float*  Pp    = (float*)(ws + 79691776);       // 32 MB  ALIAS of E (used before E)
    float*  Zp    = (float*)(ws + 113246208);      //  1 MB  [4][32][2048]
    float*  Zi    = (float*)(ws + 114294784);      // 32 KB  [4][2048]

    ushort* wqT = wT;
    ushort* wkT = wT + 1048576;
    ushort* wvT = wT + 2097152;

    // 1. converts / transposes of weights (batched)
    f32_to_bf16_vec<<<8192, 256, 0, stream>>>(x,  xb, 2097152);
    tr_cvt3<<<dim3(16, 16, 3), 256, 0, stream>>>(wq, wk, wv, wT);
    f32_to_bf16_vec<<<1024, 256, 0, stream>>>(wo, wo_bf, 262144);

    // 2. W2 rows 0-1023: M^T = Wk^T·Wq ; rows 1024-2047: Wvo = Wo·Wv
    //    (batched split-K=4 partials -> fixed-order reduce; deterministic)
    wgemm_splitk<<<dim3(8, 8, 8), 256, 0, stream>>>(wkT, wqT, wo_bf, wvT, Pp);
    wreduce<<<2048, 256, 0, stream>>>(Pp, W2);

    // 3. TVw = xb @ W2^T  [8192][2048]   (256 blocks = 1 exact round)
    gemm256_8ph<false><<<dim3(8, 32, 1), 512, 0, stream>>>(
        xb, 1024, 0, W2, 1024, 0, TVw, 2048, 0, 1024, 1.f, nullptr);

    // 4. Vw^T per batch -> [b][1024][2048]
    transpose_v<<<dim3(16, 32, 4), 256, 0, stream>>>(TVw + 1024, 2048, 2048LL * 2048, Vtb);

    // 5. E = exp(T x^T / 32) bf16 + row-sum partials   (256 blocks)
    gemm256_8ph<true><<<dim3(8, 8, 4), 512, 0, stream>>>(
        TVw, 2048, 2048LL * 2048, xb, 1024, 2048LL * 1024,
        E, 2048, 2048LL * 2048, 1024, 0.03125f, Zp);

    // 6. Zi = 1 / rowsum
    zinv_k<<<32, 256, 0, stream>>>(Zp, Zi);

    // 7. out = (E @ Vw) * Zi  -> fp32 d_out   (256 blocks)
    gemm_bm128<float, true><<<dim3(4, 16, 4), 512, 0, stream>>>(
        E, 2048, 2048LL * 2048, Vtb, 2048, 1024LL * 2048,
        out, 1024, 2048LL * 1024, 2048, Zi);
}

// Round 11
// 164.530 us; speedup vs baseline: 1.2756x; 1.0071x over previous
//
#include <hip/hip_runtime.h>

typedef unsigned int uint;
typedef unsigned short ushort;
typedef __bf16 bf16x8 __attribute__((ext_vector_type(8)));
typedef float f32x4 __attribute__((ext_vector_type(4)));

__device__ __forceinline__ ushort f2bf(float v) {
    uint u = __builtin_bit_cast(uint, v);
    u += 0x7fffu + ((u >> 16) & 1u);   // RNE
    return (ushort)(u >> 16);
}

__device__ __forceinline__ void storeval(float* p, float v)  { *p = v; }
__device__ __forceinline__ void storeval(ushort* p, float v) { *p = f2bf(v); }

#define GLDS(g, l) __builtin_amdgcn_global_load_lds( \
    (const __attribute__((address_space(1))) uint*)(g), \
    (__attribute__((address_space(3))) uint*)(l), 16, 0, 0)

#define VMW(N)  asm volatile("s_waitcnt vmcnt(" #N ")" ::: "memory")
#define SBAR()  asm volatile("s_barrier" ::: "memory")

// Stage 128 rows x 64 cols bf16 (16KB) = one half-tile = 2 gload_lds/thread.
// LDS swizzle: 16B-slot s of row r stored at slot s^(r&7); pre-swizzled
// GLOBAL source (linear LDS dest, rule #21); reads apply the same XOR.
__device__ __forceinline__ void stage_half(const ushort* __restrict__ src, int ld,
                                           int halfrow, char* ldsbase, int tid)
{
#pragma unroll
    for (int i = 0; i < 2; i++) {
        const int byte = i * 8192 + tid * 16;
        const int row  = byte >> 7;
        const int slot = (byte >> 4) & 7;
        const int srcs = slot ^ (row & 7);
        GLDS(src + (long long)(halfrow + row) * ld + srcs * 8,
             ldsbase + halfrow * 128 + byte);
    }
}

__device__ __forceinline__ bf16x8 ldf(const char* base, int rbase, int ks,
                                      int lrow, int lquad)
{
    const int r    = rbase + lrow;
    const int slot = ((ks << 2) + lquad) ^ (r & 7);
    return *(const bf16x8*)(base + r * 128 + slot * 16);
}

#define RD_A(BASE, ROFF) \
    _Pragma("unroll") for (int m_ = 0; m_ < 4; m_++) \
    _Pragma("unroll") for (int k_ = 0; k_ < 2; k_++) \
        af[m_][k_] = ldf(BASE, (ROFF) + m_ * 16, k_, lrow, lquad);

#define RD_B(DST, BASE, ROFF) \
    _Pragma("unroll") for (int n_ = 0; n_ < 2; n_++) \
    _Pragma("unroll") for (int k_ = 0; k_ < 2; k_++) \
        DST[n_][k_] = ldf(BASE, (ROFF) + n_ * 16, k_, lrow, lquad);

// R5-verified (non-swapped) MFMA quad: mfma(A, B).
#define QUAD(MOFF, NOFF, B) \
    __builtin_amdgcn_s_setprio(1); \
    _Pragma("unroll") for (int m_ = 0; m_ < 4; m_++) \
    _Pragma("unroll") for (int n_ = 0; n_ < 2; n_++) \
    _Pragma("unroll") for (int k_ = 0; k_ < 2; k_++) \
        acc[(MOFF) + m_][(NOFF) + n_] = __builtin_amdgcn_mfma_f32_16x16x32_bf16( \
            af[m_][k_], B[n_][k_], acc[(MOFF) + m_][(NOFF) + n_], 0, 0, 0); \
    __builtin_amdgcn_s_setprio(0);

// ---------------------------------------------------------------------------
// gemm256_8ph: 256x256 tile, BK=64, 8-phase counted-vmcnt (R5/R9-verified).
// EXP epilogue: e=exp(acc*scale) -> bf16, per-wave 64-col row sums -> Zp.
// ---------------------------------------------------------------------------
template<bool EXP>
__global__ __launch_bounds__(512, 2)
void gemm256_8ph(const ushort* __restrict__ A, int lda, long long bsA,
                 const ushort* __restrict__ Bt, int ldb, long long bsB,
                 ushort* __restrict__ C, int ldc, long long bsC,
                 int K, float scale, float* __restrict__ Zp)
{
    __shared__ char smem[131072];
    char* A0 = smem;
    char* A1 = smem + 32768;
    char* B0 = smem + 65536;
    char* B1 = smem + 98304;

    const int tid   = threadIdx.x;
    const int lane  = tid & 63;
    const int wave  = tid >> 6;
    const int wr    = wave >> 2;
    const int wc    = wave & 3;
    const int lrow  = lane & 15;
    const int lquad = lane >> 4;
    const long long b = blockIdx.z;

    const ushort* Ag = A  + b * bsA + (long long)blockIdx.y * 256 * lda;
    const ushort* Bg = Bt + b * bsB + (long long)blockIdx.x * 256 * ldb;
    ushort*       Cg = C  + b * bsC + (long long)blockIdx.y * 256 * ldc
                           + (long long)blockIdx.x * 256;

    f32x4 acc[8][4] = {};
    bf16x8 af[4][2], bl[2][2], bh[2][2];

    const int nk    = K >> 6;
    const int nIter = nk >> 1;

    stage_half(Ag,      lda, 0,   A0, tid);
    stage_half(Bg,      ldb, 0,   B0, tid);
    stage_half(Bg,      ldb, 128, B0, tid);
    stage_half(Ag,      lda, 128, A0, tid);
    stage_half(Ag + 64, lda, 0,   A1, tid);
    stage_half(Bg + 64, ldb, 0,   B1, tid);
    stage_half(Bg + 64, ldb, 128, B1, tid);
    VMW(6); SBAR();

    for (int i = 0; i < nIter - 1; ++i) {
        const ushort* An1 = Ag + (2 * i + 1) * 64;
        const ushort* An2 = Ag + (2 * i + 2) * 64;
        const ushort* Bn2 = Bg + (2 * i + 2) * 64;
        const ushort* An3 = Ag + (2 * i + 3) * 64;
        const ushort* Bn3 = Bg + (2 * i + 3) * 64;

        RD_A(A0, wr * 64); RD_B(bl, B0, wc * 32);
        stage_half(An1, lda, 128, A1, tid);
        SBAR(); QUAD(0, 0, bl); SBAR();

        RD_B(bh, B0, 128 + wc * 32);
        stage_half(An2, lda, 0, A0, tid);
        SBAR(); QUAD(0, 2, bh); SBAR();

        RD_A(A0, 128 + wr * 64);
        stage_half(Bn2, ldb, 0, B0, tid);
        SBAR(); QUAD(4, 0, bl); SBAR();

        stage_half(Bn2, ldb, 128, B0, tid);
        SBAR(); QUAD(4, 2, bh); VMW(6); SBAR();

        RD_A(A1, wr * 64); RD_B(bl, B1, wc * 32);
        stage_half(An2, lda, 128, A0, tid);
        SBAR(); QUAD(0, 0, bl); SBAR();

        RD_B(bh, B1, 128 + wc * 32);
        stage_half(An3, lda, 0, A1, tid);
        SBAR(); QUAD(0, 2, bh); SBAR();

        RD_A(A1, 128 + wr * 64);
        stage_half(Bn3, ldb, 0, B1, tid);
        SBAR(); QUAD(4, 0, bl); SBAR();

        stage_half(Bn3, ldb, 128, B1, tid);
        SBAR(); QUAD(4, 2, bh); VMW(6); SBAR();
    }

    {
        const ushort* An1 = Ag + (nk - 1) * 64;

        RD_A(A0, wr * 64); RD_B(bl, B0, wc * 32);
        stage_half(An1, lda, 128, A1, tid);
        SBAR(); QUAD(0, 0, bl); SBAR();

        RD_B(bh, B0, 128 + wc * 32);
        SBAR(); QUAD(0, 2, bh); SBAR();

        RD_A(A0, 128 + wr * 64);
        SBAR(); QUAD(4, 0, bl); SBAR();

        SBAR(); QUAD(4, 2, bh); VMW(0); SBAR();

        RD_A(A1, wr * 64); RD_B(bl, B1, wc * 32);
        SBAR(); QUAD(0, 0, bl); SBAR();

        RD_B(bh, B1, 128 + wc * 32);
        SBAR(); QUAD(0, 2, bh); SBAR();

        RD_A(A1, 128 + wr * 64);
        SBAR(); QUAD(4, 0, bl); SBAR();

        SBAR(); QUAD(4, 2, bh);
    }

#pragma unroll
    for (int m = 0; m < 8; m++) {
        const int row = (m >> 2) * 128 + wr * 64 + (m & 3) * 16 + lquad * 4;
        float rs[4] = {0.f, 0.f, 0.f, 0.f};
#pragma unroll
        for (int n = 0; n < 4; n++) {
            const int col = (n >> 1) * 128 + wc * 32 + (n & 1) * 16 + lrow;
#pragma unroll
            for (int j = 0; j < 4; j++) {
                float v = acc[m][n][j];
                if (EXP) {
                    float e = __expf(v * scale);
                    rs[j] += e;
                    Cg[(long long)(row + j) * ldc + col] = f2bf(e);
                } else {
                    Cg[(long long)(row + j) * ldc + col] = f2bf(v);
                }
            }
        }
        if (EXP) {
#pragma unroll
            for (int j = 0; j < 4; j++) {
                float s = rs[j];
                s += __shfl_xor(s, 1);
                s += __shfl_xor(s, 2);
                s += __shfl_xor(s, 4);
                s += __shfl_xor(s, 8);
                rs[j] = s;
            }
            if (lrow == 0) {
                const long long zi = ((long long)b * 32 + blockIdx.x * 4 + wc) * 2048
                                   + (long long)blockIdx.y * 256 + row;
#pragma unroll
                for (int j = 0; j < 4; j++) Zp[zi + j] = rs[j];
            }
        }
    }
}

// ---------------------------------------------------------------------------
// gemm_bm128: 128x256 tile, BK=64, 2-phase counted-vmcnt (R5/R9-verified).
// ZSCALE: zinv computed IN-KERNEL from Zp partials (threads 0-127, fixed
// order, before staging; LDS zbuf; deletes the zinv_k launch).
// ---------------------------------------------------------------------------
template<typename OUT_T, bool ZSCALE>
__global__ __launch_bounds__(512, 2)
void gemm_bm128(const ushort* __restrict__ A, int lda, long long bsA,
                const ushort* __restrict__ Bt, int ldb, long long bsB,
                OUT_T* __restrict__ C, int ldc, long long bsC,
                int K, const float* __restrict__ Zp)
{
    __shared__ char smem[98304];
    __shared__ float zbuf[128];

    const int tid   = threadIdx.x;
    const int lane  = tid & 63;
    const int wave  = tid >> 6;
    const int wr    = wave >> 2;
    const int wc    = wave & 3;
    const int lrow  = lane & 15;
    const int lquad = lane >> 4;
    const long long b = blockIdx.z;

    if (ZSCALE) {
        if (tid < 128) {
            const float* p = Zp + b * 32 * 2048
                           + (long long)blockIdx.y * 128 + tid;
            float s = 0.f;
#pragma unroll
            for (int i = 0; i < 32; i++) s += p[i * 2048];
            zbuf[tid] = 1.0f / s;
        }
        __syncthreads();   // Zp loads drained (compiler waitcnt) -> vmcnt clean
    }

    const ushort* Ag = A  + b * bsA + (long long)blockIdx.y * 128 * lda;
    const ushort* Bg = Bt + b * bsB + (long long)blockIdx.x * 256 * ldb;
    OUT_T*        Cg = C  + b * bsC + (long long)blockIdx.y * 128 * ldc
                           + (long long)blockIdx.x * 256;

    f32x4 acc[4][4] = {};
    bf16x8 af[4][2], bl[2][2], bh[2][2];

    const int nk = K >> 6;

    stage_half(Ag, lda, 0,   smem,         tid);
    stage_half(Bg, ldb, 0,   smem + 32768, tid);
    stage_half(Bg, ldb, 128, smem + 32768, tid);
    VMW(2); SBAR();

    for (int t = 0; t < nk - 1; ++t) {
        const int cur = t & 1;
        const char* lAc = smem + cur * 16384;
        const char* lBc = smem + 32768 + cur * 32768;
        char* lAn = smem + (cur ^ 1) * 16384;
        char* lBn = smem + 32768 + (cur ^ 1) * 32768;
        const ushort* An = Ag + (t + 1) * 64;
        const ushort* Bn = Bg + (t + 1) * 64;

        RD_A(lAc, wr * 64);
        RD_B(bl, lBc, wc * 32);
        stage_half(An, lda, 0, lAn, tid);
        stage_half(Bn, ldb, 0, lBn, tid);
        SBAR();
        QUAD(0, 0, bl);
        VMW(4); SBAR();

        RD_B(bh, lBc, 128 + wc * 32);
        stage_half(Bn, ldb, 128, lBn, tid);
        SBAR();
        QUAD(0, 2, bh);
        VMW(2); SBAR();
    }

    {
        const int cur = (nk - 1) & 1;
        const char* lAc = smem + cur * 16384;
        const char* lBc = smem + 32768 + cur * 32768;

        RD_A(lAc, wr * 64);
        RD_B(bl, lBc, wc * 32);
        SBAR();
        QUAD(0, 0, bl);
        VMW(0); SBAR();

        RD_B(bh, lBc, 128 + wc * 32);
        SBAR();
        QUAD(0, 2, bh);
    }

#pragma unroll
    for (int m = 0; m < 4; m++) {
        const int row = wr * 64 + m * 16 + lquad * 4;
        f32x4 z4;
        if (ZSCALE) z4 = *(const f32x4*)&zbuf[row];
#pragma unroll
        for (int n = 0; n < 4; n++) {
            const int col = (n >> 1) * 128 + wc * 32 + (n & 1) * 16 + lrow;
#pragma unroll
            for (int j = 0; j < 4; j++) {
                float v = acc[m][n][j];
                if (ZSCALE) v *= z4[j];
                storeval(&Cg[(long long)(row + j) * ldc + col], v);
            }
        }
    }
}

// ---------------------------------------------------------------------------
// wgemm_splitk: BATCHED split-K weight GEMM. grid (8,8,4): z = pair*2 + ks.
// pair 0: C[e][d] = sum_c wkT[e][c]*wqT[d][c]  (= M^T rows of W2)
// pair 1: C[i][j] = sum_k wo[i][k]*wvT[j][k]   (= Wvo rows of W2)
// Each block: 128x128 tile over K in [ks*512, ks*512+512) -> fp32 partial
// P[z][1024][1024]. Fixed-order reduce in wreduce (deterministic).
// ---------------------------------------------------------------------------
__global__ __launch_bounds__(256)
void wgemm_splitk(const ushort* __restrict__ A0, const ushort* __restrict__ B0,
                  const ushort* __restrict__ A1, const ushort* __restrict__ B1,
                  float* __restrict__ P)
{
    __shared__ ushort lA[128 * 64];
    __shared__ ushort lB[128 * 64];

    const int z    = blockIdx.z;
    const int pair = z >> 1;
    const int ksl  = z & 1;

    const ushort* A  = pair ? A1 : A0;
    const ushort* Bt = pair ? B1 : B0;

    const int tid  = threadIdx.x;
    const int lane = tid & 63;
    const int wave = tid >> 6;
    const int wr   = wave >> 1;
    const int wc   = wave & 1;

    A  += (long long)blockIdx.y * 128 * 1024 + ksl * 512;
    Bt += (long long)blockIdx.x * 128 * 1024 + ksl * 512;
    float* Pg = P + (long long)z * 1048576
                  + (long long)blockIdx.y * 128 * 1024 + (long long)blockIdx.x * 128;

    f32x4 acc[4][4] = {};
    const int byte_base = wave * 1024 + lane * 16;

    for (int kt = 0; kt < 512; kt += 64) {
#pragma unroll
        for (int i = 0; i < 4; i++) {
            const int byte = i * 4096 + byte_base;
            const int row  = byte >> 7;
            const int k0   = (byte & 127) >> 1;
            GLDS(A  + (long long)row * 1024 + kt + k0, (char*)lA + byte);
            GLDS(Bt + (long long)row * 1024 + kt + k0, (char*)lB + byte);
        }
        __syncthreads();

#pragma unroll
        for (int ks = 0; ks < 2; ks++) {
            bf16x8 af2[4], bf2[4];
#pragma unroll
            for (int m = 0; m < 4; m++)
                af2[m] = *(const bf16x8*)&lA[(wr * 64 + m * 16 + (lane & 15)) * 64 + ks * 32 + (lane >> 4) * 8];
#pragma unroll
            for (int n = 0; n < 4; n++)
                bf2[n] = *(const bf16x8*)&lB[(wc * 64 + n * 16 + (lane & 15)) * 64 + ks * 32 + (lane >> 4) * 8];
#pragma unroll
            for (int m = 0; m < 4; m++)
#pragma unroll
                for (int n = 0; n < 4; n++)
                    acc[m][n] = __builtin_amdgcn_mfma_f32_16x16x32_bf16(af2[m], bf2[n], acc[m][n], 0, 0, 0);
        }
        __syncthreads();
    }

    const int r0 = wr * 64 + (lane >> 4) * 4;
    const int c0 = wc * 64 + (lane & 15);
#pragma unroll
    for (int m = 0; m < 4; m++)
#pragma unroll
        for (int n = 0; n < 4; n++)
#pragma unroll
            for (int j = 0; j < 4; j++)
                Pg[(long long)(r0 + m * 16 + j) * 1024 + c0 + n * 16] = acc[m][n][j];
}

// ---------------------------------------------------------------------------
// wreduce: W2[pair][1024][1024] = bf16( sum_{ks=0..1} P[pair*2+ks][...] ).
// One float4-group per thread; fixed summation order -> deterministic.
// ---------------------------------------------------------------------------
__global__ __launch_bounds__(256)
void wreduce(const float* __restrict__ P, ushort* __restrict__ W2)
{
    const int i = blockIdx.x * 256 + threadIdx.x;      // 0..524287
    const int pair = i >> 18;
    const int off  = (i & 262143) * 4;
    const float* base = P + (long long)pair * 2097152 + off;
    float4 s = *(const float4*)(base);
    float4 v = *(const float4*)(base + 1048576);
    s.x += v.x; s.y += v.y; s.z += v.z; s.w += v.w;
    ushort o[4] = { f2bf(s.x), f2bf(s.y), f2bf(s.z), f2bf(s.w) };
    *(uint2*)&W2[(long long)pair * 1048576 + off] = *(const uint2*)&o[0];
}

// ---------------------------------------------------------------------------
__global__ __launch_bounds__(256)
void f32_to_bf16_vec(const float* __restrict__ in, ushort* __restrict__ out, int n4)
{
    int i = blockIdx.x * 256 + threadIdx.x;
    if (i >= n4) return;
    float4 v = ((const float4*)in)[i];
    ushort o[4] = { f2bf(v.x), f2bf(v.y), f2bf(v.z), f2bf(v.w) };
    *(uint2*)&out[(size_t)i * 4] = *(const uint2*)&o[0];
}

// ---------------------------------------------------------------------------
// wprep: BATCHED weight prep. z in {0,1,2}: transpose-convert wq/wk/wv into
// wT[z] (dst[j][k] = src[k][j], bf16). z == 3: plain convert wo -> wo_bf.
// ---------------------------------------------------------------------------
__global__ __launch_bounds__(256)
void wprep(const float* __restrict__ s0, const float* __restrict__ s1,
           const float* __restrict__ s2, const float* __restrict__ s3,
           ushort* __restrict__ wT, ushort* __restrict__ wo_bf)
{
    __shared__ float t[64][65];
    const int z = blockIdx.z;
    const int k0 = blockIdx.y * 64, j0 = blockIdx.x * 64;
    const int r = threadIdx.x >> 2;
    const int c = (threadIdx.x & 3) * 16;

    if (z == 3) {
        const float* p = s3 + (size_t)(k0 + r) * 1024 + j0 + c;
        float4 a = *(const float4*)(p);
        float4 bq = *(const float4*)(p + 4);
        float4 cc = *(const float4*)(p + 8);
        float4 d = *(const float4*)(p + 12);
        ushort o[16] = { f2bf(a.x), f2bf(a.y), f2bf(a.z), f2bf(a.w),
                         f2bf(bq.x), f2bf(bq.y), f2bf(bq.z), f2bf(bq.w),
                         f2bf(cc.x), f2bf(cc.y), f2bf(cc.z), f2bf(cc.w),
                         f2bf(d.x), f2bf(d.y), f2bf(d.z), f2bf(d.w) };
        ushort* q = wo_bf + (size_t)(k0 + r) * 1024 + j0 + c;
        *(uint4*)q       = *(const uint4*)&o[0];
        *(uint4*)(q + 8) = *(const uint4*)&o[8];
        return;
    }

    const float* src = (z == 0) ? s0 : (z == 1) ? s1 : s2;
    ushort* dst = wT + (size_t)z * 1048576;

    const float* p = src + (size_t)(k0 + r) * 1024 + j0 + c;
#pragma unroll
    for (int j = 0; j < 16; j++) t[r][c + j] = p[j];
    __syncthreads();

    ushort o[16];
#pragma unroll
    for (int j = 0; j < 16; j++) o[j] = f2bf(t[c + j][r]);
    ushort* q = dst + (size_t)(j0 + r) * 1024 + k0 + c;
    *(uint4*)q       = *(const uint4*)&o[0];
    *(uint4*)(q + 8) = *(const uint4*)&o[8];
}

// ---------------------------------------------------------------------------
__global__ __launch_bounds__(256)
void transpose_v(const ushort* __restrict__ V, int ldv, long long bsV,
                 ushort* __restrict__ Vt)
{
    __shared__ ushort t[64][65];
    const int b = blockIdx.z;
    const ushort* src = V  + (size_t)b * bsV;
    ushort*       dst = Vt + (size_t)b * 1024 * 2048;
    const int e0 = blockIdx.x * 64;
    const int k0 = blockIdx.y * 64;
    const int r = threadIdx.x >> 2;
    const int c = (threadIdx.x & 3) * 16;

    const ushort* p = &src[(size_t)(k0 + r) * ldv + e0 + c];
    ushort vals[16];
    *(uint4*)&vals[0] = *(const uint4*)p;
    *(uint4*)&vals[8] = *(const uint4*)(p + 8);
#pragma unroll
    for (int j = 0; j < 16; j++) t[r][c + j] = vals[j];
    __syncthreads();

    ushort o[16];
#pragma unroll
    for (int j = 0; j < 16; j++) o[j] = t[c + j][r];
    ushort* q = &dst[(size_t)(e0 + r) * 2048 + k0 + c];
    *(uint4*)q       = *(const uint4*)&o[0];
    *(uint4*)(q + 8) = *(const uint4*)&o[8];
}

// ---------------------------------------------------------------------------
extern "C" void kernel_launch(void* const* d_in, const int* in_sizes, int n_in,
                              void* d_out, int out_size, void* d_ws, size_t ws_size,
                              hipStream_t stream)
{
    const float* x  = (const float*)d_in[0];
    const float* wq = (const float*)d_in[1];
    const float* wk = (const float*)d_in[2];
    const float* wv = (const float*)d_in[3];
    const float* wo = (const float*)d_in[4];
    float* out = (float*)d_out;

    // B=4, S=2048, D=1024; M = 8192
    // Algebra: scores = x·M·x^T with M = Wq^T·Wk  (K-projection eliminated);
    //          out    = P·x·Wvo^T · (1/Z) with Wvo = Wo·Wv (out-proj eliminated).
    // W2 = [ M^T ; Wvo ]  [2048][1024] bf16 -> TVw = xb @ W2^T  [8192][2048].
    char* ws = (char*)d_ws;
    ushort* xb    = (ushort*)(ws);                 // 16 MB  [8192][1024]
    ushort* W2    = (ushort*)(ws + 16777216);      //  4 MB  [2048][1024]
    ushort* wT    = (ushort*)(ws + 20971520);      //  6 MB  wqT|wkT|wvT
    ushort* wo_bf = (ushort*)(ws + 27262976);      //  2 MB
    ushort* TVw   = (ushort*)(ws + 29360128);      // 32 MB  [8192][2048] (T | Vw)
    ushort* Vtb   = (ushort*)(ws + 62914560);      // 16 MB  [4][1024][2048]
    ushort* E     = (ushort*)(ws + 79691776);      // 32 MB  [4][2048][2048]
    float*  Pp    = (float*)(ws + 79691776);       // 16 MB  ALIAS of E (used before E)
    float*  Zp    = (float*)(ws + 113246208);      //  1 MB  [4][32][2048]

    ushort* wqT = wT;
    ushort* wkT = wT + 1048576;
    ushort* wvT = wT + 2097152;

    // 1. converts / transposes (batched: z<3 transpose wq/wk/wv, z=3 wo)
    f32_to_bf16_vec<<<8192, 256, 0, stream>>>(x, xb, 2097152);
    wprep<<<dim3(16, 16, 4), 256, 0, stream>>>(wq, wk, wv, wo, wT, wo_bf);

    // 2. W2 rows 0-1023: M^T = Wk^T·Wq ; rows 1024-2047: Wvo = Wo·Wv
    //    (batched split-K=2 partials -> fixed-order reduce; deterministic)
    wgemm_splitk<<<dim3(8, 8, 4), 256, 0, stream>>>(wkT, wqT, wo_bf, wvT, Pp);
    wreduce<<<2048, 256, 0, stream>>>(Pp, W2);

    // 3. TVw = xb @ W2^T  [8192][2048]   (256 blocks = 1 exact round)
    gemm256_8ph<false><<<dim3(8, 32, 1), 512, 0, stream>>>(
        xb, 1024, 0, W2, 1024, 0, TVw, 2048, 0, 1024, 1.f, nullptr);

    // 4. Vw^T per batch -> [b][1024][2048]
    transpose_v<<<dim3(16, 32, 4), 256, 0, stream>>>(TVw + 1024, 2048, 2048LL * 2048, Vtb);

    // 5. E = exp(T x^T / 32) bf16 + row-sum partials   (256 blocks)
    gemm256_8ph<true><<<dim3(8, 8, 4), 512, 0, stream>>>(
        TVw, 2048, 2048LL * 2048, xb, 1024, 2048LL * 1024,
        E, 2048, 2048LL * 2048, 1024, 0.03125f, Zp);

    // 6. out = (E @ Vw) * (1/Z from Zp, in-kernel) -> fp32 d_out  (256 blocks)
    gemm_bm128<float, true><<<dim3(4, 16, 4), 512, 0, stream>>>(
        E, 2048, 2048LL * 2048, Vtb, 2048, 1024LL * 2048,
        out, 1024, 2048LL * 1024, 2048, Zp);
}

// Round 12
// 164.484 us; speedup vs baseline: 1.2760x; 1.0003x over previous
//
#include <hip/hip_runtime.h>

typedef unsigned int uint;
typedef unsigned short ushort;
typedef __bf16 bf16x8 __attribute__((ext_vector_type(8)));
typedef float f32x4 __attribute__((ext_vector_type(4)));

__device__ __forceinline__ ushort f2bf(float v) {
    uint u = __builtin_bit_cast(uint, v);
    u += 0x7fffu + ((u >> 16) & 1u);   // RNE
    return (ushort)(u >> 16);
}

__device__ __forceinline__ void storeval(float* p, float v)  { *p = v; }
__device__ __forceinline__ void storeval(ushort* p, float v) { *p = f2bf(v); }

#define GLDS(g, l) __builtin_amdgcn_global_load_lds( \
    (const __attribute__((address_space(1))) uint*)(g), \
    (__attribute__((address_space(3))) uint*)(l), 16, 0, 0)

#define VMW(N)  asm volatile("s_waitcnt vmcnt(" #N ")" ::: "memory")
#define SBAR()  asm volatile("s_barrier" ::: "memory")

// Stage 128 rows x 64 cols bf16 (16KB) = one half-tile = 2 gload_lds/thread.
// LDS swizzle: 16B-slot s of row r stored at slot s^(r&7); pre-swizzled
// GLOBAL source (linear LDS dest, rule #21); reads apply the same XOR.
__device__ __forceinline__ void stage_half(const ushort* __restrict__ src, int ld,
                                           int halfrow, char* ldsbase, int tid)
{
#pragma unroll
    for (int i = 0; i < 2; i++) {
        const int byte = i * 8192 + tid * 16;
        const int row  = byte >> 7;
        const int slot = (byte >> 4) & 7;
        const int srcs = slot ^ (row & 7);
        GLDS(src + (long long)(halfrow + row) * ld + srcs * 8,
             ldsbase + halfrow * 128 + byte);
    }
}

__device__ __forceinline__ bf16x8 ldf(const char* base, int rbase, int ks,
                                      int lrow, int lquad)
{
    const int r    = rbase + lrow;
    const int slot = ((ks << 2) + lquad) ^ (r & 7);
    return *(const bf16x8*)(base + r * 128 + slot * 16);
}

#define RD_A(BASE, ROFF) \
    _Pragma("unroll") for (int m_ = 0; m_ < 4; m_++) \
    _Pragma("unroll") for (int k_ = 0; k_ < 2; k_++) \
        af[m_][k_] = ldf(BASE, (ROFF) + m_ * 16, k_, lrow, lquad);

#define RD_B(DST, BASE, ROFF) \
    _Pragma("unroll") for (int n_ = 0; n_ < 2; n_++) \
    _Pragma("unroll") for (int k_ = 0; k_ < 2; k_++) \
        DST[n_][k_] = ldf(BASE, (ROFF) + n_ * 16, k_, lrow, lquad);

// R5-verified (non-swapped) MFMA quad: mfma(A, B).
#define QUAD(MOFF, NOFF, B) \
    __builtin_amdgcn_s_setprio(1); \
    _Pragma("unroll") for (int m_ = 0; m_ < 4; m_++) \
    _Pragma("unroll") for (int n_ = 0; n_ < 2; n_++) \
    _Pragma("unroll") for (int k_ = 0; k_ < 2; k_++) \
        acc[(MOFF) + m_][(NOFF) + n_] = __builtin_amdgcn_mfma_f32_16x16x32_bf16( \
            af[m_][k_], B[n_][k_], acc[(MOFF) + m_][(NOFF) + n_], 0, 0, 0); \
    __builtin_amdgcn_s_setprio(0);

// ---------------------------------------------------------------------------
// gemm256_8ph: 256x256 tile, BK=64, 8-phase counted-vmcnt (R5/R9-verified).
// EXP epilogue: e=exp(acc*scale) -> bf16, per-wave 64-col row sums -> Zp.
// ---------------------------------------------------------------------------
template<bool EXP>
__global__ __launch_bounds__(512, 2)
void gemm256_8ph(const ushort* __restrict__ A, int lda, long long bsA,
                 const ushort* __restrict__ Bt, int ldb, long long bsB,
                 ushort* __restrict__ C, int ldc, long long bsC,
                 int K, float scale, float* __restrict__ Zp)
{
    __shared__ char smem[131072];
    char* A0 = smem;
    char* A1 = smem + 32768;
    char* B0 = smem + 65536;
    char* B1 = smem + 98304;

    const int tid   = threadIdx.x;
    const int lane  = tid & 63;
    const int wave  = tid >> 6;
    const int wr    = wave >> 2;
    const int wc    = wave & 3;
    const int lrow  = lane & 15;
    const int lquad = lane >> 4;
    const long long b = blockIdx.z;

    const ushort* Ag = A  + b * bsA + (long long)blockIdx.y * 256 * lda;
    const ushort* Bg = Bt + b * bsB + (long long)blockIdx.x * 256 * ldb;
    ushort*       Cg = C  + b * bsC + (long long)blockIdx.y * 256 * ldc
                           + (long long)blockIdx.x * 256;

    f32x4 acc[8][4] = {};
    bf16x8 af[4][2], bl[2][2], bh[2][2];

    const int nk    = K >> 6;
    const int nIter = nk >> 1;

    stage_half(Ag,      lda, 0,   A0, tid);
    stage_half(Bg,      ldb, 0,   B0, tid);
    stage_half(Bg,      ldb, 128, B0, tid);
    stage_half(Ag,      lda, 128, A0, tid);
    stage_half(Ag + 64, lda, 0,   A1, tid);
    stage_half(Bg + 64, ldb, 0,   B1, tid);
    stage_half(Bg + 64, ldb, 128, B1, tid);
    VMW(6); SBAR();

    for (int i = 0; i < nIter - 1; ++i) {
        const ushort* An1 = Ag + (2 * i + 1) * 64;
        const ushort* An2 = Ag + (2 * i + 2) * 64;
        const ushort* Bn2 = Bg + (2 * i + 2) * 64;
        const ushort* An3 = Ag + (2 * i + 3) * 64;
        const ushort* Bn3 = Bg + (2 * i + 3) * 64;

        RD_A(A0, wr * 64); RD_B(bl, B0, wc * 32);
        stage_half(An1, lda, 128, A1, tid);
        SBAR(); QUAD(0, 0, bl); SBAR();

        RD_B(bh, B0, 128 + wc * 32);
        stage_half(An2, lda, 0, A0, tid);
        SBAR(); QUAD(0, 2, bh); SBAR();

        RD_A(A0, 128 + wr * 64);
        stage_half(Bn2, ldb, 0, B0, tid);
        SBAR(); QUAD(4, 0, bl); SBAR();

        stage_half(Bn2, ldb, 128, B0, tid);
        SBAR(); QUAD(4, 2, bh); VMW(6); SBAR();

        RD_A(A1, wr * 64); RD_B(bl, B1, wc * 32);
        stage_half(An2, lda, 128, A0, tid);
        SBAR(); QUAD(0, 0, bl); SBAR();

        RD_B(bh, B1, 128 + wc * 32);
        stage_half(An3, lda, 0, A1, tid);
        SBAR(); QUAD(0, 2, bh); SBAR();

        RD_A(A1, 128 + wr * 64);
        stage_half(Bn3, ldb, 0, B1, tid);
        SBAR(); QUAD(4, 0, bl); SBAR();

        stage_half(Bn3, ldb, 128, B1, tid);
        SBAR(); QUAD(4, 2, bh); VMW(6); SBAR();
    }

    {
        const ushort* An1 = Ag + (nk - 1) * 64;

        RD_A(A0, wr * 64); RD_B(bl, B0, wc * 32);
        stage_half(An1, lda, 128, A1, tid);
        SBAR(); QUAD(0, 0, bl); SBAR();

        RD_B(bh, B0, 128 + wc * 32);
        SBAR(); QUAD(0, 2, bh); SBAR();

        RD_A(A0, 128 + wr * 64);
        SBAR(); QUAD(4, 0, bl); SBAR();

        SBAR(); QUAD(4, 2, bh); VMW(0); SBAR();

        RD_A(A1, wr * 64); RD_B(bl, B1, wc * 32);
        SBAR(); QUAD(0, 0, bl); SBAR();

        RD_B(bh, B1, 128 + wc * 32);
        SBAR(); QUAD(0, 2, bh); SBAR();

        RD_A(A1, 128 + wr * 64);
        SBAR(); QUAD(4, 0, bl); SBAR();

        SBAR(); QUAD(4, 2, bh);
    }

#pragma unroll
    for (int m = 0; m < 8; m++) {
        const int row = (m >> 2) * 128 + wr * 64 + (m & 3) * 16 + lquad * 4;
        float rs[4] = {0.f, 0.f, 0.f, 0.f};
#pragma unroll
        for (int n = 0; n < 4; n++) {
            const int col = (n >> 1) * 128 + wc * 32 + (n & 1) * 16 + lrow;
#pragma unroll
            for (int j = 0; j < 4; j++) {
                float v = acc[m][n][j];
                if (EXP) {
                    float e = __expf(v * scale);
                    rs[j] += e;
                    Cg[(long long)(row + j) * ldc + col] = f2bf(e);
                } else {
                    Cg[(long long)(row + j) * ldc + col] = f2bf(v);
                }
            }
        }
        if (EXP) {
#pragma unroll
            for (int j = 0; j < 4; j++) {
                float s = rs[j];
                s += __shfl_xor(s, 1);
                s += __shfl_xor(s, 2);
                s += __shfl_xor(s, 4);
                s += __shfl_xor(s, 8);
                rs[j] = s;
            }
            if (lrow == 0) {
                const long long zi = ((long long)b * 32 + blockIdx.x * 4 + wc) * 2048
                                   + (long long)blockIdx.y * 256 + row;
#pragma unroll
                for (int j = 0; j < 4; j++) Zp[zi + j] = rs[j];
            }
        }
    }
}

// ---------------------------------------------------------------------------
// pv3: 128x256 tile, BK=64, 3-BUFFER depth-2 pipeline, ONE barrier per tile.
// LDS: A bufs 3x16KB @0, B bufs 3x32KB @49152 (144KB) + zbuf.
// Each tile = 6 vmem ops {A, Blo, Bhi}. Schedule:
//   prologue: stage T0,T1 (12 ops); VMW(6) lands T0; SBAR.
//   iter t: 12 ds_reads of buf t%3; stage T(t+2) -> (t+2)%3 (never equals the
//   buffer read this iter, and its last reader finished at the end-of-(t-1)
//   barrier -> WAR-safe); 32 MFMA; VMW(6) lands T(t+1) (outstanding 12 =
//   {t+1,t+2}); SBAR. Tail: t=nk-2 VMW(0); t=nk-1 no wait.
// zinv computed in-kernel from Zp partials (fixed order, deterministic).
// ---------------------------------------------------------------------------
__global__ __launch_bounds__(512, 2)
void pv3(const ushort* __restrict__ A, int lda, long long bsA,
         const ushort* __restrict__ Bt, int ldb, long long bsB,
         float* __restrict__ C, int ldc, long long bsC,
         int K, const float* __restrict__ Zp)
{
    __shared__ char smem[147456];
    __shared__ float zbuf[128];

    const int tid   = threadIdx.x;
    const int lane  = tid & 63;
    const int wave  = tid >> 6;
    const int wr    = wave >> 2;
    const int wc    = wave & 3;
    const int lrow  = lane & 15;
    const int lquad = lane >> 4;
    const long long b = blockIdx.z;

    if (tid < 128) {
        const float* p = Zp + b * 32 * 2048 + (long long)blockIdx.y * 128 + tid;
        float s = 0.f;
#pragma unroll
        for (int i = 0; i < 32; i++) s += p[i * 2048];
        zbuf[tid] = 1.0f / s;
    }
    __syncthreads();   // Zp loads drained before staging -> vmcnt counts clean

    const ushort* Ag = A  + b * bsA + (long long)blockIdx.y * 128 * lda;
    const ushort* Bg = Bt + b * bsB + (long long)blockIdx.x * 256 * ldb;
    float*        Cg = C  + b * bsC + (long long)blockIdx.y * 128 * ldc
                           + (long long)blockIdx.x * 256;

    f32x4 acc[4][4] = {};
    bf16x8 af[4][2], bl[2][2], bh[2][2];

    const int nk = K >> 6;

#define STAGE_TILE(T, I) do { \
        stage_half(Ag + (T) * 64, lda, 0,   smem + (I) * 16384,         tid); \
        stage_half(Bg + (T) * 64, ldb, 0,   smem + 49152 + (I) * 32768, tid); \
        stage_half(Bg + (T) * 64, ldb, 128, smem + 49152 + (I) * 32768, tid); \
    } while (0)

    STAGE_TILE(0, 0);
    STAGE_TILE(1, 1);
    VMW(6); SBAR();

    int cur = 0;
    for (int t = 0; t < nk; ++t) {
        const char* lAc = smem + cur * 16384;
        const char* lBc = smem + 49152 + cur * 32768;

        RD_A(lAc, wr * 64);
        RD_B(bl, lBc, wc * 32);
        RD_B(bh, lBc, 128 + wc * 32);

        if (t + 2 < nk) {
            int nxt = cur + 2; if (nxt >= 3) nxt -= 3;   // (t+2)%3
            STAGE_TILE(t + 2, nxt);
        }

        QUAD(0, 0, bl);
        QUAD(0, 2, bh);

        if (t + 1 < nk) {
            if (t + 2 < nk) { VMW(6); } else { VMW(0); }
            SBAR();
        }
        cur = (cur == 2) ? 0 : cur + 1;
    }
#undef STAGE_TILE

#pragma unroll
    for (int m = 0; m < 4; m++) {
        const int row = wr * 64 + m * 16 + lquad * 4;
        f32x4 z4 = *(const f32x4*)&zbuf[row];
#pragma unroll
        for (int n = 0; n < 4; n++) {
            const int col = (n >> 1) * 128 + wc * 32 + (n & 1) * 16 + lrow;
#pragma unroll
            for (int j = 0; j < 4; j++)
                storeval(&Cg[(long long)(row + j) * ldc + col], acc[m][n][j] * z4[j]);
        }
    }
}

// ---------------------------------------------------------------------------
// wgemm_splitk: BATCHED split-K weight GEMM. grid (8,8,4): z = pair*2 + ks.
// pair 0: C[e][d] = sum_c wkT[e][c]*wqT[d][c]  (= M^T rows of W2)
// pair 1: C[i][j] = sum_k wo[i][k]*wvT[j][k]   (= Wvo rows of W2)
// ---------------------------------------------------------------------------
__global__ __launch_bounds__(256)
void wgemm_splitk(const ushort* __restrict__ A0, const ushort* __restrict__ B0,
                  const ushort* __restrict__ A1, const ushort* __restrict__ B1,
                  float* __restrict__ P)
{
    __shared__ ushort lA[128 * 64];
    __shared__ ushort lB[128 * 64];

    const int z    = blockIdx.z;
    const int pair = z >> 1;
    const int ksl  = z & 1;

    const ushort* A  = pair ? A1 : A0;
    const ushort* Bt = pair ? B1 : B0;

    const int tid  = threadIdx.x;
    const int lane = tid & 63;
    const int wave = tid >> 6;
    const int wr   = wave >> 1;
    const int wc   = wave & 1;

    A  += (long long)blockIdx.y * 128 * 1024 + ksl * 512;
    Bt += (long long)blockIdx.x * 128 * 1024 + ksl * 512;
    float* Pg = P + (long long)z * 1048576
                  + (long long)blockIdx.y * 128 * 1024 + (long long)blockIdx.x * 128;

    f32x4 acc[4][4] = {};
    const int byte_base = wave * 1024 + lane * 16;

    for (int kt = 0; kt < 512; kt += 64) {
#pragma unroll
        for (int i = 0; i < 4; i++) {
            const int byte = i * 4096 + byte_base;
            const int row  = byte >> 7;
            const int k0   = (byte & 127) >> 1;
            GLDS(A  + (long long)row * 1024 + kt + k0, (char*)lA + byte);
            GLDS(Bt + (long long)row * 1024 + kt + k0, (char*)lB + byte);
        }
        __syncthreads();

#pragma unroll
        for (int ks = 0; ks < 2; ks++) {
            bf16x8 af2[4], bf2[4];
#pragma unroll
            for (int m = 0; m < 4; m++)
                af2[m] = *(const bf16x8*)&lA[(wr * 64 + m * 16 + (lane & 15)) * 64 + ks * 32 + (lane >> 4) * 8];
#pragma unroll
            for (int n = 0; n < 4; n++)
                bf2[n] = *(const bf16x8*)&lB[(wc * 64 + n * 16 + (lane & 15)) * 64 + ks * 32 + (lane >> 4) * 8];
#pragma unroll
            for (int m = 0; m < 4; m++)
#pragma unroll
                for (int n = 0; n < 4; n++)
                    acc[m][n] = __builtin_amdgcn_mfma_f32_16x16x32_bf16(af2[m], bf2[n], acc[m][n], 0, 0, 0);
        }
        __syncthreads();
    }

    const int r0 = wr * 64 + (lane >> 4) * 4;
    const int c0 = wc * 64 + (lane & 15);
#pragma unroll
    for (int m = 0; m < 4; m++)
#pragma unroll
        for (int n = 0; n < 4; n++)
#pragma unroll
            for (int j = 0; j < 4; j++)
                Pg[(long long)(r0 + m * 16 + j) * 1024 + c0 + n * 16] = acc[m][n][j];
}

// ---------------------------------------------------------------------------
__global__ __launch_bounds__(256)
void wreduce(const float* __restrict__ P, ushort* __restrict__ W2)
{
    const int i = blockIdx.x * 256 + threadIdx.x;      // 0..524287
    const int pair = i >> 18;
    const int off  = (i & 262143) * 4;
    const float* base = P + (long long)pair * 2097152 + off;
    float4 s = *(const float4*)(base);
    float4 v = *(const float4*)(base + 1048576);
    s.x += v.x; s.y += v.y; s.z += v.z; s.w += v.w;
    ushort o[4] = { f2bf(s.x), f2bf(s.y), f2bf(s.z), f2bf(s.w) };
    *(uint2*)&W2[(long long)pair * 1048576 + off] = *(const uint2*)&o[0];
}

// ---------------------------------------------------------------------------
__global__ __launch_bounds__(256)
void f32_to_bf16_vec(const float* __restrict__ in, ushort* __restrict__ out, int n4)
{
    int i = blockIdx.x * 256 + threadIdx.x;
    if (i >= n4) return;
    float4 v = ((const float4*)in)[i];
    ushort o[4] = { f2bf(v.x), f2bf(v.y), f2bf(v.z), f2bf(v.w) };
    *(uint2*)&out[(size_t)i * 4] = *(const uint2*)&o[0];
}

// ---------------------------------------------------------------------------
// wprep: BATCHED weight prep. z in {0,1,2}: transpose-convert wq/wk/wv into
// wT[z] (dst[j][k] = src[k][j], bf16). z == 3: plain convert wo -> wo_bf.
// ---------------------------------------------------------------------------
__global__ __launch_bounds__(256)
void wprep(const float* __restrict__ s0, const float* __restrict__ s1,
           const float* __restrict__ s2, const float* __restrict__ s3,
           ushort* __restrict__ wT, ushort* __restrict__ wo_bf)
{
    __shared__ float t[64][65];
    const int z = blockIdx.z;
    const int k0 = blockIdx.y * 64, j0 = blockIdx.x * 64;
    const int r = threadIdx.x >> 2;
    const int c = (threadIdx.x & 3) * 16;

    if (z == 3) {
        const float* p = s3 + (size_t)(k0 + r) * 1024 + j0 + c;
        float4 a = *(const float4*)(p);
        float4 bq = *(const float4*)(p + 4);
        float4 cc = *(const float4*)(p + 8);
        float4 d = *(const float4*)(p + 12);
        ushort o[16] = { f2bf(a.x), f2bf(a.y), f2bf(a.z), f2bf(a.w),
                         f2bf(bq.x), f2bf(bq.y), f2bf(bq.z), f2bf(bq.w),
                         f2bf(cc.x), f2bf(cc.y), f2bf(cc.z), f2bf(cc.w),
                         f2bf(d.x), f2bf(d.y), f2bf(d.z), f2bf(d.w) };
        ushort* q = wo_bf + (size_t)(k0 + r) * 1024 + j0 + c;
        *(uint4*)q       = *(const uint4*)&o[0];
        *(uint4*)(q + 8) = *(const uint4*)&o[8];
        return;
    }

    const float* src = (z == 0) ? s0 : (z == 1) ? s1 : s2;
    ushort* dst = wT + (size_t)z * 1048576;

    const float* p = src + (size_t)(k0 + r) * 1024 + j0 + c;
#pragma unroll
    for (int j = 0; j < 16; j++) t[r][c + j] = p[j];
    __syncthreads();

    ushort o[16];
#pragma unroll
    for (int j = 0; j < 16; j++) o[j] = f2bf(t[c + j][r]);
    ushort* q = dst + (size_t)(j0 + r) * 1024 + k0 + c;
    *(uint4*)q       = *(const uint4*)&o[0];
    *(uint4*)(q + 8) = *(const uint4*)&o[8];
}

// ---------------------------------------------------------------------------
__global__ __launch_bounds__(256)
void transpose_v(const ushort* __restrict__ V, int ldv, long long bsV,
                 ushort* __restrict__ Vt)
{
    __shared__ ushort t[64][65];
    const int b = blockIdx.z;
    const ushort* src = V  + (size_t)b * bsV;
    ushort*       dst = Vt + (size_t)b * 1024 * 2048;
    const int e0 = blockIdx.x * 64;
    const int k0 = blockIdx.y * 64;
    const int r = threadIdx.x >> 2;
    const int c = (threadIdx.x & 3) * 16;

    const ushort* p = &src[(size_t)(k0 + r) * ldv + e0 + c];
    ushort vals[16];
    *(uint4*)&vals[0] = *(const uint4*)p;
    *(uint4*)&vals[8] = *(const uint4*)(p + 8);
#pragma unroll
    for (int j = 0; j < 16; j++) t[r][c + j] = vals[j];
    __syncthreads();

    ushort o[16];
#pragma unroll
    for (int j = 0; j < 16; j++) o[j] = t[c + j][r];
    ushort* q = &dst[(size_t)(e0 + r) * 2048 + k0 + c];
    *(uint4*)q       = *(const uint4*)&o[0];
    *(uint4*)(q + 8) = *(const uint4*)&o[8];
}

// ---------------------------------------------------------------------------
extern "C" void kernel_launch(void* const* d_in, const int* in_sizes, int n_in,
                              void* d_out, int out_size, void* d_ws, size_t ws_size,
                              hipStream_t stream)
{
    const float* x  = (const float*)d_in[0];
    const float* wq = (const float*)d_in[1];
    const float* wk = (const float*)d_in[2];
    const float* wv = (const float*)d_in[3];
    const float* wo = (const float*)d_in[4];
    float* out = (float*)d_out;

    // B=4, S=2048, D=1024; M = 8192
    // Algebra: scores = x·M·x^T with M = Wq^T·Wk  (K-projection eliminated);
    //          out    = P·x·Wvo^T · (1/Z) with Wvo = Wo·Wv (out-proj eliminated).
    // W2 = [ M^T ; Wvo ]  [2048][1024] bf16 -> TVw = xb @ W2^T  [8192][2048].
    char* ws = (char*)d_ws;
    ushort* xb    = (ushort*)(ws);                 // 16 MB  [8192][1024]
    ushort* W2    = (ushort*)(ws + 16777216);      //  4 MB  [2048][1024]
    ushort* wT    = (ushort*)(ws + 20971520);      //  6 MB  wqT|wkT|wvT
    ushort* wo_bf = (ushort*)(ws + 27262976);      //  2 MB
    ushort* TVw   = (ushort*)(ws + 29360128);      // 32 MB  [8192][2048] (T | Vw)
    ushort* Vtb   = (ushort*)(ws + 62914560);      // 16 MB  [4][1024][2048]
    ushort* E     = (ushort*)(ws + 79691776);      // 32 MB  [4][2048][2048]
    float*  Pp    = (float*)(ws + 79691776);       // 16 MB  ALIAS of E (used before E)
    float*  Zp    = (float*)(ws + 113246208);      //  1 MB  [4][32][2048]

    ushort* wqT = wT;
    ushort* wkT = wT + 1048576;
    ushort* wvT = wT + 2097152;

    // 1. converts / transposes (batched: z<3 transpose wq/wk/wv, z=3 wo)
    f32_to_bf16_vec<<<8192, 256, 0, stream>>>(x, xb, 2097152);
    wprep<<<dim3(16, 16, 4), 256, 0, stream>>>(wq, wk, wv, wo, wT, wo_bf);

    // 2. W2 rows 0-1023: M^T = Wk^T·Wq ; rows 1024-2047: Wvo = Wo·Wv
    wgemm_splitk<<<dim3(8, 8, 4), 256, 0, stream>>>(wkT, wqT, wo_bf, wvT, Pp);
    wreduce<<<2048, 256, 0, stream>>>(Pp, W2);

    // 3. TVw = xb @ W2^T  [8192][2048]   (256 blocks = 1 exact round)
    gemm256_8ph<false><<<dim3(8, 32, 1), 512, 0, stream>>>(
        xb, 1024, 0, W2, 1024, 0, TVw, 2048, 0, 1024, 1.f, nullptr);

    // 4. Vw^T per batch -> [b][1024][2048]
    transpose_v<<<dim3(16, 32, 4), 256, 0, stream>>>(TVw + 1024, 2048, 2048LL * 2048, Vtb);

    // 5. E = exp(T x^T / 32) bf16 + row-sum partials   (256 blocks)
    gemm256_8ph<true><<<dim3(8, 8, 4), 512, 0, stream>>>(
        TVw, 2048, 2048LL * 2048, xb, 1024, 2048LL * 1024,
        E, 2048, 2048LL * 2048, 1024, 0.03125f, Zp);

    // 6. out = (E @ Vw) * (1/Z from Zp, in-kernel) -> fp32 d_out  (256 blocks)
    //    3-buffer depth-2 pipeline (pv3)
    pv3<<<dim3(4, 16, 4), 512, 0, stream>>>(
        E, 2048, 2048LL * 2048, Vtb, 2048, 1024LL * 2048,
        out, 1024, 2048LL * 1024, 2048, Zp);
}

// Round 13
// 155.181 us; speedup vs baseline: 1.3525x; 1.0600x over previous
//
#include <hip/hip_runtime.h>

typedef unsigned int uint;
typedef unsigned short ushort;
typedef __bf16 bf16x8 __attribute__((ext_vector_type(8)));
typedef float f32x4 __attribute__((ext_vector_type(4)));

__device__ __forceinline__ ushort f2bf(float v) {
    uint u = __builtin_bit_cast(uint, v);
    u += 0x7fffu + ((u >> 16) & 1u);   // RNE
    return (ushort)(u >> 16);
}

__device__ __forceinline__ void storeval(float* p, float v)  { *p = v; }
__device__ __forceinline__ void storeval(ushort* p, float v) { *p = f2bf(v); }

#define GLDS(g, l) __builtin_amdgcn_global_load_lds( \
    (const __attribute__((address_space(1))) uint*)(g), \
    (__attribute__((address_space(3))) uint*)(l), 16, 0, 0)

#define VMW(N)  asm volatile("s_waitcnt vmcnt(" #N ")" ::: "memory")
#define SBAR()  asm volatile("s_barrier" ::: "memory")

// Stage 128 rows x 64 cols bf16 (16KB) = one half-tile = 2 gload_lds/thread.
// LDS swizzle: 16B-slot s of row r stored at slot s^(r&7); pre-swizzled
// GLOBAL source (linear LDS dest, rule #21); reads apply the same XOR.
__device__ __forceinline__ void stage_half(const ushort* __restrict__ src, int ld,
                                           int halfrow, char* ldsbase, int tid)
{
#pragma unroll
    for (int i = 0; i < 2; i++) {
        const int byte = i * 8192 + tid * 16;
        const int row  = byte >> 7;
        const int slot = (byte >> 4) & 7;
        const int srcs = slot ^ (row & 7);
        GLDS(src + (long long)(halfrow + row) * ld + srcs * 8,
             ldsbase + halfrow * 128 + byte);
    }
}

__device__ __forceinline__ bf16x8 ldf(const char* base, int rbase, int ks,
                                      int lrow, int lquad)
{
    const int r    = rbase + lrow;
    const int slot = ((ks << 2) + lquad) ^ (r & 7);
    return *(const bf16x8*)(base + r * 128 + slot * 16);
}

#define RD_A(BASE, ROFF) \
    _Pragma("unroll") for (int m_ = 0; m_ < 4; m_++) \
    _Pragma("unroll") for (int k_ = 0; k_ < 2; k_++) \
        af[m_][k_] = ldf(BASE, (ROFF) + m_ * 16, k_, lrow, lquad);

#define RD_B(DST, BASE, ROFF) \
    _Pragma("unroll") for (int n_ = 0; n_ < 2; n_++) \
    _Pragma("unroll") for (int k_ = 0; k_ < 2; k_++) \
        DST[n_][k_] = ldf(BASE, (ROFF) + n_ * 16, k_, lrow, lquad);

// R5-verified (non-swapped) MFMA quad: mfma(A, B).
#define QUAD(MOFF, NOFF, B) \
    __builtin_amdgcn_s_setprio(1); \
    _Pragma("unroll") for (int m_ = 0; m_ < 4; m_++) \
    _Pragma("unroll") for (int n_ = 0; n_ < 2; n_++) \
    _Pragma("unroll") for (int k_ = 0; k_ < 2; k_++) \
        acc[(MOFF) + m_][(NOFF) + n_] = __builtin_amdgcn_mfma_f32_16x16x32_bf16( \
            af[m_][k_], B[n_][k_], acc[(MOFF) + m_][(NOFF) + n_], 0, 0, 0); \
    __builtin_amdgcn_s_setprio(0);

// ---------------------------------------------------------------------------
// gemm256_8ph: 256x256 tile, BK=64, 8-phase counted-vmcnt (R5/R9-verified).
// EXP: e=exp(acc*scale) -> bf16 C + per-wave row sums -> Zp.
// !EXP with Vt != nullptr (TVw mode): blocks x<4 write T packed into C
// (ldc=1024); blocks x>=4 write the Vw half DIRECTLY TRANSPOSED into
// Vt[b][e][k] (e=global col-1024, k=row) — identical bf16 bits to the old
// transpose_v path, which this replaces.
// ---------------------------------------------------------------------------
template<bool EXP>
__global__ __launch_bounds__(512, 2)
void gemm256_8ph(const ushort* __restrict__ A, int lda, long long bsA,
                 const ushort* __restrict__ Bt, int ldb, long long bsB,
                 ushort* __restrict__ C, int ldc, long long bsC,
                 int K, float scale, float* __restrict__ Zp,
                 ushort* __restrict__ Vt)
{
    __shared__ char smem[131072];
    char* A0 = smem;
    char* A1 = smem + 32768;
    char* B0 = smem + 65536;
    char* B1 = smem + 98304;

    const int tid   = threadIdx.x;
    const int lane  = tid & 63;
    const int wave  = tid >> 6;
    const int wr    = wave >> 2;
    const int wc    = wave & 3;
    const int lrow  = lane & 15;
    const int lquad = lane >> 4;
    const long long b = blockIdx.z;

    const ushort* Ag = A  + b * bsA + (long long)blockIdx.y * 256 * lda;
    const ushort* Bg = Bt + b * bsB + (long long)blockIdx.x * 256 * ldb;

    f32x4 acc[8][4] = {};
    bf16x8 af[4][2], bl[2][2], bh[2][2];

    const int nk    = K >> 6;
    const int nIter = nk >> 1;

    stage_half(Ag,      lda, 0,   A0, tid);
    stage_half(Bg,      ldb, 0,   B0, tid);
    stage_half(Bg,      ldb, 128, B0, tid);
    stage_half(Ag,      lda, 128, A0, tid);
    stage_half(Ag + 64, lda, 0,   A1, tid);
    stage_half(Bg + 64, ldb, 0,   B1, tid);
    stage_half(Bg + 64, ldb, 128, B1, tid);
    VMW(6); SBAR();

    for (int i = 0; i < nIter - 1; ++i) {
        const ushort* An1 = Ag + (2 * i + 1) * 64;
        const ushort* An2 = Ag + (2 * i + 2) * 64;
        const ushort* Bn2 = Bg + (2 * i + 2) * 64;
        const ushort* An3 = Ag + (2 * i + 3) * 64;
        const ushort* Bn3 = Bg + (2 * i + 3) * 64;

        RD_A(A0, wr * 64); RD_B(bl, B0, wc * 32);
        stage_half(An1, lda, 128, A1, tid);
        SBAR(); QUAD(0, 0, bl); SBAR();

        RD_B(bh, B0, 128 + wc * 32);
        stage_half(An2, lda, 0, A0, tid);
        SBAR(); QUAD(0, 2, bh); SBAR();

        RD_A(A0, 128 + wr * 64);
        stage_half(Bn2, ldb, 0, B0, tid);
        SBAR(); QUAD(4, 0, bl); SBAR();

        stage_half(Bn2, ldb, 128, B0, tid);
        SBAR(); QUAD(4, 2, bh); VMW(6); SBAR();

        RD_A(A1, wr * 64); RD_B(bl, B1, wc * 32);
        stage_half(An2, lda, 128, A0, tid);
        SBAR(); QUAD(0, 0, bl); SBAR();

        RD_B(bh, B1, 128 + wc * 32);
        stage_half(An3, lda, 0, A1, tid);
        SBAR(); QUAD(0, 2, bh); SBAR();

        RD_A(A1, 128 + wr * 64);
        stage_half(Bn3, ldb, 0, B1, tid);
        SBAR(); QUAD(4, 0, bl); SBAR();

        stage_half(Bn3, ldb, 128, B1, tid);
        SBAR(); QUAD(4, 2, bh); VMW(6); SBAR();
    }

    {
        const ushort* An1 = Ag + (nk - 1) * 64;

        RD_A(A0, wr * 64); RD_B(bl, B0, wc * 32);
        stage_half(An1, lda, 128, A1, tid);
        SBAR(); QUAD(0, 0, bl); SBAR();

        RD_B(bh, B0, 128 + wc * 32);
        SBAR(); QUAD(0, 2, bh); SBAR();

        RD_A(A0, 128 + wr * 64);
        SBAR(); QUAD(4, 0, bl); SBAR();

        SBAR(); QUAD(4, 2, bh); VMW(0); SBAR();

        RD_A(A1, wr * 64); RD_B(bl, B1, wc * 32);
        SBAR(); QUAD(0, 0, bl); SBAR();

        RD_B(bh, B1, 128 + wc * 32);
        SBAR(); QUAD(0, 2, bh); SBAR();

        RD_A(A1, 128 + wr * 64);
        SBAR(); QUAD(4, 0, bl); SBAR();

        SBAR(); QUAD(4, 2, bh);
    }

    if (!EXP && Vt != nullptr && blockIdx.x >= 4) {
        // Vw half -> transposed store into Vt[b2][e][k]
        const int b2 = (int)(blockIdx.y >> 3);
        const int kb = (int)(blockIdx.y & 7) * 256;
        ushort* Vg = Vt + (long long)b2 * 1024 * 2048
                   + (long long)(blockIdx.x - 4) * 256 * 2048 + kb;
#pragma unroll
        for (int m = 0; m < 8; m++) {
            const int row = (m >> 2) * 128 + wr * 64 + (m & 3) * 16 + lquad * 4;
#pragma unroll
            for (int n = 0; n < 4; n++) {
                const int col = (n >> 1) * 128 + wc * 32 + (n & 1) * 16 + lrow;
                ushort o[4] = { f2bf(acc[m][n][0]), f2bf(acc[m][n][1]),
                                f2bf(acc[m][n][2]), f2bf(acc[m][n][3]) };
                *(uint2*)&Vg[(long long)col * 2048 + row] = *(const uint2*)&o[0];
            }
        }
        return;
    }

    ushort* Cg = C + b * bsC + (long long)blockIdx.y * 256 * ldc
                   + (long long)blockIdx.x * 256;

#pragma unroll
    for (int m = 0; m < 8; m++) {
        const int row = (m >> 2) * 128 + wr * 64 + (m & 3) * 16 + lquad * 4;
        float rs[4] = {0.f, 0.f, 0.f, 0.f};
#pragma unroll
        for (int n = 0; n < 4; n++) {
            const int col = (n >> 1) * 128 + wc * 32 + (n & 1) * 16 + lrow;
#pragma unroll
            for (int j = 0; j < 4; j++) {
                float v = acc[m][n][j];
                if (EXP) {
                    float e = __expf(v * scale);
                    rs[j] += e;
                    Cg[(long long)(row + j) * ldc + col] = f2bf(e);
                } else {
                    Cg[(long long)(row + j) * ldc + col] = f2bf(v);
                }
            }
        }
        if (EXP) {
#pragma unroll
            for (int j = 0; j < 4; j++) {
                float s = rs[j];
                s += __shfl_xor(s, 1);
                s += __shfl_xor(s, 2);
                s += __shfl_xor(s, 4);
                s += __shfl_xor(s, 8);
                rs[j] = s;
            }
            if (lrow == 0) {
                const long long zi = ((long long)b * 32 + blockIdx.x * 4 + wc) * 2048
                                   + (long long)blockIdx.y * 256 + row;
#pragma unroll
                for (int j = 0; j < 4; j++) Zp[zi + j] = rs[j];
            }
        }
    }
}

// ---------------------------------------------------------------------------
// pv3: 128x256 tile, BK=64, 3-BUFFER depth-2 pipeline, ONE barrier per tile
// (R12-verified). zinv computed in-kernel from Zp partials (fixed order).
// ---------------------------------------------------------------------------
__global__ __launch_bounds__(512, 2)
void pv3(const ushort* __restrict__ A, int lda, long long bsA,
         const ushort* __restrict__ Bt, int ldb, long long bsB,
         float* __restrict__ C, int ldc, long long bsC,
         int K, const float* __restrict__ Zp)
{
    __shared__ char smem[147456];
    __shared__ float zbuf[128];

    const int tid   = threadIdx.x;
    const int lane  = tid & 63;
    const int wave  = tid >> 6;
    const int wr    = wave >> 2;
    const int wc    = wave & 3;
    const int lrow  = lane & 15;
    const int lquad = lane >> 4;
    const long long b = blockIdx.z;

    if (tid < 128) {
        const float* p = Zp + b * 32 * 2048 + (long long)blockIdx.y * 128 + tid;
        float s = 0.f;
#pragma unroll
        for (int i = 0; i < 32; i++) s += p[i * 2048];
        zbuf[tid] = 1.0f / s;
    }
    __syncthreads();   // Zp loads drained before staging -> vmcnt counts clean

    const ushort* Ag = A  + b * bsA + (long long)blockIdx.y * 128 * lda;
    const ushort* Bg = Bt + b * bsB + (long long)blockIdx.x * 256 * ldb;
    float*        Cg = C  + b * bsC + (long long)blockIdx.y * 128 * ldc
                           + (long long)blockIdx.x * 256;

    f32x4 acc[4][4] = {};
    bf16x8 af[4][2], bl[2][2], bh[2][2];

    const int nk = K >> 6;

#define STAGE_TILE(T, I) do { \
        stage_half(Ag + (T) * 64, lda, 0,   smem + (I) * 16384,         tid); \
        stage_half(Bg + (T) * 64, ldb, 0,   smem + 49152 + (I) * 32768, tid); \
        stage_half(Bg + (T) * 64, ldb, 128, smem + 49152 + (I) * 32768, tid); \
    } while (0)

    STAGE_TILE(0, 0);
    STAGE_TILE(1, 1);
    VMW(6); SBAR();

    int cur = 0;
    for (int t = 0; t < nk; ++t) {
        const char* lAc = smem + cur * 16384;
        const char* lBc = smem + 49152 + cur * 32768;

        RD_A(lAc, wr * 64);
        RD_B(bl, lBc, wc * 32);
        RD_B(bh, lBc, 128 + wc * 32);

        if (t + 2 < nk) {
            int nxt = cur + 2; if (nxt >= 3) nxt -= 3;   // (t+2)%3
            STAGE_TILE(t + 2, nxt);
        }

        QUAD(0, 0, bl);
        QUAD(0, 2, bh);

        if (t + 1 < nk) {
            if (t + 2 < nk) { VMW(6); } else { VMW(0); }
            SBAR();
        }
        cur = (cur == 2) ? 0 : cur + 1;
    }
#undef STAGE_TILE

#pragma unroll
    for (int m = 0; m < 4; m++) {
        const int row = wr * 64 + m * 16 + lquad * 4;
        f32x4 z4 = *(const f32x4*)&zbuf[row];
#pragma unroll
        for (int n = 0; n < 4; n++) {
            const int col = (n >> 1) * 128 + wc * 32 + (n & 1) * 16 + lrow;
#pragma unroll
            for (int j = 0; j < 4; j++)
                storeval(&Cg[(long long)(row + j) * ldc + col], acc[m][n][j] * z4[j]);
        }
    }
}

// ---------------------------------------------------------------------------
// wgemm_splitk: BATCHED split-K weight GEMM. grid (8,8,4): z = pair*2 + ks.
// pair 0: C[e][d] = sum_c wkT[e][c]*wqT[d][c]  (= M^T rows of W2)
// pair 1: C[i][j] = sum_k wo[i][k]*wvT[j][k]   (= Wvo rows of W2)
// ---------------------------------------------------------------------------
__global__ __launch_bounds__(256)
void wgemm_splitk(const ushort* __restrict__ A0, const ushort* __restrict__ B0,
                  const ushort* __restrict__ A1, const ushort* __restrict__ B1,
                  float* __restrict__ P)
{
    __shared__ ushort lA[128 * 64];
    __shared__ ushort lB[128 * 64];

    const int z    = blockIdx.z;
    const int pair = z >> 1;
    const int ksl  = z & 1;

    const ushort* A  = pair ? A1 : A0;
    const ushort* Bt = pair ? B1 : B0;

    const int tid  = threadIdx.x;
    const int lane = tid & 63;
    const int wave = tid >> 6;
    const int wr   = wave >> 1;
    const int wc   = wave & 1;

    A  += (long long)blockIdx.y * 128 * 1024 + ksl * 512;
    Bt += (long long)blockIdx.x * 128 * 1024 + ksl * 512;
    float* Pg = P + (long long)z * 1048576
                  + (long long)blockIdx.y * 128 * 1024 + (long long)blockIdx.x * 128;

    f32x4 acc[4][4] = {};
    const int byte_base = wave * 1024 + lane * 16;

    for (int kt = 0; kt < 512; kt += 64) {
#pragma unroll
        for (int i = 0; i < 4; i++) {
            const int byte = i * 4096 + byte_base;
            const int row  = byte >> 7;
            const int k0   = (byte & 127) >> 1;
            GLDS(A  + (long long)row * 1024 + kt + k0, (char*)lA + byte);
            GLDS(Bt + (long long)row * 1024 + kt + k0, (char*)lB + byte);
        }
        __syncthreads();

#pragma unroll
        for (int ks = 0; ks < 2; ks++) {
            bf16x8 af2[4], bf2[4];
#pragma unroll
            for (int m = 0; m < 4; m++)
                af2[m] = *(const bf16x8*)&lA[(wr * 64 + m * 16 + (lane & 15)) * 64 + ks * 32 + (lane >> 4) * 8];
#pragma unroll
            for (int n = 0; n < 4; n++)
                bf2[n] = *(const bf16x8*)&lB[(wc * 64 + n * 16 + (lane & 15)) * 64 + ks * 32 + (lane >> 4) * 8];
#pragma unroll
            for (int m = 0; m < 4; m++)
#pragma unroll
                for (int n = 0; n < 4; n++)
                    acc[m][n] = __builtin_amdgcn_mfma_f32_16x16x32_bf16(af2[m], bf2[n], acc[m][n], 0, 0, 0);
        }
        __syncthreads();
    }

    const int r0 = wr * 64 + (lane >> 4) * 4;
    const int c0 = wc * 64 + (lane & 15);
#pragma unroll
    for (int m = 0; m < 4; m++)
#pragma unroll
        for (int n = 0; n < 4; n++)
#pragma unroll
            for (int j = 0; j < 4; j++)
                Pg[(long long)(r0 + m * 16 + j) * 1024 + c0 + n * 16] = acc[m][n][j];
}

// ---------------------------------------------------------------------------
__global__ __launch_bounds__(256)
void wreduce(const float* __restrict__ P, ushort* __restrict__ W2)
{
    const int i = blockIdx.x * 256 + threadIdx.x;      // 0..524287
    const int pair = i >> 18;
    const int off  = (i & 262143) * 4;
    const float* base = P + (long long)pair * 2097152 + off;
    float4 s = *(const float4*)(base);
    float4 v = *(const float4*)(base + 1048576);
    s.x += v.x; s.y += v.y; s.z += v.z; s.w += v.w;
    ushort o[4] = { f2bf(s.x), f2bf(s.y), f2bf(s.z), f2bf(s.w) };
    *(uint2*)&W2[(long long)pair * 1048576 + off] = *(const uint2*)&o[0];
}

// ---------------------------------------------------------------------------
// prep: MERGED input convert + weight prep (one launch, 9216 blocks).
//   blocks 0..8191   : x fp32 -> xb bf16 (float4-vectorized)
//   blocks 8192..9215: idx -> (z, by, bx); z<3: transpose-convert wq/wk/wv
//                      into wT[z]; z==3: plain convert wo -> wo_bf.
// ---------------------------------------------------------------------------
__global__ __launch_bounds__(256)
void prep(const float* __restrict__ x, ushort* __restrict__ xb,
          const float* __restrict__ s0, const float* __restrict__ s1,
          const float* __restrict__ s2, const float* __restrict__ s3,
          ushort* __restrict__ wT, ushort* __restrict__ wo_bf)
{
    __shared__ float t[64][65];

    if (blockIdx.x < 8192) {
        const int i = blockIdx.x * 256 + threadIdx.x;
        float4 v = ((const float4*)x)[i];
        ushort o[4] = { f2bf(v.x), f2bf(v.y), f2bf(v.z), f2bf(v.w) };
        *(uint2*)&xb[(size_t)i * 4] = *(const uint2*)&o[0];
        return;
    }

    const int idx = blockIdx.x - 8192;     // 0..1023
    const int z   = idx >> 8;              // 0..3
    const int r2  = idx & 255;
    const int by  = r2 >> 4;
    const int bx  = r2 & 15;
    const int k0 = by * 64, j0 = bx * 64;
    const int r = threadIdx.x >> 2;
    const int c = (threadIdx.x & 3) * 16;

    if (z == 3) {
        const float* p = s3 + (size_t)(k0 + r) * 1024 + j0 + c;
        ushort o[16];
#pragma unroll
        for (int j = 0; j < 16; j++) o[j] = f2bf(p[j]);
        ushort* q = wo_bf + (size_t)(k0 + r) * 1024 + j0 + c;
        *(uint4*)q       = *(const uint4*)&o[0];
        *(uint4*)(q + 8) = *(const uint4*)&o[8];
        return;
    }

    const float* src = (z == 0) ? s0 : (z == 1) ? s1 : s2;
    ushort* dst = wT + (size_t)z * 1048576;

    const float* p = src + (size_t)(k0 + r) * 1024 + j0 + c;
#pragma unroll
    for (int j = 0; j < 16; j++) t[r][c + j] = p[j];
    __syncthreads();

    ushort o[16];
#pragma unroll
    for (int j = 0; j < 16; j++) o[j] = f2bf(t[c + j][r]);
    ushort* q = dst + (size_t)(j0 + r) * 1024 + k0 + c;
    *(uint4*)q       = *(const uint4*)&o[0];
    *(uint4*)(q + 8) = *(const uint4*)&o[8];
}

// ---------------------------------------------------------------------------
extern "C" void kernel_launch(void* const* d_in, const int* in_sizes, int n_in,
                              void* d_out, int out_size, void* d_ws, size_t ws_size,
                              hipStream_t stream)
{
    const float* x  = (const float*)d_in[0];
    const float* wq = (const float*)d_in[1];
    const float* wk = (const float*)d_in[2];
    const float* wv = (const float*)d_in[3];
    const float* wo = (const float*)d_in[4];
    float* out = (float*)d_out;

    // B=4, S=2048, D=1024; M = 8192
    // Algebra: scores = x·M·x^T with M = Wq^T·Wk  (K-projection eliminated);
    //          out    = P·x·Wvo^T · (1/Z) with Wvo = Wo·Wv (out-proj eliminated).
    // W2 = [ M^T ; Wvo ] [2048][1024]. One GEMM produces T (packed Tbuf) and
    // Vw (written transposed straight into Vtb — no transpose_v pass).
    char* ws = (char*)d_ws;
    ushort* xb    = (ushort*)(ws);                 // 16 MB  [8192][1024]
    ushort* W2    = (ushort*)(ws + 16777216);      //  4 MB  [2048][1024]
    ushort* wT    = (ushort*)(ws + 20971520);      //  6 MB  wqT|wkT|wvT
    ushort* wo_bf = (ushort*)(ws + 27262976);      //  2 MB
    ushort* Tbuf  = (ushort*)(ws + 29360128);      // 16 MB  [8192][1024]
    ushort* Vtb   = (ushort*)(ws + 46137344);      // 16 MB  [4][1024][2048]
    ushort* E     = (ushort*)(ws + 62914560);      // 32 MB  [4][2048][2048]
    float*  Pp    = (float*)(ws + 62914560);       // 16 MB  ALIAS of E (used before E)
    float*  Zp    = (float*)(ws + 96468992);       //  1 MB  [4][32][2048]

    ushort* wqT = wT;
    ushort* wkT = wT + 1048576;
    ushort* wvT = wT + 2097152;

    // 1. merged converts/transposes (x + wq/wk/wv/wo), one launch
    prep<<<9216, 256, 0, stream>>>(x, xb, wq, wk, wv, wo, wT, wo_bf);

    // 2. W2 rows 0-1023: M^T = Wk^T·Wq ; rows 1024-2047: Wvo = Wo·Wv
    wgemm_splitk<<<dim3(8, 8, 4), 256, 0, stream>>>(wkT, wqT, wo_bf, wvT, Pp);
    wreduce<<<2048, 256, 0, stream>>>(Pp, W2);

    // 3. [T | Vw] = xb @ W2^T: T -> Tbuf packed (x<4); Vw -> Vtb transposed (x>=4)
    gemm256_8ph<false><<<dim3(8, 32, 1), 512, 0, stream>>>(
        xb, 1024, 0, W2, 1024, 0, Tbuf, 1024, 0, 1024, 1.f, nullptr, Vtb);

    // 4. E = exp(T x^T / 32) bf16 + row-sum partials   (256 blocks)
    gemm256_8ph<true><<<dim3(8, 8, 4), 512, 0, stream>>>(
        Tbuf, 1024, 2048LL * 1024, xb, 1024, 2048LL * 1024,
        E, 2048, 2048LL * 2048, 1024, 0.03125f, Zp, nullptr);

    // 5. out = (E @ Vw) * (1/Z from Zp, in-kernel) -> fp32 d_out  (256 blocks)
    pv3<<<dim3(4, 16, 4), 512, 0, stream>>>(
        E, 2048, 2048LL * 2048, Vtb, 2048, 1024LL * 2048,
        out, 1024, 2048LL * 1024, 2048, Zp);
}

// Round 15
// 154.736 us; speedup vs baseline: 1.3564x; 1.0029x over previous
//
#include <hip/hip_runtime.h>

typedef unsigned int uint;
typedef unsigned short ushort;
typedef __bf16 bf16x8 __attribute__((ext_vector_type(8)));
typedef float f32x4 __attribute__((ext_vector_type(4)));

__device__ __forceinline__ ushort f2bf(float v) {
    uint u = __builtin_bit_cast(uint, v);
    u += 0x7fffu + ((u >> 16) & 1u);   // RNE
    return (ushort)(u >> 16);
}

__device__ __forceinline__ void storeval(float* p, float v)  { *p = v; }
__device__ __forceinline__ void storeval(ushort* p, float v) { *p = f2bf(v); }

#define GLDS(g, l) __builtin_amdgcn_global_load_lds( \
    (const __attribute__((address_space(1))) uint*)(g), \
    (__attribute__((address_space(3))) uint*)(l), 16, 0, 0)

#define VMW(N)  asm volatile("s_waitcnt vmcnt(" #N ")" ::: "memory")
#define SBAR()  asm volatile("s_barrier" ::: "memory")

// Stage 128 rows x 64 cols bf16 (16KB) = one half-tile = 2 gload_lds/thread.
// LDS swizzle: 16B-slot s of row r stored at slot s^(r&7); pre-swizzled
// GLOBAL source (linear LDS dest, rule #21); reads apply the same XOR.
__device__ __forceinline__ void stage_half(const ushort* __restrict__ src, int ld,
                                           int halfrow, char* ldsbase, int tid)
{
#pragma unroll
    for (int i = 0; i < 2; i++) {
        const int byte = i * 8192 + tid * 16;
        const int row  = byte >> 7;
        const int slot = (byte >> 4) & 7;
        const int srcs = slot ^ (row & 7);
        GLDS(src + (long long)(halfrow + row) * ld + srcs * 8,
             ldsbase + halfrow * 128 + byte);
    }
}

__device__ __forceinline__ bf16x8 ldf(const char* base, int rbase, int ks,
                                      int lrow, int lquad)
{
    const int r    = rbase + lrow;
    const int slot = ((ks << 2) + lquad) ^ (r & 7);
    return *(const bf16x8*)(base + r * 128 + slot * 16);
}

#define RD_A(BASE, ROFF) \
    _Pragma("unroll") for (int m_ = 0; m_ < 4; m_++) \
    _Pragma("unroll") for (int k_ = 0; k_ < 2; k_++) \
        af[m_][k_] = ldf(BASE, (ROFF) + m_ * 16, k_, lrow, lquad);

#define RD_B(DST, BASE, ROFF) \
    _Pragma("unroll") for (int n_ = 0; n_ < 2; n_++) \
    _Pragma("unroll") for (int k_ = 0; k_ < 2; k_++) \
        DST[n_][k_] = ldf(BASE, (ROFF) + n_ * 16, k_, lrow, lquad);

// R5-verified (non-swapped) MFMA quad: mfma(A, B).
#define QUAD(MOFF, NOFF, B) \
    __builtin_amdgcn_s_setprio(1); \
    _Pragma("unroll") for (int m_ = 0; m_ < 4; m_++) \
    _Pragma("unroll") for (int n_ = 0; n_ < 2; n_++) \
    _Pragma("unroll") for (int k_ = 0; k_ < 2; k_++) \
        acc[(MOFF) + m_][(NOFF) + n_] = __builtin_amdgcn_mfma_f32_16x16x32_bf16( \
            af[m_][k_], B[n_][k_], acc[(MOFF) + m_][(NOFF) + n_], 0, 0, 0); \
    __builtin_amdgcn_s_setprio(0);

// ---------------------------------------------------------------------------
// gemm256_8ph: 256x256 tile, BK=64, 8-phase counted-vmcnt (R5/R9-verified).
// EXP: e=exp(acc*scale) -> bf16 C + per-wave row sums -> Zp.
// !EXP with Vt != nullptr (TVw mode): blocks x<4 write T packed into C
// (ldc=1024); blocks x>=4 write the Vw half DIRECTLY TRANSPOSED into
// Vt[b][e][k] (e=global col-1024, k=row) — identical bf16 bits to the old
// transpose_v path, which this replaces.
// ---------------------------------------------------------------------------
template<bool EXP>
__global__ __launch_bounds__(512, 2)
void gemm256_8ph(const ushort* __restrict__ A, int lda, long long bsA,
                 const ushort* __restrict__ Bt, int ldb, long long bsB,
                 ushort* __restrict__ C, int ldc, long long bsC,
                 int K, float scale, float* __restrict__ Zp,
                 ushort* __restrict__ Vt)
{
    __shared__ char smem[131072];
    char* A0 = smem;
    char* A1 = smem + 32768;
    char* B0 = smem + 65536;
    char* B1 = smem + 98304;

    const int tid   = threadIdx.x;
    const int lane  = tid & 63;
    const int wave  = tid >> 6;
    const int wr    = wave >> 2;
    const int wc    = wave & 3;
    const int lrow  = lane & 15;
    const int lquad = lane >> 4;
    const long long b = blockIdx.z;

    const ushort* Ag = A  + b * bsA + (long long)blockIdx.y * 256 * lda;
    const ushort* Bg = Bt + b * bsB + (long long)blockIdx.x * 256 * ldb;

    f32x4 acc[8][4] = {};
    bf16x8 af[4][2], bl[2][2], bh[2][2];

    const int nk    = K >> 6;
    const int nIter = nk >> 1;

    stage_half(Ag,      lda, 0,   A0, tid);
    stage_half(Bg,      ldb, 0,   B0, tid);
    stage_half(Bg,      ldb, 128, B0, tid);
    stage_half(Ag,      lda, 128, A0, tid);
    stage_half(Ag + 64, lda, 0,   A1, tid);
    stage_half(Bg + 64, ldb, 0,   B1, tid);
    stage_half(Bg + 64, ldb, 128, B1, tid);
    VMW(6); SBAR();

    for (int i = 0; i < nIter - 1; ++i) {
        const ushort* An1 = Ag + (2 * i + 1) * 64;
        const ushort* An2 = Ag + (2 * i + 2) * 64;
        const ushort* Bn2 = Bg + (2 * i + 2) * 64;
        const ushort* An3 = Ag + (2 * i + 3) * 64;
        const ushort* Bn3 = Bg + (2 * i + 3) * 64;

        RD_A(A0, wr * 64); RD_B(bl, B0, wc * 32);
        stage_half(An1, lda, 128, A1, tid);
        SBAR(); QUAD(0, 0, bl); SBAR();

        RD_B(bh, B0, 128 + wc * 32);
        stage_half(An2, lda, 0, A0, tid);
        SBAR(); QUAD(0, 2, bh); SBAR();

        RD_A(A0, 128 + wr * 64);
        stage_half(Bn2, ldb, 0, B0, tid);
        SBAR(); QUAD(4, 0, bl); SBAR();

        stage_half(Bn2, ldb, 128, B0, tid);
        SBAR(); QUAD(4, 2, bh); VMW(6); SBAR();

        RD_A(A1, wr * 64); RD_B(bl, B1, wc * 32);
        stage_half(An2, lda, 128, A0, tid);
        SBAR(); QUAD(0, 0, bl); SBAR();

        RD_B(bh, B1, 128 + wc * 32);
        stage_half(An3, lda, 0, A1, tid);
        SBAR(); QUAD(0, 2, bh); SBAR();

        RD_A(A1, 128 + wr * 64);
        stage_half(Bn3, ldb, 0, B1, tid);
        SBAR(); QUAD(4, 0, bl); SBAR();

        stage_half(Bn3, ldb, 128, B1, tid);
        SBAR(); QUAD(4, 2, bh); VMW(6); SBAR();
    }

    {
        const ushort* An1 = Ag + (nk - 1) * 64;

        RD_A(A0, wr * 64); RD_B(bl, B0, wc * 32);
        stage_half(An1, lda, 128, A1, tid);
        SBAR(); QUAD(0, 0, bl); SBAR();

        RD_B(bh, B0, 128 + wc * 32);
        SBAR(); QUAD(0, 2, bh); SBAR();

        RD_A(A0, 128 + wr * 64);
        SBAR(); QUAD(4, 0, bl); SBAR();

        SBAR(); QUAD(4, 2, bh); VMW(0); SBAR();

        RD_A(A1, wr * 64); RD_B(bl, B1, wc * 32);
        SBAR(); QUAD(0, 0, bl); SBAR();

        RD_B(bh, B1, 128 + wc * 32);
        SBAR(); QUAD(0, 2, bh); SBAR();

        RD_A(A1, 128 + wr * 64);
        SBAR(); QUAD(4, 0, bl); SBAR();

        SBAR(); QUAD(4, 2, bh);
    }

    if (!EXP && Vt != nullptr && blockIdx.x >= 4) {
        // Vw half -> transposed store into Vt[b2][e][k]
        const int b2 = (int)(blockIdx.y >> 3);
        const int kb = (int)(blockIdx.y & 7) * 256;
        ushort* Vg = Vt + (long long)b2 * 1024 * 2048
                   + (long long)(blockIdx.x - 4) * 256 * 2048 + kb;
#pragma unroll
        for (int m = 0; m < 8; m++) {
            const int row = (m >> 2) * 128 + wr * 64 + (m & 3) * 16 + lquad * 4;
#pragma unroll
            for (int n = 0; n < 4; n++) {
                const int col = (n >> 1) * 128 + wc * 32 + (n & 1) * 16 + lrow;
                ushort o[4] = { f2bf(acc[m][n][0]), f2bf(acc[m][n][1]),
                                f2bf(acc[m][n][2]), f2bf(acc[m][n][3]) };
                *(uint2*)&Vg[(long long)col * 2048 + row] = *(const uint2*)&o[0];
            }
        }
        return;
    }

    ushort* Cg = C + b * bsC + (long long)blockIdx.y * 256 * ldc
                   + (long long)blockIdx.x * 256;

#pragma unroll
    for (int m = 0; m < 8; m++) {
        const int row = (m >> 2) * 128 + wr * 64 + (m & 3) * 16 + lquad * 4;
        float rs[4] = {0.f, 0.f, 0.f, 0.f};
#pragma unroll
        for (int n = 0; n < 4; n++) {
            const int col = (n >> 1) * 128 + wc * 32 + (n & 1) * 16 + lrow;
#pragma unroll
            for (int j = 0; j < 4; j++) {
                float v = acc[m][n][j];
                if (EXP) {
                    float e = __expf(v * scale);
                    rs[j] += e;
                    Cg[(long long)(row + j) * ldc + col] = f2bf(e);
                } else {
                    Cg[(long long)(row + j) * ldc + col] = f2bf(v);
                }
            }
        }
        if (EXP) {
#pragma unroll
            for (int j = 0; j < 4; j++) {
                float s = rs[j];
                s += __shfl_xor(s, 1);
                s += __shfl_xor(s, 2);
                s += __shfl_xor(s, 4);
                s += __shfl_xor(s, 8);
                rs[j] = s;
            }
            if (lrow == 0) {
                const long long zi = ((long long)b * 32 + blockIdx.x * 4 + wc) * 2048
                                   + (long long)blockIdx.y * 256 + row;
#pragma unroll
                for (int j = 0; j < 4; j++) Zp[zi + j] = rs[j];
            }
        }
    }
}

// ---------------------------------------------------------------------------
// pv3: 128x256 tile, BK=64, 3-BUFFER depth-2 pipeline, ONE barrier per tile
// (R12-verified). zinv computed in-kernel from Zp partials (fixed order).
// ---------------------------------------------------------------------------
__global__ __launch_bounds__(512, 2)
void pv3(const ushort* __restrict__ A, int lda, long long bsA,
         const ushort* __restrict__ Bt, int ldb, long long bsB,
         float* __restrict__ C, int ldc, long long bsC,
         int K, const float* __restrict__ Zp)
{
    __shared__ char smem[147456];
    __shared__ float zbuf[128];

    const int tid   = threadIdx.x;
    const int lane  = tid & 63;
    const int wave  = tid >> 6;
    const int wr    = wave >> 2;
    const int wc    = wave & 3;
    const int lrow  = lane & 15;
    const int lquad = lane >> 4;
    const long long b = blockIdx.z;

    if (tid < 128) {
        const float* p = Zp + b * 32 * 2048 + (long long)blockIdx.y * 128 + tid;
        float s = 0.f;
#pragma unroll
        for (int i = 0; i < 32; i++) s += p[i * 2048];
        zbuf[tid] = 1.0f / s;
    }
    __syncthreads();   // Zp loads drained before staging -> vmcnt counts clean

    const ushort* Ag = A  + b * bsA + (long long)blockIdx.y * 128 * lda;
    const ushort* Bg = Bt + b * bsB + (long long)blockIdx.x * 256 * ldb;
    float*        Cg = C  + b * bsC + (long long)blockIdx.y * 128 * ldc
                           + (long long)blockIdx.x * 256;

    f32x4 acc[4][4] = {};
    bf16x8 af[4][2], bl[2][2], bh[2][2];

    const int nk = K >> 6;

#define STAGE_TILE(T, I) do { \
        stage_half(Ag + (T) * 64, lda, 0,   smem + (I) * 16384,         tid); \
        stage_half(Bg + (T) * 64, ldb, 0,   smem + 49152 + (I) * 32768, tid); \
        stage_half(Bg + (T) * 64, ldb, 128, smem + 49152 + (I) * 32768, tid); \
    } while (0)

    STAGE_TILE(0, 0);
    STAGE_TILE(1, 1);
    VMW(6); SBAR();

    int cur = 0;
    for (int t = 0; t < nk; ++t) {
        const char* lAc = smem + cur * 16384;
        const char* lBc = smem + 49152 + cur * 32768;

        RD_A(lAc, wr * 64);
        RD_B(bl, lBc, wc * 32);
        RD_B(bh, lBc, 128 + wc * 32);

        if (t + 2 < nk) {
            int nxt = cur + 2; if (nxt >= 3) nxt -= 3;   // (t+2)%3
            STAGE_TILE(t + 2, nxt);
        }

        QUAD(0, 0, bl);
        QUAD(0, 2, bh);

        if (t + 1 < nk) {
            if (t + 2 < nk) { VMW(6); } else { VMW(0); }
            SBAR();
        }
        cur = (cur == 2) ? 0 : cur + 1;
    }
#undef STAGE_TILE

#pragma unroll
    for (int m = 0; m < 4; m++) {
        const int row = wr * 64 + m * 16 + lquad * 4;
        f32x4 z4 = *(const f32x4*)&zbuf[row];
#pragma unroll
        for (int n = 0; n < 4; n++) {
            const int col = (n >> 1) * 128 + wc * 32 + (n & 1) * 16 + lrow;
#pragma unroll
            for (int j = 0; j < 4; j++)
                storeval(&Cg[(long long)(row + j) * ldc + col], acc[m][n][j] * z4[j]);
        }
    }
}

// ---------------------------------------------------------------------------
// wgemm_splitk: BATCHED split-K weight GEMM. grid (8,8,4): z = pair*2 + ks.
// pair 0: C[e][d] = sum_c wkT[e][c]*wqT[d][c]  (= M^T rows of W2)
// pair 1: C[i][j] = sum_k wo[i][k]*wvT[j][k]   (= Wvo rows of W2)
// ---------------------------------------------------------------------------
__global__ __launch_bounds__(256)
void wgemm_splitk(const ushort* __restrict__ A0, const ushort* __restrict__ B0,
                  const ushort* __restrict__ A1, const ushort* __restrict__ B1,
                  float* __restrict__ P)
{
    __shared__ ushort lA[128 * 64];
    __shared__ ushort lB[128 * 64];

    const int z    = blockIdx.z;
    const int pair = z >> 1;
    const int ksl  = z & 1;

    const ushort* A  = pair ? A1 : A0;
    const ushort* Bt = pair ? B1 : B0;

    const int tid  = threadIdx.x;
    const int lane = tid & 63;
    const int wave = tid >> 6;
    const int wr   = wave >> 1;
    const int wc   = wave & 1;

    A  += (long long)blockIdx.y * 128 * 1024 + ksl * 512;
    Bt += (long long)blockIdx.x * 128 * 1024 + ksl * 512;
    float* Pg = P + (long long)z * 1048576
                  + (long long)blockIdx.y * 128 * 1024 + (long long)blockIdx.x * 128;

    f32x4 acc[4][4] = {};
    const int byte_base = wave * 1024 + lane * 16;

    for (int kt = 0; kt < 512; kt += 64) {
#pragma unroll
        for (int i = 0; i < 4; i++) {
            const int byte = i * 4096 + byte_base;
            const int row  = byte >> 7;
            const int k0   = (byte & 127) >> 1;
            GLDS(A  + (long long)row * 1024 + kt + k0, (char*)lA + byte);
            GLDS(Bt + (long long)row * 1024 + kt + k0, (char*)lB + byte);
        }
        __syncthreads();

#pragma unroll
        for (int ks = 0; ks < 2; ks++) {
            bf16x8 af2[4], bf2[4];
#pragma unroll
            for (int m = 0; m < 4; m++)
                af2[m] = *(const bf16x8*)&lA[(wr * 64 + m * 16 + (lane & 15)) * 64 + ks * 32 + (lane >> 4) * 8];
#pragma unroll
            for (int n = 0; n < 4; n++)
                bf2[n] = *(const bf16x8*)&lB[(wc * 64 + n * 16 + (lane & 15)) * 64 + ks * 32 + (lane >> 4) * 8];
#pragma unroll
            for (int m = 0; m < 4; m++)
#pragma unroll
                for (int n = 0; n < 4; n++)
                    acc[m][n] = __builtin_amdgcn_mfma_f32_16x16x32_bf16(af2[m], bf2[n], acc[m][n], 0, 0, 0);
        }
        __syncthreads();
    }

    const int r0 = wr * 64 + (lane >> 4) * 4;
    const int c0 = wc * 64 + (lane & 15);
#pragma unroll
    for (int m = 0; m < 4; m++)
#pragma unroll
        for (int n = 0; n < 4; n++)
#pragma unroll
            for (int j = 0; j < 4; j++)
                Pg[(long long)(r0 + m * 16 + j) * 1024 + c0 + n * 16] = acc[m][n][j];
}

// ---------------------------------------------------------------------------
__global__ __launch_bounds__(256)
void wreduce(const float* __restrict__ P, ushort* __restrict__ W2)
{
    const int i = blockIdx.x * 256 + threadIdx.x;      // 0..524287
    const int pair = i >> 18;
    const int off  = (i & 262143) * 4;
    const float* base = P + (long long)pair * 2097152 + off;
    float4 s = *(const float4*)(base);
    float4 v = *(const float4*)(base + 1048576);
    s.x += v.x; s.y += v.y; s.z += v.z; s.w += v.w;
    ushort o[4] = { f2bf(s.x), f2bf(s.y), f2bf(s.z), f2bf(s.w) };
    *(uint2*)&W2[(long long)pair * 1048576 + off] = *(const uint2*)&o[0];
}

// ---------------------------------------------------------------------------
// prep: MERGED input convert + weight prep (one launch, 9216 blocks).
//   blocks 0..8191   : x fp32 -> xb bf16 (float4-vectorized)
//   blocks 8192..9215: idx -> (z, by, bx); z<3: transpose-convert wq/wk/wv
//                      into wT[z]; z==3: plain convert wo -> wo_bf.
// ---------------------------------------------------------------------------
__global__ __launch_bounds__(256)
void prep(const float* __restrict__ x, ushort* __restrict__ xb,
          const float* __restrict__ s0, const float* __restrict__ s1,
          const float* __restrict__ s2, const float* __restrict__ s3,
          ushort* __restrict__ wT, ushort* __restrict__ wo_bf)
{
    __shared__ float t[64][65];

    if (blockIdx.x < 8192) {
        const int i = blockIdx.x * 256 + threadIdx.x;
        float4 v = ((const float4*)x)[i];
        ushort o[4] = { f2bf(v.x), f2bf(v.y), f2bf(v.z), f2bf(v.w) };
        *(uint2*)&xb[(size_t)i * 4] = *(const uint2*)&o[0];
        return;
    }

    const int idx = blockIdx.x - 8192;     // 0..1023
    const int z   = idx >> 8;              // 0..3
    const int r2  = idx & 255;
    const int by  = r2 >> 4;
    const int bx  = r2 & 15;
    const int k0 = by * 64, j0 = bx * 64;
    const int r = threadIdx.x >> 2;
    const int c = (threadIdx.x & 3) * 16;

    if (z == 3) {
        const float* p = s3 + (size_t)(k0 + r) * 1024 + j0 + c;
        ushort o[16];
#pragma unroll
        for (int j = 0; j < 16; j++) o[j] = f2bf(p[j]);
        ushort* q = wo_bf + (size_t)(k0 + r) * 1024 + j0 + c;
        *(uint4*)q       = *(const uint4*)&o[0];
        *(uint4*)(q + 8) = *(const uint4*)&o[8];
        return;
    }

    const float* src = (z == 0) ? s0 : (z == 1) ? s1 : s2;
    ushort* dst = wT + (size_t)z * 1048576;

    const float* p = src + (size_t)(k0 + r) * 1024 + j0 + c;
#pragma unroll
    for (int j = 0; j < 16; j++) t[r][c + j] = p[j];
    __syncthreads();

    ushort o[16];
#pragma unroll
    for (int j = 0; j < 16; j++) o[j] = f2bf(t[c + j][r]);
    ushort* q = dst + (size_t)(j0 + r) * 1024 + k0 + c;
    *(uint4*)q       = *(const uint4*)&o[0];
    *(uint4*)(q + 8) = *(const uint4*)&o[8];
}

// ---------------------------------------------------------------------------
extern "C" void kernel_launch(void* const* d_in, const int* in_sizes, int n_in,
                              void* d_out, int out_size, void* d_ws, size_t ws_size,
                              hipStream_t stream)
{
    const float* x  = (const float*)d_in[0];
    const float* wq = (const float*)d_in[1];
    const float* wk = (const float*)d_in[2];
    const float* wv = (const float*)d_in[3];
    const float* wo = (const float*)d_in[4];
    float* out = (float*)d_out;

    // B=4, S=2048, D=1024; M = 8192
    // Algebra: scores = x·M·x^T with M = Wq^T·Wk  (K-projection eliminated);
    //          out    = P·x·Wvo^T · (1/Z) with Wvo = Wo·Wv (out-proj eliminated).
    // W2 = [ M^T ; Wvo ] [2048][1024]. One GEMM produces T (packed Tbuf) and
    // Vw (written transposed straight into Vtb — no transpose_v pass).
    char* ws = (char*)d_ws;
    ushort* xb    = (ushort*)(ws);                 // 16 MB  [8192][1024]
    ushort* W2    = (ushort*)(ws + 16777216);      //  4 MB  [2048][1024]
    ushort* wT    = (ushort*)(ws + 20971520);      //  6 MB  wqT|wkT|wvT
    ushort* wo_bf = (ushort*)(ws + 27262976);      //  2 MB
    ushort* Tbuf  = (ushort*)(ws + 29360128);      // 16 MB  [8192][1024]
    ushort* Vtb   = (ushort*)(ws + 46137344);      // 16 MB  [4][1024][2048]
    ushort* E     = (ushort*)(ws + 62914560);      // 32 MB  [4][2048][2048]
    float*  Pp    = (float*)(ws + 62914560);       // 16 MB  ALIAS of E (used before E)
    float*  Zp    = (float*)(ws + 96468992);       //  1 MB  [4][32][2048]

    ushort* wqT = wT;
    ushort* wkT = wT + 1048576;
    ushort* wvT = wT + 2097152;

    // 1. merged converts/transposes (x + wq/wk/wv/wo), one launch
    prep<<<9216, 256, 0, stream>>>(x, xb, wq, wk, wv, wo, wT, wo_bf);

    // 2. W2 rows 0-1023: M^T = Wk^T·Wq ; rows 1024-2047: Wvo = Wo·Wv
    wgemm_splitk<<<dim3(8, 8, 4), 256, 0, stream>>>(wkT, wqT, wo_bf, wvT, Pp);
    wreduce<<<2048, 256, 0, stream>>>(Pp, W2);

    // 3. [T | Vw] = xb @ W2^T: T -> Tbuf packed (x<4); Vw -> Vtb transposed (x>=4)
    gemm256_8ph<false><<<dim3(8, 32, 1), 512, 0, stream>>>(
        xb, 1024, 0, W2, 1024, 0, Tbuf, 1024, 0, 1024, 1.f, nullptr, Vtb);

    // 4. E = exp(T x^T / 32) bf16 + row-sum partials   (256 blocks)
    gemm256_8ph<true><<<dim3(8, 8, 4), 512, 0, stream>>>(
        Tbuf, 1024, 2048LL * 1024, xb, 1024, 2048LL * 1024,
        E, 2048, 2048LL * 2048, 1024, 0.03125f, Zp, nullptr);

    // 5. out = (E @ Vw) * (1/Z from Zp, in-kernel) -> fp32 d_out  (256 blocks)
    pv3<<<dim3(4, 16, 4), 512, 0, stream>>>(
        E, 2048, 2048LL * 2048, Vtb, 2048, 1024LL * 2048,
        out, 1024, 2048LL * 1024, 2048, Zp);
}